// Round 2
// baseline (1240.855 us; speedup 1.0000x reference)
//
#include <hip/hip_runtime.h>
#include <math.h>

// ---------------- problem sizes ----------------
// B=16, T=2000, D=300, TQ=30, TOPT=16, ranges {1,2,4,10,25}
// ALL float tensors are fp32 (per reference setup_inputs); output fp32 (B,4).

// ---------------- workspace layout (float indices), total ~124 MB ----------------
constexpr size_t OFF_ART   = 0;          //  9,600,000 f32  article embeddings
constexpr size_t OFF_R2    = 9600000;    //  9,600,000 f32  HC (coarse h) -> Z -> cs -> ENC
constexpr size_t OFF_GATE  = 19200000;   //  9,600,000 f32  gate -> AOQ
constexpr size_t OFF_WT    = 28800000;   //    630,000 f32  7 x 300x300 packed W^T [d][e]
constexpr size_t OFF_QEMB  = 29430000;   //    144,000
constexpr size_t OFF_KEYSQ = 29574000;   //    144,000
constexpr size_t OFF_OPTE  = 29718000;   //    307,200
constexpr size_t OFF_KEYS2 = 30025200;   //    307,200
constexpr size_t OFF_KEYS3 = 30332400;   //    307,200
constexpr size_t OFF_SCANA = 30639600;   //     76,800
constexpr size_t OFF_SCANB = 30716400;   //     76,800
constexpr size_t OFF_CST   = 30793200;   //     76,800
constexpr size_t OFF_PART  = 30870000;   //    129,024  per-tile softmax column sums
// end = 30,999,024 floats = 123,996,096 bytes

// HC row layout inside R2 (range-local rows, 300 cols each):
//   r=2: [0,16000) = b*1000+g | r=4: [16000,24000) = b*500+g
//   r=10:[24000,27200) = b*200+g | r=25:[27200,28480) = b*80+g

// ---------------- weight pack: Wt[m][d][e] = W_m[e][d] ----------------
// m: 0..4 = ce_W[0..4], 5 = Wz, 6 = Wo
__global__ void k_pack(float* ws, const float* ceW, const float* Wz, const float* Wo){
    int id = blockIdx.x * 256 + threadIdx.x;
    if (id >= 630000) return;
    int m = id / 90000; int r = id % 90000; int d = r / 300; int e = r % 300;
    const float* src = (m < 5) ? (ceW + (size_t)m * 90000) : (m == 5 ? Wz : Wo);
    ws[OFF_WT + id] = src[(size_t)e * 300 + d];
}

// ---------------- embedding gathers ----------------
__global__ void k_gather(float* ws, const float* emb, const int* art_in, const int* q_in,
                         const int* o1, const int* o2, const int* o3, const int* o4){
    size_t id = (size_t)blockIdx.x * 256 + threadIdx.x;
    if (id < 9600000) {                        // article
        size_t row = id / 300; int d = (int)(id % 300);
        int tok = art_in[row];
        ws[OFF_ART + id] = emb[(size_t)tok * 300 + d];
    } else if (id < 9744000) {                 // question
        size_t i2 = id - 9600000; size_t row = i2 / 300; int d = (int)(i2 % 300);
        int tok = q_in[row];
        ws[OFF_QEMB + i2] = emb[(size_t)tok * 300 + d];
    } else if (id < 10051200) {                // options: row = opt*256 + b*16 + w
        size_t i3 = id - 9744000; size_t row = i3 / 300; int d = (int)(i3 % 300);
        int opt = (int)(row / 256); int rr = (int)(row % 256);
        const int* op = (opt == 0) ? o1 : (opt == 1) ? o2 : (opt == 2) ? o3 : o4;
        int tok = op[rr];
        ws[OFF_OPTE + i3] = emb[(size_t)tok * 300 + d];
    }
}

// ---------------- coarse CE matvec (r=2,4,10,25): group-sum staged in LDS ----------------
// blocks: [0,500) r=2 | [500,750) r=4 | [750,850) r=10 | [850,890) r=25
__global__ __launch_bounds__(256) void k_ce_coarse(float* ws, const float* ceb){
    int g = blockIdx.x;
    int r, rows0, wi, sb, bdiv;
    if (g < 500)      { r = 2;  rows0 = 0;     wi = 1; sb = 0;   bdiv = 1000; }
    else if (g < 750) { r = 4;  rows0 = 16000; wi = 2; sb = 500; bdiv = 500; }
    else if (g < 850) { r = 10; rows0 = 24000; wi = 3; sb = 750; bdiv = 200; }
    else              { r = 25; rows0 = 27200; wi = 4; sb = 850; bdiv = 80;  }
    int rowLocal0 = (g - sb) * 32;

    __shared__ float X[32 * 300];
    int tid = threadIdx.x;
    for (int i = tid; i < 9600; i += 256) {
        int rl = i / 300, d = i % 300;
        int R = rowLocal0 + rl;
        int b = R / bdiv, gg = R % bdiv;
        size_t base = OFF_ART + ((size_t)b * 2000 + (size_t)gg * r) * 300 + d;
        float s = 0.f;
        for (int j = 0; j < r; j++) s += ws[base + (size_t)j * 300];
        X[i] = s;
    }
    __syncthreads();

    int wave = tid >> 6, lane = tid & 63;
    int r0 = wave * 8;
    float acc[5][8];
    #pragma unroll
    for (int c = 0; c < 5; c++)
        #pragma unroll
        for (int j = 0; j < 8; j++) acc[c][j] = 0.f;

    const float* W = ws + OFF_WT + (size_t)wi * 90000;
    for (int d = 0; d < 300; d++) {
        float xv[8];
        #pragma unroll
        for (int j = 0; j < 8; j++) xv[j] = X[(r0 + j) * 300 + d];
        const float* Wrow = W + d * 300;
        #pragma unroll
        for (int c = 0; c < 5; c++) {
            int e = c * 64 + lane;
            float wv = (c < 4 || e < 300) ? Wrow[e] : 0.f;
            #pragma unroll
            for (int j = 0; j < 8; j++) acc[c][j] = fmaf(xv[j], wv, acc[c][j]);
        }
    }
    #pragma unroll
    for (int c = 0; c < 5; c++) {
        int e = c * 64 + lane;
        if (e < 300) {
            float bv = ceb[(size_t)wi * 300 + e];
            #pragma unroll
            for (int j = 0; j < 8; j++) {
                float v = fmaxf(acc[c][j] + bv, 0.f);
                ws[OFF_R2 + (size_t)(rows0 + rowLocal0 + r0 + j) * 300 + e] = v;
            }
        }
    }
}

// ---------------- r=1 CE matvec fused with gate MLP ----------------
__global__ __launch_bounds__(256) void k_gate_fused(float* ws, const float* ceb,
                                                    const float* m1W, const float* m1b,
                                                    const float* m2W, const float* m2b){
    int row0 = blockIdx.x * 32;
    __shared__ float X[32 * 300];
    int tid = threadIdx.x;
    for (int i = tid; i < 9600; i += 256)
        X[i] = ws[OFF_ART + (size_t)row0 * 300 + i];
    __syncthreads();

    // hoist tiny gate weights
    float w1[3][5], b1[3], w2[3], b2;
    #pragma unroll
    for (int k = 0; k < 3; k++) {
        #pragma unroll
        for (int i = 0; i < 5; i++) w1[k][i] = m1W[k * 5 + i];
        b1[k] = m1b[k]; w2[k] = m2W[k];
    }
    b2 = m2b[0];

    int wave = tid >> 6, lane = tid & 63;
    int r0 = wave * 8;
    float acc[5][8];
    #pragma unroll
    for (int c = 0; c < 5; c++)
        #pragma unroll
        for (int j = 0; j < 8; j++) acc[c][j] = 0.f;

    const float* W = ws + OFF_WT;  // ce index 0
    for (int d = 0; d < 300; d++) {
        float xv[8];
        #pragma unroll
        for (int j = 0; j < 8; j++) xv[j] = X[(r0 + j) * 300 + d];
        const float* Wrow = W + d * 300;
        #pragma unroll
        for (int c = 0; c < 5; c++) {
            int e = c * 64 + lane;
            float wv = (c < 4 || e < 300) ? Wrow[e] : 0.f;
            #pragma unroll
            for (int j = 0; j < 8; j++) acc[c][j] = fmaf(xv[j], wv, acc[c][j]);
        }
    }

    #pragma unroll
    for (int j = 0; j < 8; j++) {
        int row = row0 + r0 + j;
        int b = row / 2000, t = row % 2000;
        size_t c1 = OFF_R2 + (size_t)((size_t)b * 1000 + t / 2) * 300;
        size_t c2 = OFF_R2 + (size_t)(16000 + (size_t)b * 500 + t / 4) * 300;
        size_t c3 = OFF_R2 + (size_t)(24000 + (size_t)b * 200 + t / 10) * 300;
        size_t c4 = OFF_R2 + (size_t)(27200 + (size_t)b * 80 + t / 25) * 300;
        #pragma unroll
        for (int c = 0; c < 5; c++) {
            int e = c * 64 + lane;
            if (e < 300) {
                float y0 = fmaxf(acc[c][j] + ceb[e], 0.f);
                float y1 = ws[c1 + e] * 0.5f;
                float y2 = ws[c2 + e] * 0.25f;
                float y3 = ws[c3 + e] * 0.1f;
                float y4 = ws[c4 + e] * 0.04f;
                float gacc = b2;
                #pragma unroll
                for (int k = 0; k < 3; k++) {
                    float a = b1[k] + y0 * w1[k][0] + y1 * w1[k][1] + y2 * w1[k][2]
                            + y3 * w1[k][3] + y4 * w1[k][4];
                    gacc += fmaxf(a, 0.f) * w2[k];
                }
                ws[OFF_GATE + (size_t)row * 300 + e] = fmaxf(gacc, 0.f);
            }
        }
    }
}

// ---------------- z matvec (tanh) -> R2 region (clobbers dead HC) ----------------
__global__ __launch_bounds__(256) void k_zmat(float* ws, const float* bz){
    int row0 = blockIdx.x * 32;
    __shared__ float X[32 * 300];
    int tid = threadIdx.x;
    for (int i = tid; i < 9600; i += 256)
        X[i] = ws[OFF_ART + (size_t)row0 * 300 + i];
    __syncthreads();

    int wave = tid >> 6, lane = tid & 63;
    int r0 = wave * 8;
    float acc[5][8];
    #pragma unroll
    for (int c = 0; c < 5; c++)
        #pragma unroll
        for (int j = 0; j < 8; j++) acc[c][j] = 0.f;

    const float* W = ws + OFF_WT + (size_t)5 * 90000;  // Wz
    for (int d = 0; d < 300; d++) {
        float xv[8];
        #pragma unroll
        for (int j = 0; j < 8; j++) xv[j] = X[(r0 + j) * 300 + d];
        const float* Wrow = W + d * 300;
        #pragma unroll
        for (int c = 0; c < 5; c++) {
            int e = c * 64 + lane;
            float wv = (c < 4 || e < 300) ? Wrow[e] : 0.f;
            #pragma unroll
            for (int j = 0; j < 8; j++) acc[c][j] = fmaf(xv[j], wv, acc[c][j]);
        }
    }
    #pragma unroll
    for (int c = 0; c < 5; c++) {
        int e = c * 64 + lane;
        if (e < 300) {
            float bv = bz[e];
            #pragma unroll
            for (int j = 0; j < 8; j++)
                ws[OFF_R2 + (size_t)(row0 + r0 + j) * 300 + e] = tanhf(acc[c][j] + bv);
        }
    }
}

// ---------------- MRU scan: 16 chunks x 125 steps ----------------
__global__ void k_scan1(float* ws){
    int tid = blockIdx.x * 256 + threadIdx.x;
    if (tid >= 76800) return;
    int c = tid / 4800, ch = tid % 4800;
    int b = ch / 300, d = ch % 300;
    size_t base = (size_t)b * 2000 * 300 + d;
    float A = 1.f, Bv = 0.f;
    int t0 = c * 125;
    for (int k = 0; k < 125; k++) {
        size_t ix = base + (size_t)(t0 + k) * 300;
        float g = ws[OFF_GATE + ix], zz = ws[OFF_R2 + ix];
        Bv = g * Bv + (1.f - g) * zz;
        A *= g;
    }
    ws[OFF_SCANA + tid] = A;
    ws[OFF_SCANB + tid] = Bv;
}

__global__ void k_scan2(float* ws){
    int ch = blockIdx.x * 256 + threadIdx.x;
    if (ch >= 4800) return;
    float c = 0.f;
    for (int j = 0; j < 16; j++) {
        ws[OFF_CST + (size_t)j * 4800 + ch] = c;
        c = ws[OFF_SCANA + (size_t)j * 4800 + ch] * c + ws[OFF_SCANB + (size_t)j * 4800 + ch];
    }
}

__global__ void k_scan3(float* ws){
    int tid = blockIdx.x * 256 + threadIdx.x;
    if (tid >= 76800) return;
    int c = tid / 4800, ch = tid % 4800;
    int b = ch / 300, d = ch % 300;
    size_t base = (size_t)b * 2000 * 300 + d;
    float cc = ws[OFF_CST + tid];
    int t0 = c * 125;
    for (int k = 0; k < 125; k++) {
        size_t ix = base + (size_t)(t0 + k) * 300;
        float g = ws[OFF_GATE + ix], zz = ws[OFF_R2 + ix];
        cc = g * cc + (1.f - g) * zz;
        ws[OFF_R2 + ix] = cc;          // store cs in place of z
    }
}

// ---------------- o matvec (tanh) fused with enc = o * cs (in-place in R2) ----------------
__global__ __launch_bounds__(256) void k_oenc(float* ws, const float* bo){
    int row0 = blockIdx.x * 32;
    __shared__ float X[32 * 300];
    int tid = threadIdx.x;
    for (int i = tid; i < 9600; i += 256)
        X[i] = ws[OFF_ART + (size_t)row0 * 300 + i];
    __syncthreads();

    int wave = tid >> 6, lane = tid & 63;
    int r0 = wave * 8;
    float acc[5][8];
    #pragma unroll
    for (int c = 0; c < 5; c++)
        #pragma unroll
        for (int j = 0; j < 8; j++) acc[c][j] = 0.f;

    const float* W = ws + OFF_WT + (size_t)6 * 90000;  // Wo
    for (int d = 0; d < 300; d++) {
        float xv[8];
        #pragma unroll
        for (int j = 0; j < 8; j++) xv[j] = X[(r0 + j) * 300 + d];
        const float* Wrow = W + d * 300;
        #pragma unroll
        for (int c = 0; c < 5; c++) {
            int e = c * 64 + lane;
            float wv = (c < 4 || e < 300) ? Wrow[e] : 0.f;
            #pragma unroll
            for (int j = 0; j < 8; j++) acc[c][j] = fmaf(xv[j], wv, acc[c][j]);
        }
    }
    #pragma unroll
    for (int c = 0; c < 5; c++) {
        int e = c * 64 + lane;
        if (e < 300) {
            float bv = bo[e];
            #pragma unroll
            for (int j = 0; j < 8; j++) {
                size_t idx = OFF_R2 + (size_t)(row0 + r0 + j) * 300 + e;
                float o = tanhf(acc[c][j] + bv);
                ws[idx] = o * ws[idx];
            }
        }
    }
}

// ---------------- key projections (f1 on q; f2,f3 on options) ----------------
__global__ __launch_bounds__(320) void k_keys(float* ws, const float* f1W, const float* f1b,
                                              const float* f2W, const float* f2b,
                                              const float* f3W, const float* f3b){
    int rid = blockIdx.x;
    const float* src; const float* W; const float* bias; float* out;
    if (rid < 480)       { src = ws + OFF_QEMB + (size_t)rid * 300;               W = f1W; bias = f1b; out = ws + OFF_KEYSQ + (size_t)rid * 300; }
    else if (rid < 1504) { int rr = rid - 480;  src = ws + OFF_OPTE + (size_t)rr * 300; W = f2W; bias = f2b; out = ws + OFF_KEYS2 + (size_t)rr * 300; }
    else                 { int rr = rid - 1504; src = ws + OFF_OPTE + (size_t)rr * 300; W = f3W; bias = f3b; out = ws + OFF_KEYS3 + (size_t)rr * 300; }
    __shared__ float X[300];
    int tid = threadIdx.x;
    for (int i = tid; i < 300; i += 320) X[i] = src[i];
    __syncthreads();
    if (tid < 300) {
        float acc = bias[tid];
        const float* wr = W + (size_t)tid * 300;
        for (int d = 0; d < 300; d++) acc += X[d] * wr[d];
        out[tid] = acc;
    }
}

// ---------------- aoq attention: main=art_enc (R2), attn_in=q; out -> GATE region ----------------
__global__ __launch_bounds__(256) void k_aoq(float* ws){
    int tile = blockIdx.x, b = blockIdx.y;
    int t0 = tile * 32;
    __shared__ float K[30 * 300], Q[30 * 300], Xe[32 * 300], S[32 * 32];
    int tid = threadIdx.x;
    for (int i = tid; i < 9000; i += 256) {
        K[i] = ws[OFF_KEYSQ + (size_t)b * 9000 + i];
        Q[i] = ws[OFF_QEMB  + (size_t)b * 9000 + i];
    }
    for (int i = tid; i < 9600; i += 256) {
        int r = i / 300; int t = t0 + r;
        Xe[i] = (t < 2000) ? ws[OFF_R2 + ((size_t)b * 2000 + t) * 300 + (i % 300)] : 0.f;
    }
    __syncthreads();
    for (int p = tid; p < 960; p += 256) {
        int tl = p / 30, w = p % 30;
        const float4* xr = (const float4*)&Xe[tl * 300];
        const float4* kr = (const float4*)&K[w * 300];
        float acc = 0.f;
        #pragma unroll 5
        for (int q = 0; q < 75; q++) {
            float4 a = xr[q], kk = kr[q];
            acc += a.x * kk.x + a.y * kk.y + a.z * kk.z + a.w * kk.w;
        }
        S[tl * 32 + w] = acc;
    }
    __syncthreads();
    if (tid < 32) {
        float m = -1e30f;
        for (int w = 0; w < 30; w++) m = fmaxf(m, S[tid * 32 + w]);
        float s = 0.f;
        for (int w = 0; w < 30; w++) { float e = expf(S[tid * 32 + w] - m); S[tid * 32 + w] = e; s += e; }
        float inv = 1.f / s;
        for (int w = 0; w < 30; w++) S[tid * 32 + w] *= inv;
    }
    __syncthreads();
    for (int idx = tid; idx < 9600; idx += 256) {
        int tl = idx / 300, e = idx % 300;
        int t = t0 + tl;
        if (t < 2000) {
            float acc = 0.f;
            for (int w = 0; w < 30; w++) acc += S[tl * 32 + w] * Q[w * 300 + e];
            ws[OFF_GATE + ((size_t)b * 2000 + t) * 300 + e] = acc;
        }
    }
}

// ---------------- option attentions: per-tile softmax column sums -> PART ----------------
__global__ __launch_bounds__(256) void k_optatt(float* ws){
    int tile = blockIdx.x, b = blockIdx.y;
    int t0 = tile * 32;
    __shared__ float A_[32 * 300], KY[16 * 300], S[32 * 16];
    int tid = threadIdx.x;
    for (int i = tid; i < 9600; i += 256) {
        int r = i / 300; int t = t0 + r;
        A_[i] = (t < 2000) ? ws[OFF_GATE + ((size_t)b * 2000 + t) * 300 + (i % 300)] : 0.f;
    }
    for (int combo = 0; combo < 8; combo++) {
        int opt = combo & 3; bool f3 = combo >= 4;
        size_t kbase = (f3 ? OFF_KEYS3 : OFF_KEYS2) + ((size_t)opt * 256 + (size_t)b * 16) * 300;
        __syncthreads();
        for (int i = tid; i < 4800; i += 256) KY[i] = ws[kbase + i];
        __syncthreads();
        for (int p = tid; p < 512; p += 256) {
            int tl = p / 16, w = p % 16;
            const float4* xr = (const float4*)&A_[tl * 300];
            const float4* kr = (const float4*)&KY[w * 300];
            float acc = 0.f;
            #pragma unroll 5
            for (int q = 0; q < 75; q++) {
                float4 a = xr[q], kk = kr[q];
                acc += a.x * kk.x + a.y * kk.y + a.z * kk.z + a.w * kk.w;
            }
            S[tl * 16 + w] = acc;
        }
        __syncthreads();
        if (tid < 32) {
            float m = -1e30f;
            for (int w = 0; w < 16; w++) m = fmaxf(m, S[tid * 16 + w]);
            float s = 0.f;
            for (int w = 0; w < 16; w++) { float e = expf(S[tid * 16 + w] - m); S[tid * 16 + w] = e; s += e; }
            float inv = 1.f / s;
            for (int w = 0; w < 16; w++) S[tid * 16 + w] *= inv;
        }
        __syncthreads();
        if (tid < 16) {
            float s = 0.f;
            int lim = (2000 - t0 < 32) ? (2000 - t0) : 32;
            for (int tl = 0; tl < lim; tl++) s += S[tl * 16 + tid];
            ws[OFF_PART + (((size_t)combo * 16 + b) * 63 + tile) * 16 + tid] = s;
        }
    }
}

// ---------------- final: reduce PART, per-option vec -> 75 -> 1 ----------------
__global__ __launch_bounds__(256) void k_final(float* ws, const float* as1W, const float* as1b,
                                               const float* as2W, const float* as2b, float* out){
    int blk = blockIdx.x; int o = blk >> 4, b = blk & 15;
    __shared__ float vec[600]; __shared__ float cm[32]; __shared__ float hb[80];
    int tid = threadIdx.x;
    if (tid < 32) {
        int half = tid / 16, wk = tid % 16;
        int combo = half ? (4 + o) : o;
        float s = 0.f;
        size_t base = OFF_PART + (((size_t)combo * 16 + b) * 63) * 16 + wk;
        for (int t = 0; t < 63; t++) s += ws[base + (size_t)t * 16];
        cm[tid] = s * (1.f / 2000.f);
    }
    __syncthreads();
    const float* oe = ws + OFF_OPTE + ((size_t)o * 256 + (size_t)b * 16) * 300;
    for (int idx = tid; idx < 600; idx += 256) {
        int half = idx / 300, e = idx % 300;
        float acc = 0.f;
        for (int w = 0; w < 16; w++) acc += cm[half * 16 + w] * oe[(size_t)w * 300 + e];
        vec[idx] = acc;
    }
    __syncthreads();
    if (tid < 75) {
        float acc = as1b[tid];
        for (int m = 0; m < 600; m++) acc += vec[m] * as1W[(size_t)tid * 600 + m];
        hb[tid] = fmaxf(acc, 0.f);
    }
    __syncthreads();
    if (tid == 0) {
        float s = as2b[0];
        for (int j = 0; j < 75; j++) s += hb[j] * as2W[j];
        out[b * 4 + o] = s;
    }
}

extern "C" void kernel_launch(void* const* d_in, const int* in_sizes, int n_in,
                              void* d_out, int out_size, void* d_ws, size_t ws_size,
                              hipStream_t stream) {
    float* ws = (float*)d_ws;
    const int* o1 = (const int*)d_in[0];
    const int* o2 = (const int*)d_in[1];
    const int* o3 = (const int*)d_in[2];
    const int* o4 = (const int*)d_in[3];
    const int* qin = (const int*)d_in[4];
    const int* ain = (const int*)d_in[5];
    const float* emb  = (const float*)d_in[6];
    const float* ceW  = (const float*)d_in[7];
    const float* ceb  = (const float*)d_in[8];
    const float* m1W  = (const float*)d_in[9];
    const float* m1b  = (const float*)d_in[10];
    const float* m2W  = (const float*)d_in[11];
    const float* m2b  = (const float*)d_in[12];
    const float* Wz   = (const float*)d_in[13];
    const float* bz   = (const float*)d_in[14];
    const float* Wo   = (const float*)d_in[15];
    const float* bo   = (const float*)d_in[16];
    const float* f1W  = (const float*)d_in[17];
    const float* f1b  = (const float*)d_in[18];
    const float* f2W  = (const float*)d_in[19];
    const float* f2b  = (const float*)d_in[20];
    const float* f3W  = (const float*)d_in[21];
    const float* f3b  = (const float*)d_in[22];
    const float* as1W = (const float*)d_in[23];
    const float* as1b = (const float*)d_in[24];
    const float* as2W = (const float*)d_in[25];
    const float* as2b = (const float*)d_in[26];

    k_pack<<<(630000 + 255) / 256, 256, 0, stream>>>(ws, ceW, Wz, Wo);
    k_gather<<<(10051200 + 255) / 256, 256, 0, stream>>>(ws, emb, ain, qin, o1, o2, o3, o4);
    k_ce_coarse<<<890, 256, 0, stream>>>(ws, ceb);
    k_gate_fused<<<1000, 256, 0, stream>>>(ws, ceb, m1W, m1b, m2W, m2b);
    k_zmat<<<1000, 256, 0, stream>>>(ws, bz);
    k_scan1<<<300, 256, 0, stream>>>(ws);
    k_scan2<<<19, 256, 0, stream>>>(ws);
    k_scan3<<<300, 256, 0, stream>>>(ws);
    k_oenc<<<1000, 256, 0, stream>>>(ws, bo);
    k_keys<<<2528, 320, 0, stream>>>(ws, f1W, f1b, f2W, f2b, f3W, f3b);
    k_aoq<<<dim3(63, 16), 256, 0, stream>>>(ws);
    k_optatt<<<dim3(63, 16), 256, 0, stream>>>(ws);
    k_final<<<64, 256, 0, stream>>>(ws, as1W, as1b, as2W, as2b, (float*)d_out);
}

// Round 3
// 1083.220 us; speedup vs baseline: 1.1455x; 1.1455x over previous
//
#include <hip/hip_runtime.h>
#include <math.h>

// B=16, T=2000, D=300, TQ=30, TOPT=16, ranges {1,2,4,10,25}; all fp32.

// ---------------- workspace layout (float indices), ~160 MB ----------------
constexpr size_t OFF_ART   = 0;           // 9,600,000  article embeddings
constexpr size_t OFF_R2    = 9600000;     // 9,600,000  z -> cs -> enc
constexpr size_t OFF_GATE  = 19200000;    // 9,600,000  gate
constexpr size_t OFF_HC    = 28800000;    // 8,544,000  coarse CE outputs
constexpr size_t OFF_WT    = 37344000;    //   630,000  7 x 300x300 packed W^T [d][e]
constexpr size_t OFF_QEMB  = 37974000;    //   144,000
constexpr size_t OFF_KEYSQ = 38118000;    //   144,000
constexpr size_t OFF_OPTE  = 38262000;    //   307,200
constexpr size_t OFF_KEYS2 = 38569200;    //   307,200
constexpr size_t OFF_KEYS3 = 38876400;    //   307,200
constexpr size_t OFF_SCANA = 39183600;    //   192,000  (40 chunks x 4800)
constexpr size_t OFF_SCANB = 39375600;    //   192,000
constexpr size_t OFF_CST   = 39567600;    //   192,000
constexpr size_t OFF_PART  = 39759600;    //   129,024
// end = 39,888,624 floats = 159.6 MB (round-1 binary proved >=172.6 MB writable)

// HC row layout: r2 [0,16000)=b*1000+g | r4 [16000,24000)=b*500+g
//                r10 [24000,27200)=b*200+g | r25 [27200,28480)=b*80+g

__global__ void k_pack(float* ws, const float* ceW, const float* Wz, const float* Wo){
    int id = blockIdx.x * 256 + threadIdx.x;
    if (id >= 630000) return;
    int m = id / 90000; int r = id % 90000; int d = r / 300; int e = r % 300;
    const float* src = (m < 5) ? (ceW + (size_t)m * 90000) : (m == 5 ? Wz : Wo);
    ws[OFF_WT + id] = src[(size_t)e * 300 + d];
}

__global__ void k_gather(float* ws, const float* emb, const int* art_in, const int* q_in,
                         const int* o1, const int* o2, const int* o3, const int* o4){
    size_t id = (size_t)blockIdx.x * 256 + threadIdx.x;
    if (id < 9600000) {
        size_t row = id / 300; int d = (int)(id % 300);
        ws[OFF_ART + id] = emb[(size_t)art_in[row] * 300 + d];
    } else if (id < 9744000) {
        size_t i2 = id - 9600000; size_t row = i2 / 300; int d = (int)(i2 % 300);
        ws[OFF_QEMB + i2] = emb[(size_t)q_in[row] * 300 + d];
    } else if (id < 10051200) {
        size_t i3 = id - 9744000; size_t row = i3 / 300; int d = (int)(i3 % 300);
        int opt = (int)(row / 256); int rr = (int)(row % 256);
        const int* op = (opt == 0) ? o1 : (opt == 1) ? o2 : (opt == 2) ? o3 : o4;
        ws[OFF_OPTE + i3] = emb[(size_t)op[rr] * 300 + d];
    }
}

// ---------------- coarse CE matvec (r=2,4,10,25), 16-row tiles ----------------
// blocks: [0,1000) r=2 | [1000,1500) r=4 | [1500,1700) r=10 | [1700,1780) r=25
__global__ __launch_bounds__(256) void k_ce_coarse(float* ws, const float* ceb){
    int g = blockIdx.x;
    int r, rows0, wi, sb, bdiv;
    if (g < 1000)      { r = 2;  rows0 = 0;     wi = 1; sb = 0;    bdiv = 1000; }
    else if (g < 1500) { r = 4;  rows0 = 16000; wi = 2; sb = 1000; bdiv = 500; }
    else if (g < 1700) { r = 10; rows0 = 24000; wi = 3; sb = 1500; bdiv = 200; }
    else               { r = 25; rows0 = 27200; wi = 4; sb = 1700; bdiv = 80;  }
    int rowLocal0 = (g - sb) * 16;

    __shared__ float X[16 * 300];
    int tid = threadIdx.x;
    for (int i = tid; i < 4800; i += 256) {
        int rl = i / 300, d = i % 300;
        int R = rowLocal0 + rl;
        int b = R / bdiv, gg = R % bdiv;
        size_t base = OFF_ART + ((size_t)b * 2000 + (size_t)gg * r) * 300 + d;
        float s = 0.f;
        for (int j = 0; j < r; j++) s += ws[base + (size_t)j * 300];
        X[i] = s;
    }
    __syncthreads();

    int wave = tid >> 6, lane = tid & 63;
    int r0 = wave * 4;
    float acc[5][4];
    #pragma unroll
    for (int c = 0; c < 5; c++)
        #pragma unroll
        for (int j = 0; j < 4; j++) acc[c][j] = 0.f;

    const float* W = ws + OFF_WT + (size_t)wi * 90000;
    #pragma unroll 2
    for (int d = 0; d < 300; d++) {
        float xv[4];
        #pragma unroll
        for (int j = 0; j < 4; j++) xv[j] = X[(r0 + j) * 300 + d];
        const float* Wrow = W + d * 300;
        #pragma unroll
        for (int c = 0; c < 5; c++) {
            int e = c * 64 + lane;
            float wv = (c < 4 || e < 300) ? Wrow[e] : 0.f;
            #pragma unroll
            for (int j = 0; j < 4; j++) acc[c][j] = fmaf(xv[j], wv, acc[c][j]);
        }
    }
    #pragma unroll
    for (int c = 0; c < 5; c++) {
        int e = c * 64 + lane;
        if (e < 300) {
            float bv = ceb[(size_t)wi * 300 + e];
            #pragma unroll
            for (int j = 0; j < 4; j++)
                ws[OFF_HC + (size_t)(rows0 + rowLocal0 + r0 + j) * 300 + e] = fmaxf(acc[c][j] + bv, 0.f);
        }
    }
}

// ---------------- fused: ce0 matvec + gate MLP + z matvec, 16-row tiles ----------------
__global__ __launch_bounds__(256) void k_fused(float* ws, const float* ceb,
                                               const float* m1W, const float* m1b,
                                               const float* m2W, const float* m2b,
                                               const float* bz){
    int row0 = blockIdx.x * 16;
    __shared__ float X[16 * 300];
    int tid = threadIdx.x;
    for (int i = tid; i < 4800; i += 256) X[i] = ws[OFF_ART + (size_t)row0 * 300 + i];
    __syncthreads();

    float w1[3][5], b1[3], w2[3], b2;
    #pragma unroll
    for (int k = 0; k < 3; k++) {
        #pragma unroll
        for (int i = 0; i < 5; i++) w1[k][i] = m1W[k * 5 + i];
        b1[k] = m1b[k]; w2[k] = m2W[k];
    }
    b2 = m2b[0];

    int wave = tid >> 6, lane = tid & 63;
    int r0 = wave * 4;
    float accA[5][4], accZ[5][4];
    #pragma unroll
    for (int c = 0; c < 5; c++)
        #pragma unroll
        for (int j = 0; j < 4; j++) { accA[c][j] = 0.f; accZ[c][j] = 0.f; }

    const float* W0 = ws + OFF_WT;                       // ce_W[0]
    const float* WZ = ws + OFF_WT + (size_t)5 * 90000;   // Wz
    #pragma unroll 2
    for (int d = 0; d < 300; d++) {
        float xv[4];
        #pragma unroll
        for (int j = 0; j < 4; j++) xv[j] = X[(r0 + j) * 300 + d];
        const float* W0row = W0 + d * 300;
        const float* WZrow = WZ + d * 300;
        #pragma unroll
        for (int c = 0; c < 5; c++) {
            int e = c * 64 + lane;
            bool ok = (c < 4 || e < 300);
            float wa = ok ? W0row[e] : 0.f;
            float wz = ok ? WZrow[e] : 0.f;
            #pragma unroll
            for (int j = 0; j < 4; j++) {
                accA[c][j] = fmaf(xv[j], wa, accA[c][j]);
                accZ[c][j] = fmaf(xv[j], wz, accZ[c][j]);
            }
        }
    }

    #pragma unroll
    for (int j = 0; j < 4; j++) {
        int row = row0 + r0 + j;
        int b = row / 2000, t = row % 2000;
        size_t c1 = OFF_HC + (size_t)((size_t)b * 1000 + t / 2) * 300;
        size_t c2 = OFF_HC + (size_t)(16000 + (size_t)b * 500 + t / 4) * 300;
        size_t c3 = OFF_HC + (size_t)(24000 + (size_t)b * 200 + t / 10) * 300;
        size_t c4 = OFF_HC + (size_t)(27200 + (size_t)b * 80 + t / 25) * 300;
        #pragma unroll
        for (int c = 0; c < 5; c++) {
            int e = c * 64 + lane;
            if (e < 300) {
                float y0 = fmaxf(accA[c][j] + ceb[e], 0.f);
                float y1 = ws[c1 + e] * 0.5f;
                float y2 = ws[c2 + e] * 0.25f;
                float y3 = ws[c3 + e] * 0.1f;
                float y4 = ws[c4 + e] * 0.04f;
                float gacc = b2;
                #pragma unroll
                for (int k = 0; k < 3; k++) {
                    float a = b1[k] + y0 * w1[k][0] + y1 * w1[k][1] + y2 * w1[k][2]
                            + y3 * w1[k][3] + y4 * w1[k][4];
                    gacc += fmaxf(a, 0.f) * w2[k];
                }
                ws[OFF_GATE + (size_t)row * 300 + e] = fmaxf(gacc, 0.f);
                ws[OFF_R2 + (size_t)row * 300 + e] = tanhf(accZ[c][j] + bz[e]);
            }
        }
    }
}

// ---------------- MRU scan: 40 chunks x 50 steps ----------------
__global__ void k_scan1(float* ws){
    int tid = blockIdx.x * 256 + threadIdx.x;
    if (tid >= 192000) return;
    int c = tid / 4800, ch = tid % 4800;
    int b = ch / 300, d = ch % 300;
    size_t base = (size_t)b * 2000 * 300 + d;
    float A = 1.f, Bv = 0.f;
    int t0 = c * 50;
    for (int k = 0; k < 50; k++) {
        size_t ix = base + (size_t)(t0 + k) * 300;
        float g = ws[OFF_GATE + ix], zz = ws[OFF_R2 + ix];
        Bv = g * Bv + (1.f - g) * zz;
        A *= g;
    }
    ws[OFF_SCANA + tid] = A;
    ws[OFF_SCANB + tid] = Bv;
}

__global__ void k_scan2(float* ws){
    int ch = blockIdx.x * 256 + threadIdx.x;
    if (ch >= 4800) return;
    float c = 0.f;
    for (int j = 0; j < 40; j++) {
        ws[OFF_CST + (size_t)j * 4800 + ch] = c;
        c = ws[OFF_SCANA + (size_t)j * 4800 + ch] * c + ws[OFF_SCANB + (size_t)j * 4800 + ch];
    }
}

__global__ void k_scan3(float* ws){
    int tid = blockIdx.x * 256 + threadIdx.x;
    if (tid >= 192000) return;
    int c = tid / 4800, ch = tid % 4800;
    int b = ch / 300, d = ch % 300;
    size_t base = (size_t)b * 2000 * 300 + d;
    float cc = ws[OFF_CST + tid];
    int t0 = c * 50;
    for (int k = 0; k < 50; k++) {
        size_t ix = base + (size_t)(t0 + k) * 300;
        float g = ws[OFF_GATE + ix], zz = ws[OFF_R2 + ix];
        cc = g * cc + (1.f - g) * zz;
        ws[OFF_R2 + ix] = cc;   // cs in place of z
    }
}

// ---------------- o matvec fused with enc = tanh(o)*cs, 16-row tiles ----------------
__global__ __launch_bounds__(256) void k_oenc(float* ws, const float* bo){
    int row0 = blockIdx.x * 16;
    __shared__ float X[16 * 300];
    int tid = threadIdx.x;
    for (int i = tid; i < 4800; i += 256) X[i] = ws[OFF_ART + (size_t)row0 * 300 + i];
    __syncthreads();

    int wave = tid >> 6, lane = tid & 63;
    int r0 = wave * 4;
    float acc[5][4];
    #pragma unroll
    for (int c = 0; c < 5; c++)
        #pragma unroll
        for (int j = 0; j < 4; j++) acc[c][j] = 0.f;

    const float* W = ws + OFF_WT + (size_t)6 * 90000;   // Wo
    #pragma unroll 2
    for (int d = 0; d < 300; d++) {
        float xv[4];
        #pragma unroll
        for (int j = 0; j < 4; j++) xv[j] = X[(r0 + j) * 300 + d];
        const float* Wrow = W + d * 300;
        #pragma unroll
        for (int c = 0; c < 5; c++) {
            int e = c * 64 + lane;
            float wv = (c < 4 || e < 300) ? Wrow[e] : 0.f;
            #pragma unroll
            for (int j = 0; j < 4; j++) acc[c][j] = fmaf(xv[j], wv, acc[c][j]);
        }
    }
    #pragma unroll
    for (int c = 0; c < 5; c++) {
        int e = c * 64 + lane;
        if (e < 300) {
            float bv = bo[e];
            #pragma unroll
            for (int j = 0; j < 4; j++) {
                size_t idx = OFF_R2 + (size_t)(row0 + r0 + j) * 300 + e;
                ws[idx] = tanhf(acc[c][j] + bv) * ws[idx];
            }
        }
    }
}

// ---------------- key projections ----------------
__global__ __launch_bounds__(320) void k_keys(float* ws, const float* f1W, const float* f1b,
                                              const float* f2W, const float* f2b,
                                              const float* f3W, const float* f3b){
    int rid = blockIdx.x;
    const float* src; const float* W; const float* bias; float* out;
    if (rid < 480)       { src = ws + OFF_QEMB + (size_t)rid * 300;               W = f1W; bias = f1b; out = ws + OFF_KEYSQ + (size_t)rid * 300; }
    else if (rid < 1504) { int rr = rid - 480;  src = ws + OFF_OPTE + (size_t)rr * 300; W = f2W; bias = f2b; out = ws + OFF_KEYS2 + (size_t)rr * 300; }
    else                 { int rr = rid - 1504; src = ws + OFF_OPTE + (size_t)rr * 300; W = f3W; bias = f3b; out = ws + OFF_KEYS3 + (size_t)rr * 300; }
    __shared__ float X[300];
    int tid = threadIdx.x;
    for (int i = tid; i < 300; i += 320) X[i] = src[i];
    __syncthreads();
    if (tid < 300) {
        float acc = bias[tid];
        const float* wr = W + (size_t)tid * 300;
        for (int d = 0; d < 300; d++) acc += X[d] * wr[d];
        out[tid] = acc;
    }
}

// ---------------- fused attention: aoq tile in LDS, then 8 option combos ----------------
__global__ __launch_bounds__(256) void k_attn(float* ws){
    int tile = blockIdx.x, b = blockIdx.y;
    int t0 = tile * 32;
    __shared__ __align__(16) float Xe[32 * 300];   // enc tile -> aoq tile (in place)
    __shared__ __align__(16) float Kb[30 * 300];   // f1-keys -> Q -> option keys (reused)
    __shared__ float S[32 * 30];                   // scores (also used 32x16)
    int tid = threadIdx.x;
    int lim = (2000 - t0 < 32) ? (2000 - t0) : 32;

    for (int i = tid; i < 9600; i += 256) {
        int r = i / 300; int t = t0 + r;
        Xe[i] = (t < 2000) ? ws[OFF_R2 + ((size_t)b * 2000 + t) * 300 + (i % 300)] : 0.f;
    }
    for (int i = tid; i < 9000; i += 256) Kb[i] = ws[OFF_KEYSQ + (size_t)b * 9000 + i];
    __syncthreads();

    // S1 = Xe . f1keys
    for (int p = tid; p < 960; p += 256) {
        int tl = p / 30, w = p % 30;
        const float4* xr = (const float4*)&Xe[tl * 300];
        const float4* kr = (const float4*)&Kb[w * 300];
        float acc = 0.f;
        #pragma unroll 5
        for (int q = 0; q < 75; q++) {
            float4 a = xr[q], kk = kr[q];
            acc += a.x * kk.x + a.y * kk.y + a.z * kk.z + a.w * kk.w;
        }
        S[tl * 30 + w] = acc;
    }
    __syncthreads();
    // restage Kb <- Q while 32 threads softmax S1 rows
    for (int i = tid; i < 9000; i += 256) Kb[i] = ws[OFF_QEMB + (size_t)b * 9000 + i];
    if (tid < 32) {
        float m = -1e30f;
        for (int w = 0; w < 30; w++) m = fmaxf(m, S[tid * 30 + w]);
        float s = 0.f;
        for (int w = 0; w < 30; w++) { float e = expf(S[tid * 30 + w] - m); S[tid * 30 + w] = e; s += e; }
        float inv = 1.f / s;
        for (int w = 0; w < 30; w++) S[tid * 30 + w] *= inv;
    }
    __syncthreads();
    // aoq = S1 . Q, written over Xe (aoq doesn't read Xe)
    for (int idx = tid; idx < 9600; idx += 256) {
        int tl = idx / 300, e = idx % 300;
        float acc = 0.f;
        #pragma unroll 6
        for (int w = 0; w < 30; w++) acc += S[tl * 30 + w] * Kb[w * 300 + e];
        Xe[idx] = acc;
    }
    __syncthreads();

    // 8 combos: f2/f3 keys x 4 options
    for (int combo = 0; combo < 8; combo++) {
        int opt = combo & 3; bool f3 = combo >= 4;
        size_t kbase = (f3 ? OFF_KEYS3 : OFF_KEYS2) + ((size_t)opt * 256 + (size_t)b * 16) * 300;
        for (int i = tid; i < 4800; i += 256) Kb[i] = ws[kbase + i];
        __syncthreads();
        for (int p = tid; p < 512; p += 256) {
            int tl = p / 16, w = p % 16;
            const float4* xr = (const float4*)&Xe[tl * 300];
            const float4* kr = (const float4*)&Kb[w * 300];
            float acc = 0.f;
            #pragma unroll 5
            for (int q = 0; q < 75; q++) {
                float4 a = xr[q], kk = kr[q];
                acc += a.x * kk.x + a.y * kk.y + a.z * kk.z + a.w * kk.w;
            }
            S[tl * 16 + w] = acc;
        }
        __syncthreads();
        if (tid < 32) {
            float m = -1e30f;
            for (int w = 0; w < 16; w++) m = fmaxf(m, S[tid * 16 + w]);
            float s = 0.f;
            for (int w = 0; w < 16; w++) { float e = expf(S[tid * 16 + w] - m); S[tid * 16 + w] = e; s += e; }
            float inv = 1.f / s;
            for (int w = 0; w < 16; w++) S[tid * 16 + w] *= inv;
        }
        __syncthreads();
        if (tid < 16) {
            float s = 0.f;
            for (int tl = 0; tl < lim; tl++) s += S[tl * 16 + tid];
            ws[OFF_PART + (((size_t)combo * 16 + b) * 63 + tile) * 16 + tid] = s;
        }
        __syncthreads();
    }
}

// ---------------- final: reduce PART, (2D)->75->1 ----------------
__global__ __launch_bounds__(256) void k_final(float* ws, const float* as1W, const float* as1b,
                                               const float* as2W, const float* as2b, float* out){
    int blk = blockIdx.x; int o = blk >> 4, b = blk & 15;
    __shared__ float vec[600]; __shared__ float cm[32]; __shared__ float hb[80];
    int tid = threadIdx.x;
    if (tid < 32) {
        int half = tid / 16, wk = tid % 16;
        int combo = half ? (4 + o) : o;
        float s = 0.f;
        size_t base = OFF_PART + (((size_t)combo * 16 + b) * 63) * 16 + wk;
        for (int t = 0; t < 63; t++) s += ws[base + (size_t)t * 16];
        cm[tid] = s * (1.f / 2000.f);
    }
    __syncthreads();
    const float* oe = ws + OFF_OPTE + ((size_t)o * 256 + (size_t)b * 16) * 300;
    for (int idx = tid; idx < 600; idx += 256) {
        int half = idx / 300, e = idx % 300;
        float acc = 0.f;
        for (int w = 0; w < 16; w++) acc += cm[half * 16 + w] * oe[(size_t)w * 300 + e];
        vec[idx] = acc;
    }
    __syncthreads();
    if (tid < 75) {
        float acc = as1b[tid];
        for (int m = 0; m < 600; m++) acc += vec[m] * as1W[(size_t)tid * 600 + m];
        hb[tid] = fmaxf(acc, 0.f);
    }
    __syncthreads();
    if (tid == 0) {
        float s = as2b[0];
        for (int j = 0; j < 75; j++) s += hb[j] * as2W[j];
        out[b * 4 + o] = s;
    }
}

extern "C" void kernel_launch(void* const* d_in, const int* in_sizes, int n_in,
                              void* d_out, int out_size, void* d_ws, size_t ws_size,
                              hipStream_t stream) {
    float* ws = (float*)d_ws;
    const int* o1 = (const int*)d_in[0];
    const int* o2 = (const int*)d_in[1];
    const int* o3 = (const int*)d_in[2];
    const int* o4 = (const int*)d_in[3];
    const int* qin = (const int*)d_in[4];
    const int* ain = (const int*)d_in[5];
    const float* emb  = (const float*)d_in[6];
    const float* ceW  = (const float*)d_in[7];
    const float* ceb  = (const float*)d_in[8];
    const float* m1W  = (const float*)d_in[9];
    const float* m1b  = (const float*)d_in[10];
    const float* m2W  = (const float*)d_in[11];
    const float* m2b  = (const float*)d_in[12];
    const float* Wz   = (const float*)d_in[13];
    const float* bz   = (const float*)d_in[14];
    const float* Wo   = (const float*)d_in[15];
    const float* bo   = (const float*)d_in[16];
    const float* f1W  = (const float*)d_in[17];
    const float* f1b  = (const float*)d_in[18];
    const float* f2W  = (const float*)d_in[19];
    const float* f2b  = (const float*)d_in[20];
    const float* f3W  = (const float*)d_in[21];
    const float* f3b  = (const float*)d_in[22];
    const float* as1W = (const float*)d_in[23];
    const float* as1b = (const float*)d_in[24];
    const float* as2W = (const float*)d_in[25];
    const float* as2b = (const float*)d_in[26];

    k_pack<<<(630000 + 255) / 256, 256, 0, stream>>>(ws, ceW, Wz, Wo);
    k_gather<<<(10051200 + 255) / 256, 256, 0, stream>>>(ws, emb, ain, qin, o1, o2, o3, o4);
    k_ce_coarse<<<1780, 256, 0, stream>>>(ws, ceb);
    k_fused<<<2000, 256, 0, stream>>>(ws, ceb, m1W, m1b, m2W, m2b, bz);
    k_scan1<<<750, 256, 0, stream>>>(ws);
    k_scan2<<<19, 256, 0, stream>>>(ws);
    k_scan3<<<750, 256, 0, stream>>>(ws);
    k_oenc<<<2000, 256, 0, stream>>>(ws, bo);
    k_keys<<<2528, 320, 0, stream>>>(ws, f1W, f1b, f2W, f2b, f3W, f3b);
    k_attn<<<dim3(63, 16), 256, 0, stream>>>(ws);
    k_final<<<64, 256, 0, stream>>>(ws, as1W, as1b, as2W, as2b, (float*)d_out);
}

// Round 4
// 952.077 us; speedup vs baseline: 1.3033x; 1.1377x over previous
//
#include <hip/hip_runtime.h>
#include <math.h>

typedef unsigned short ushortT;
typedef short bf8 __attribute__((ext_vector_type(8)));
typedef float f32x4 __attribute__((ext_vector_type(4)));

__device__ __forceinline__ float bf2f(ushortT u){
    union { unsigned int i; float f; } v; v.i = ((unsigned int)u) << 16; return v.f;
}
__device__ __forceinline__ ushortT f2bf(float f){
    union { float f; unsigned int i; } v; v.f = f;
    unsigned int x = v.i;
    return (ushortT)((x + 0x7fffu + ((x >> 16) & 1u)) >> 16);
}

// B=16, T=2000, D=300, TQ=30, TOPT=16, ranges {1,2,4,10,25}; all fp32 I/O.
// Matvecs run on bf16-split MFMA (xh*wh + xh*wl + xl*wh ~ fp32 precision).

// ---------------- workspace layout (float indices), ~159.8 MB ----------------
constexpr size_t OFF_ART   = 0;           // 9,600,000  article embeddings
constexpr size_t OFF_R2    = 9600000;     // 9,600,000  z -> cs -> enc
constexpr size_t OFF_GATE  = 19200000;    // 9,600,000  gate
constexpr size_t OFF_HC    = 28800000;    // 8,544,000  coarse CE outputs
constexpr size_t OFF_WB    = 37344000;    //   680,960 f32 = 1,361,920 bf16 B-fragments
constexpr size_t OFF_QEMB  = 38024960;    //   144,000
constexpr size_t OFF_KEYSQ = 38168960;    //   144,000
constexpr size_t OFF_OPTE  = 38312960;    //   307,200
constexpr size_t OFF_KEYS2 = 38620160;    //   307,200
constexpr size_t OFF_KEYS3 = 38927360;    //   307,200
constexpr size_t OFF_SCANA = 39234560;    //   192,000
constexpr size_t OFF_SCANB = 39426560;    //   192,000
constexpr size_t OFF_CST   = 39618560;    //   192,000
constexpr size_t OFF_PART  = 39810560;    //   129,024
// end = 39,939,584 floats

// HC rows: r2 [0,16000)=b*1000+g | r4 [16000,24000)=b*500+g
//          r10 [24000,27200)=b*200+g | r25 [27200,28480)=b*80+g

// WB layout (ushort units): ((mp + kt)*19 + nt)*512 + lane*8 + j
//   mp = matrix*20 + part*10;  matrix: 0..4 ce, 5 Wz, 6 Wo; part: 0 hi, 1 lo
//   value = bf16 part of W^T[d = kt*32 + (lane>>4)*8 + j][e = nt*16 + (lane&15)]

__global__ void k_pack(float* ws, const float* ceW, const float* Wz, const float* Wo){
    int id = blockIdx.x * 256 + threadIdx.x;
    if (id >= 680960) return;          // 7 * 97280
    int m = id / 97280; int rr = id % 97280;
    int kt = rr / 9728; rr %= 9728;    // 19*512
    int nt = rr / 512;  rr %= 512;
    int lane = rr / 8; int j = rr % 8;
    int d = kt * 32 + (lane >> 4) * 8 + j;
    int e = nt * 16 + (lane & 15);
    float w = 0.f;
    if (d < 300 && e < 300) {
        const float* src = (m < 5) ? (ceW + (size_t)m * 90000) : (m == 5 ? Wz : Wo);
        w = src[(size_t)e * 300 + d];
    }
    ushortT hi = f2bf(w);
    ushortT lo = f2bf(w - bf2f(hi));
    ushortT* wb = (ushortT*)(ws + OFF_WB);
    wb[((size_t)(m * 20 + kt) * 19 + nt) * 512 + lane * 8 + j] = hi;
    wb[((size_t)(m * 20 + 10 + kt) * 19 + nt) * 512 + lane * 8 + j] = lo;
}

__device__ __forceinline__ bf8 load_bfrag(const ushortT* wb, int mp, int kt, int nt, int lane){
    return *(const bf8*)(wb + (((size_t)(mp + kt) * 19 + nt) * 512 + lane * 8));
}

// Convert one row's K-slices from LDS X (stride 324, zero-padded to 320) to hi/lo frags
__device__ __forceinline__ void prep_afrags(const float* X, int lane, bf8* Ah, bf8* Al){
    int mrow = lane & 15, quad = lane >> 4;
    #pragma unroll
    for (int kt = 0; kt < 10; kt++) {
        const float* xp = &X[mrow * 324 + kt * 32 + quad * 8];
        float4 x0 = *(const float4*)xp;
        float4 x1 = *(const float4*)(xp + 4);
        float xv[8] = {x0.x, x0.y, x0.z, x0.w, x1.x, x1.y, x1.z, x1.w};
        bf8 h, l;
        #pragma unroll
        for (int j = 0; j < 8; j++) {
            ushortT hh = f2bf(xv[j]);
            h[j] = (short)hh;
            l[j] = (short)f2bf(xv[j] - bf2f(hh));
        }
        Ah[kt] = h; Al[kt] = l;
    }
}

// ---------------- float4 embedding gathers ----------------
__global__ void k_gather(float* ws, const float* emb, const int* art_in, const int* q_in,
                         const int* o1, const int* o2, const int* o3, const int* o4){
    size_t id = (size_t)blockIdx.x * 256 + threadIdx.x;
    const float4* embv = (const float4*)emb;
    if (id < 2400000) {                       // article: 32000 rows x 75 f4
        size_t row = id / 75; int wi = (int)(id % 75);
        ((float4*)(ws + OFF_ART))[id] = embv[(size_t)art_in[row] * 75 + wi];
    } else if (id < 2436000) {                // question: 480 rows
        size_t i2 = id - 2400000; size_t row = i2 / 75; int wi = (int)(i2 % 75);
        ((float4*)(ws + OFF_QEMB))[i2] = embv[(size_t)q_in[row] * 75 + wi];
    } else if (id < 2512800) {                // options: 1024 rows = opt*256+b*16+w
        size_t i3 = id - 2436000; size_t row = i3 / 75; int wi = (int)(i3 % 75);
        int opt = (int)(row / 256); int rr = (int)(row % 256);
        const int* op = (opt == 0) ? o1 : (opt == 1) ? o2 : (opt == 2) ? o3 : o4;
        ((float4*)(ws + OFF_OPTE))[i3] = embv[(size_t)op[rr] * 75 + wi];
    }
}

// ---------------- coarse CE (r=2,4,10,25): group-sum stage + MFMA ----------------
// blocks: [0,1000) r=2 | [1000,1500) r=4 | [1500,1700) r=10 | [1700,1780) r=25
__global__ __launch_bounds__(256) void k_ce_coarse(float* ws, const float* ceb){
    int gb = blockIdx.x;
    int rng, rows0, wi, sb, bdiv;
    if (gb < 1000)      { rng = 2;  rows0 = 0;     wi = 1; sb = 0;    bdiv = 1000; }
    else if (gb < 1500) { rng = 4;  rows0 = 16000; wi = 2; sb = 1000; bdiv = 500; }
    else if (gb < 1700) { rng = 10; rows0 = 24000; wi = 3; sb = 1500; bdiv = 200; }
    else                { rng = 25; rows0 = 27200; wi = 4; sb = 1700; bdiv = 80;  }
    int rowLocal0 = (gb - sb) * 16;

    __shared__ float X[16 * 324];
    int tid = threadIdx.x;
    for (int i = tid; i < 16 * 324; i += 256) {
        int rl = i / 324, d = i % 324;
        float s = 0.f;
        if (d < 300) {
            int R = rowLocal0 + rl;
            int bb = R / bdiv, gg = R % bdiv;
            size_t base = OFF_ART + ((size_t)bb * 2000 + (size_t)gg * rng) * 300 + d;
            for (int j = 0; j < rng; j++) s += ws[base + (size_t)j * 300];
        }
        X[i] = s;
    }
    __syncthreads();

    int lane = tid & 63, wave = tid >> 6;
    int mrow = lane & 15, quad = lane >> 4;
    bf8 Ah[10], Al[10];
    prep_afrags(X, lane, Ah, Al);

    const ushortT* wb = (const ushortT*)(ws + OFF_WB);
    int mpH = wi * 20, mpL = wi * 20 + 10;
    for (int nt = wave; nt < 19; nt += 4) {
        f32x4 acc = {0.f, 0.f, 0.f, 0.f};
        #pragma unroll
        for (int kt = 0; kt < 10; kt++) {
            bf8 Bh = load_bfrag(wb, mpH, kt, nt, lane);
            bf8 Bl = load_bfrag(wb, mpL, kt, nt, lane);
            acc = __builtin_amdgcn_mfma_f32_16x16x32_bf16(Ah[kt], Bh, acc, 0, 0, 0);
            acc = __builtin_amdgcn_mfma_f32_16x16x32_bf16(Ah[kt], Bl, acc, 0, 0, 0);
            acc = __builtin_amdgcn_mfma_f32_16x16x32_bf16(Al[kt], Bh, acc, 0, 0, 0);
        }
        int e = nt * 16 + mrow;
        if (e < 300) {
            float bv = ceb[wi * 300 + e];
            #pragma unroll
            for (int q = 0; q < 4; q++) {
                int mm = quad * 4 + q;
                ws[OFF_HC + (size_t)(rows0 + rowLocal0 + mm) * 300 + e] = fmaxf(acc[q] + bv, 0.f);
            }
        }
    }
}

// ---------------- fused: ce0 + Wz MFMA (shared A-frags) + gate MLP epilogue ----------------
__global__ __launch_bounds__(256) void k_fused(float* ws, const float* ceb,
                                               const float* m1W, const float* m1b,
                                               const float* m2W, const float* m2b,
                                               const float* bz){
    int row0 = blockIdx.x * 16;
    __shared__ float X[16 * 324];
    int tid = threadIdx.x;
    for (int v = tid; v < 1200; v += 256) {
        int rl = v / 75, dc = (v % 75) * 4;
        *(float4*)&X[rl * 324 + dc] = *(const float4*)&ws[OFF_ART + (size_t)row0 * 300 + (size_t)v * 4];
    }
    for (int i = tid; i < 16 * 24; i += 256) X[(i / 24) * 324 + 300 + (i % 24)] = 0.f;
    __syncthreads();

    float w1[3][5], b1[3], w2[3], b2;
    #pragma unroll
    for (int k = 0; k < 3; k++) {
        #pragma unroll
        for (int i = 0; i < 5; i++) w1[k][i] = m1W[k * 5 + i];
        b1[k] = m1b[k]; w2[k] = m2W[k];
    }
    b2 = m2b[0];

    int lane = tid & 63, wave = tid >> 6;
    int mrow = lane & 15, quad = lane >> 4;
    bf8 Ah[10], Al[10];
    prep_afrags(X, lane, Ah, Al);

    const ushortT* wb = (const ushortT*)(ws + OFF_WB);
    for (int nt = wave; nt < 19; nt += 4) {
        f32x4 accA = {0.f, 0.f, 0.f, 0.f};
        f32x4 accZ = {0.f, 0.f, 0.f, 0.f};
        #pragma unroll
        for (int kt = 0; kt < 10; kt++) {
            bf8 B0h = load_bfrag(wb, 0,   kt, nt, lane);
            bf8 B0l = load_bfrag(wb, 10,  kt, nt, lane);
            bf8 B5h = load_bfrag(wb, 100, kt, nt, lane);
            bf8 B5l = load_bfrag(wb, 110, kt, nt, lane);
            accA = __builtin_amdgcn_mfma_f32_16x16x32_bf16(Ah[kt], B0h, accA, 0, 0, 0);
            accZ = __builtin_amdgcn_mfma_f32_16x16x32_bf16(Ah[kt], B5h, accZ, 0, 0, 0);
            accA = __builtin_amdgcn_mfma_f32_16x16x32_bf16(Ah[kt], B0l, accA, 0, 0, 0);
            accZ = __builtin_amdgcn_mfma_f32_16x16x32_bf16(Ah[kt], B5l, accZ, 0, 0, 0);
            accA = __builtin_amdgcn_mfma_f32_16x16x32_bf16(Al[kt], B0h, accA, 0, 0, 0);
            accZ = __builtin_amdgcn_mfma_f32_16x16x32_bf16(Al[kt], B5h, accZ, 0, 0, 0);
        }
        int e = nt * 16 + mrow;
        if (e < 300) {
            float cebe = ceb[e], bze = bz[e];
            #pragma unroll
            for (int q = 0; q < 4; q++) {
                int row = row0 + quad * 4 + q;
                int bb = row / 2000, t = row % 2000;
                size_t c1 = OFF_HC + ((size_t)bb * 1000 + t / 2) * 300;
                size_t c2 = OFF_HC + (16000 + (size_t)bb * 500 + t / 4) * 300;
                size_t c3 = OFF_HC + (24000 + (size_t)bb * 200 + t / 10) * 300;
                size_t c4 = OFF_HC + (27200 + (size_t)bb * 80 + t / 25) * 300;
                float y0 = fmaxf(accA[q] + cebe, 0.f);
                float y1 = ws[c1 + e] * 0.5f;
                float y2 = ws[c2 + e] * 0.25f;
                float y3 = ws[c3 + e] * 0.1f;
                float y4 = ws[c4 + e] * 0.04f;
                float gacc = b2;
                #pragma unroll
                for (int k = 0; k < 3; k++) {
                    float a = b1[k] + y0 * w1[k][0] + y1 * w1[k][1] + y2 * w1[k][2]
                            + y3 * w1[k][3] + y4 * w1[k][4];
                    gacc += fmaxf(a, 0.f) * w2[k];
                }
                ws[OFF_GATE + (size_t)row * 300 + e] = fmaxf(gacc, 0.f);
                ws[OFF_R2 + (size_t)row * 300 + e] = tanhf(accZ[q] + bze);
            }
        }
    }
}

// ---------------- MRU scan: 40 chunks x 50 steps ----------------
__global__ void k_scan1(float* ws){
    int tid = blockIdx.x * 256 + threadIdx.x;
    if (tid >= 192000) return;
    int c = tid / 4800, ch = tid % 4800;
    int b = ch / 300, d = ch % 300;
    size_t base = (size_t)b * 2000 * 300 + d;
    float A = 1.f, Bv = 0.f;
    int t0 = c * 50;
    for (int k = 0; k < 50; k++) {
        size_t ix = base + (size_t)(t0 + k) * 300;
        float g = ws[OFF_GATE + ix], zz = ws[OFF_R2 + ix];
        Bv = g * Bv + (1.f - g) * zz;
        A *= g;
    }
    ws[OFF_SCANA + tid] = A;
    ws[OFF_SCANB + tid] = Bv;
}

__global__ void k_scan2(float* ws){
    int ch = blockIdx.x * 256 + threadIdx.x;
    if (ch >= 4800) return;
    float c = 0.f;
    for (int j = 0; j < 40; j++) {
        ws[OFF_CST + (size_t)j * 4800 + ch] = c;
        c = ws[OFF_SCANA + (size_t)j * 4800 + ch] * c + ws[OFF_SCANB + (size_t)j * 4800 + ch];
    }
}

__global__ void k_scan3(float* ws){
    int tid = blockIdx.x * 256 + threadIdx.x;
    if (tid >= 192000) return;
    int c = tid / 4800, ch = tid % 4800;
    int b = ch / 300, d = ch % 300;
    size_t base = (size_t)b * 2000 * 300 + d;
    float cc = ws[OFF_CST + tid];
    int t0 = c * 50;
    for (int k = 0; k < 50; k++) {
        size_t ix = base + (size_t)(t0 + k) * 300;
        float g = ws[OFF_GATE + ix], zz = ws[OFF_R2 + ix];
        cc = g * cc + (1.f - g) * zz;
        ws[OFF_R2 + ix] = cc;   // cs in place of z
    }
}

// ---------------- Wo MFMA fused with enc = tanh(o)*cs (in place) ----------------
__global__ __launch_bounds__(256) void k_oenc(float* ws, const float* bo){
    int row0 = blockIdx.x * 16;
    __shared__ float X[16 * 324];
    int tid = threadIdx.x;
    for (int v = tid; v < 1200; v += 256) {
        int rl = v / 75, dc = (v % 75) * 4;
        *(float4*)&X[rl * 324 + dc] = *(const float4*)&ws[OFF_ART + (size_t)row0 * 300 + (size_t)v * 4];
    }
    for (int i = tid; i < 16 * 24; i += 256) X[(i / 24) * 324 + 300 + (i % 24)] = 0.f;
    __syncthreads();

    int lane = tid & 63, wave = tid >> 6;
    int mrow = lane & 15, quad = lane >> 4;
    bf8 Ah[10], Al[10];
    prep_afrags(X, lane, Ah, Al);

    const ushortT* wb = (const ushortT*)(ws + OFF_WB);
    for (int nt = wave; nt < 19; nt += 4) {
        f32x4 acc = {0.f, 0.f, 0.f, 0.f};
        #pragma unroll
        for (int kt = 0; kt < 10; kt++) {
            bf8 Bh = load_bfrag(wb, 120, kt, nt, lane);
            bf8 Bl = load_bfrag(wb, 130, kt, nt, lane);
            acc = __builtin_amdgcn_mfma_f32_16x16x32_bf16(Ah[kt], Bh, acc, 0, 0, 0);
            acc = __builtin_amdgcn_mfma_f32_16x16x32_bf16(Ah[kt], Bl, acc, 0, 0, 0);
            acc = __builtin_amdgcn_mfma_f32_16x16x32_bf16(Al[kt], Bh, acc, 0, 0, 0);
        }
        int e = nt * 16 + mrow;
        if (e < 300) {
            float bv = bo[e];
            #pragma unroll
            for (int q = 0; q < 4; q++) {
                size_t idx = OFF_R2 + (size_t)(row0 + quad * 4 + q) * 300 + e;
                ws[idx] = tanhf(acc[q] + bv) * ws[idx];
            }
        }
    }
}

// ---------------- key projections ----------------
__global__ __launch_bounds__(320) void k_keys(float* ws, const float* f1W, const float* f1b,
                                              const float* f2W, const float* f2b,
                                              const float* f3W, const float* f3b){
    int rid = blockIdx.x;
    const float* src; const float* W; const float* bias; float* out;
    if (rid < 480)       { src = ws + OFF_QEMB + (size_t)rid * 300;               W = f1W; bias = f1b; out = ws + OFF_KEYSQ + (size_t)rid * 300; }
    else if (rid < 1504) { int rr = rid - 480;  src = ws + OFF_OPTE + (size_t)rr * 300; W = f2W; bias = f2b; out = ws + OFF_KEYS2 + (size_t)rr * 300; }
    else                 { int rr = rid - 1504; src = ws + OFF_OPTE + (size_t)rr * 300; W = f3W; bias = f3b; out = ws + OFF_KEYS3 + (size_t)rr * 300; }
    __shared__ float X[300];
    int tid = threadIdx.x;
    for (int i = tid; i < 300; i += 320) X[i] = src[i];
    __syncthreads();
    if (tid < 300) {
        float acc = bias[tid];
        const float* wr = W + (size_t)tid * 300;
        for (int d = 0; d < 300; d++) acc += X[d] * wr[d];
        out[tid] = acc;
    }
}

// ---------------- fused attention: aoq tile in LDS, then 8 option combos ----------------
__global__ __launch_bounds__(256) void k_attn(float* ws){
    int tile = blockIdx.x, b = blockIdx.y;
    int t0 = tile * 32;
    __shared__ __align__(16) float Xe[32 * 300];
    __shared__ __align__(16) float Kb[30 * 300];
    __shared__ float S[32 * 30];
    int tid = threadIdx.x;
    int lim = (2000 - t0 < 32) ? (2000 - t0) : 32;

    for (int i = tid; i < 9600; i += 256) {
        int r = i / 300; int t = t0 + r;
        Xe[i] = (t < 2000) ? ws[OFF_R2 + ((size_t)b * 2000 + t) * 300 + (i % 300)] : 0.f;
    }
    for (int i = tid; i < 9000; i += 256) Kb[i] = ws[OFF_KEYSQ + (size_t)b * 9000 + i];
    __syncthreads();

    for (int p = tid; p < 960; p += 256) {
        int tl = p / 30, w = p % 30;
        const float4* xr = (const float4*)&Xe[tl * 300];
        const float4* kr = (const float4*)&Kb[w * 300];
        float acc = 0.f;
        #pragma unroll 5
        for (int q = 0; q < 75; q++) {
            float4 a = xr[q], kk = kr[q];
            acc += a.x * kk.x + a.y * kk.y + a.z * kk.z + a.w * kk.w;
        }
        S[tl * 30 + w] = acc;
    }
    __syncthreads();
    for (int i = tid; i < 9000; i += 256) Kb[i] = ws[OFF_QEMB + (size_t)b * 9000 + i];
    if (tid < 32) {
        float m = -1e30f;
        for (int w = 0; w < 30; w++) m = fmaxf(m, S[tid * 30 + w]);
        float s = 0.f;
        for (int w = 0; w < 30; w++) { float e = expf(S[tid * 30 + w] - m); S[tid * 30 + w] = e; s += e; }
        float inv = 1.f / s;
        for (int w = 0; w < 30; w++) S[tid * 30 + w] *= inv;
    }
    __syncthreads();
    for (int idx = tid; idx < 9600; idx += 256) {
        int tl = idx / 300, e = idx % 300;
        float acc = 0.f;
        #pragma unroll 6
        for (int w = 0; w < 30; w++) acc += S[tl * 30 + w] * Kb[w * 300 + e];
        Xe[idx] = acc;
    }
    __syncthreads();

    for (int combo = 0; combo < 8; combo++) {
        int opt = combo & 3; bool f3 = combo >= 4;
        size_t kbase = (f3 ? OFF_KEYS3 : OFF_KEYS2) + ((size_t)opt * 256 + (size_t)b * 16) * 300;
        for (int i = tid; i < 4800; i += 256) Kb[i] = ws[kbase + i];
        __syncthreads();
        for (int p = tid; p < 512; p += 256) {
            int tl = p / 16, w = p % 16;
            const float4* xr = (const float4*)&Xe[tl * 300];
            const float4* kr = (const float4*)&Kb[w * 300];
            float acc = 0.f;
            #pragma unroll 5
            for (int q = 0; q < 75; q++) {
                float4 a = xr[q], kk = kr[q];
                acc += a.x * kk.x + a.y * kk.y + a.z * kk.z + a.w * kk.w;
            }
            S[tl * 16 + w] = acc;
        }
        __syncthreads();
        if (tid < 32) {
            float m = -1e30f;
            for (int w = 0; w < 16; w++) m = fmaxf(m, S[tid * 16 + w]);
            float s = 0.f;
            for (int w = 0; w < 16; w++) { float e = expf(S[tid * 16 + w] - m); S[tid * 16 + w] = e; s += e; }
            float inv = 1.f / s;
            for (int w = 0; w < 16; w++) S[tid * 16 + w] *= inv;
        }
        __syncthreads();
        if (tid < 16) {
            float s = 0.f;
            for (int tl = 0; tl < lim; tl++) s += S[tl * 16 + tid];
            ws[OFF_PART + (((size_t)combo * 16 + b) * 63 + tile) * 16 + tid] = s;
        }
        __syncthreads();
    }
}

// ---------------- final: reduce PART, (2D)->75->1 ----------------
__global__ __launch_bounds__(256) void k_final(float* ws, const float* as1W, const float* as1b,
                                               const float* as2W, const float* as2b, float* out){
    int blk = blockIdx.x; int o = blk >> 4, b = blk & 15;
    __shared__ float vec[600]; __shared__ float cm[32]; __shared__ float hb[80];
    int tid = threadIdx.x;
    if (tid < 32) {
        int half = tid / 16, wk = tid % 16;
        int combo = half ? (4 + o) : o;
        float s = 0.f;
        size_t base = OFF_PART + (((size_t)combo * 16 + b) * 63) * 16 + wk;
        for (int t = 0; t < 63; t++) s += ws[base + (size_t)t * 16];
        cm[tid] = s * (1.f / 2000.f);
    }
    __syncthreads();
    const float* oe = ws + OFF_OPTE + ((size_t)o * 256 + (size_t)b * 16) * 300;
    for (int idx = tid; idx < 600; idx += 256) {
        int half = idx / 300, e = idx % 300;
        float acc = 0.f;
        for (int w = 0; w < 16; w++) acc += cm[half * 16 + w] * oe[(size_t)w * 300 + e];
        vec[idx] = acc;
    }
    __syncthreads();
    if (tid < 75) {
        float acc = as1b[tid];
        for (int m = 0; m < 600; m++) acc += vec[m] * as1W[(size_t)tid * 600 + m];
        hb[tid] = fmaxf(acc, 0.f);
    }
    __syncthreads();
    if (tid == 0) {
        float s = as2b[0];
        for (int j = 0; j < 75; j++) s += hb[j] * as2W[j];
        out[b * 4 + o] = s;
    }
}

extern "C" void kernel_launch(void* const* d_in, const int* in_sizes, int n_in,
                              void* d_out, int out_size, void* d_ws, size_t ws_size,
                              hipStream_t stream) {
    float* ws = (float*)d_ws;
    const int* o1 = (const int*)d_in[0];
    const int* o2 = (const int*)d_in[1];
    const int* o3 = (const int*)d_in[2];
    const int* o4 = (const int*)d_in[3];
    const int* qin = (const int*)d_in[4];
    const int* ain = (const int*)d_in[5];
    const float* emb  = (const float*)d_in[6];
    const float* ceW  = (const float*)d_in[7];
    const float* ceb  = (const float*)d_in[8];
    const float* m1W  = (const float*)d_in[9];
    const float* m1b  = (const float*)d_in[10];
    const float* m2W  = (const float*)d_in[11];
    const float* m2b  = (const float*)d_in[12];
    const float* Wz   = (const float*)d_in[13];
    const float* bz   = (const float*)d_in[14];
    const float* Wo   = (const float*)d_in[15];
    const float* bo   = (const float*)d_in[16];
    const float* f1W  = (const float*)d_in[17];
    const float* f1b  = (const float*)d_in[18];
    const float* f2W  = (const float*)d_in[19];
    const float* f2b  = (const float*)d_in[20];
    const float* f3W  = (const float*)d_in[21];
    const float* f3b  = (const float*)d_in[22];
    const float* as1W = (const float*)d_in[23];
    const float* as1b = (const float*)d_in[24];
    const float* as2W = (const float*)d_in[25];
    const float* as2b = (const float*)d_in[26];

    k_pack<<<(680960 + 255) / 256, 256, 0, stream>>>(ws, ceW, Wz, Wo);
    k_gather<<<(2512800 + 255) / 256, 256, 0, stream>>>(ws, emb, ain, qin, o1, o2, o3, o4);
    k_ce_coarse<<<1780, 256, 0, stream>>>(ws, ceb);
    k_fused<<<2000, 256, 0, stream>>>(ws, ceb, m1W, m1b, m2W, m2b, bz);
    k_scan1<<<750, 256, 0, stream>>>(ws);
    k_scan2<<<19, 256, 0, stream>>>(ws);
    k_scan3<<<750, 256, 0, stream>>>(ws);
    k_oenc<<<2000, 256, 0, stream>>>(ws, bo);
    k_keys<<<2528, 320, 0, stream>>>(ws, f1W, f1b, f2W, f2b, f3W, f3b);
    k_attn<<<dim3(63, 16), 256, 0, stream>>>(ws);
    k_final<<<64, 256, 0, stream>>>(ws, as1W, as1b, as2W, as2b, (float*)d_out);
}

// Round 5
// 786.544 us; speedup vs baseline: 1.5776x; 1.2105x over previous
//
#include <hip/hip_runtime.h>
#include <math.h>

typedef unsigned short ushortT;
typedef short bf8 __attribute__((ext_vector_type(8)));
typedef float f32x4 __attribute__((ext_vector_type(4)));

__device__ __forceinline__ float bf2f(ushortT u){
    union { unsigned int i; float f; } v; v.i = ((unsigned int)u) << 16; return v.f;
}
__device__ __forceinline__ ushortT f2bf(float f){
    union { float f; unsigned int i; } v; v.f = f;
    unsigned int x = v.i;
    return (ushortT)((x + 0x7fffu + ((x >> 16) & 1u)) >> 16);
}
__device__ __forceinline__ float4 f4add(float4 a, float4 b){
    return make_float4(a.x + b.x, a.y + b.y, a.z + b.z, a.w + b.w);
}

// B=16, T=2000, D=300, TQ=30, TOPT=16, ranges {1,2,4,10,25}; all fp32 I/O.
// Matvecs run on bf16-split MFMA (xh*wh + xh*wl + xl*wh ~ fp32 precision).

// ---------------- workspace layout (float indices), ~159.8 MB ----------------
constexpr size_t OFF_ART   = 0;           // 9,600,000  article embeddings
constexpr size_t OFF_R2    = 9600000;     // 9,600,000  S5 -> z -> cs -> enc
constexpr size_t OFF_GATE  = 19200000;    // 9,600,000  S2 -> gate
constexpr size_t OFF_HC    = 28800000;    // 8,544,000  coarse CE outputs
constexpr size_t OFF_WB    = 37344000;    //   680,960 f32 = 1,361,920 bf16 B-fragments
constexpr size_t OFF_QEMB  = 38024960;    //   144,000
constexpr size_t OFF_KEYSQ = 38168960;    //   144,000
constexpr size_t OFF_OPTE  = 38312960;    //   307,200
constexpr size_t OFF_KEYS2 = 38620160;    //   307,200
constexpr size_t OFF_KEYS3 = 38927360;    //   307,200
constexpr size_t OFF_SCANA = 39234560;    //   192,000
constexpr size_t OFF_SCANB = 39426560;    //   192,000
constexpr size_t OFF_CST   = 39618560;    //   192,000
constexpr size_t OFF_PART  = 39810560;    //   129,024
// end = 39,939,584 floats

// HC rows: r2 [0,16000)=b*1000+g | r4 [16000,24000)=b*500+g
//          r10 [24000,27200)=b*200+g | r25 [27200,28480)=b*80+g
// S2 (at OFF_GATE): 16000 rows = b*1000+g (pair sums of ART)
// S5 (at OFF_R2):    6400 rows = b*400+g  (5-sums of ART)

// WB layout (ushort units): ((mp + kt)*19 + nt)*512 + lane*8 + j
//   mp = matrix*20 + part*10;  matrix: 0..4 ce, 5 Wz, 6 Wo; part: 0 hi, 1 lo

__global__ void k_pack(float* ws, const float* ceW, const float* Wz, const float* Wo){
    int id = blockIdx.x * 256 + threadIdx.x;
    if (id >= 680960) return;          // 7 * 97280
    int m = id / 97280; int rr = id % 97280;
    int kt = rr / 9728; rr %= 9728;    // 19*512
    int nt = rr / 512;  rr %= 512;
    int lane = rr / 8; int j = rr % 8;
    int d = kt * 32 + (lane >> 4) * 8 + j;
    int e = nt * 16 + (lane & 15);
    float w = 0.f;
    if (d < 300 && e < 300) {
        const float* src = (m < 5) ? (ceW + (size_t)m * 90000) : (m == 5 ? Wz : Wo);
        w = src[(size_t)e * 300 + d];
    }
    ushortT hi = f2bf(w);
    ushortT lo = f2bf(w - bf2f(hi));
    ushortT* wb = (ushortT*)(ws + OFF_WB);
    wb[((size_t)(m * 20 + kt) * 19 + nt) * 512 + lane * 8 + j] = hi;
    wb[((size_t)(m * 20 + 10 + kt) * 19 + nt) * 512 + lane * 8 + j] = lo;
}

__device__ __forceinline__ bf8 load_bfrag(const ushortT* wb, int mp, int kt, int nt, int lane){
    return *(const bf8*)(wb + (((size_t)(mp + kt) * 19 + nt) * 512 + lane * 8));
}

__device__ __forceinline__ void prep_afrags(const float* X, int lane, bf8* Ah, bf8* Al){
    int mrow = lane & 15, quad = lane >> 4;
    #pragma unroll
    for (int kt = 0; kt < 10; kt++) {
        const float* xp = &X[mrow * 324 + kt * 32 + quad * 8];
        float4 x0 = *(const float4*)xp;
        float4 x1 = *(const float4*)(xp + 4);
        float xv[8] = {x0.x, x0.y, x0.z, x0.w, x1.x, x1.y, x1.z, x1.w};
        bf8 h, l;
        #pragma unroll
        for (int j = 0; j < 8; j++) {
            ushortT hh = f2bf(xv[j]);
            h[j] = (short)hh;
            l[j] = (short)f2bf(xv[j] - bf2f(hh));
        }
        Ah[kt] = h; Al[kt] = l;
    }
}

// ---------------- float4 embedding gathers ----------------
__global__ void k_gather(float* ws, const float* emb, const int* art_in, const int* q_in,
                         const int* o1, const int* o2, const int* o3, const int* o4){
    size_t id = (size_t)blockIdx.x * 256 + threadIdx.x;
    const float4* embv = (const float4*)emb;
    if (id < 2400000) {                       // article: 32000 rows x 75 f4
        size_t row = id / 75; int wi = (int)(id % 75);
        ((float4*)(ws + OFF_ART))[id] = embv[(size_t)art_in[row] * 75 + wi];
    } else if (id < 2436000) {                // question: 480 rows
        size_t i2 = id - 2400000; size_t row = i2 / 75; int wi = (int)(i2 % 75);
        ((float4*)(ws + OFF_QEMB))[i2] = embv[(size_t)q_in[row] * 75 + wi];
    } else if (id < 2512800) {                // options: 1024 rows = opt*256+b*16+w
        size_t i3 = id - 2436000; size_t row = i3 / 75; int wi = (int)(i3 % 75);
        int opt = (int)(row / 256); int rr = (int)(row % 256);
        const int* op = (opt == 0) ? o1 : (opt == 1) ? o2 : (opt == 2) ? o3 : o4;
        ((float4*)(ws + OFF_OPTE))[i3] = embv[(size_t)op[rr] * 75 + wi];
    }
}

// ---------------- hierarchical group sums: S2 and S5 from ART ----------------
__global__ void k_s2s5(float* ws){
    size_t id = (size_t)blockIdx.x * 256 + threadIdx.x;
    const float4* art = (const float4*)(ws + OFF_ART);
    if (id < 1200000) {                        // S2: 16000 rows x 75 f4
        size_t row = id / 75; int wi = (int)(id % 75);
        size_t b = row / 1000, g = row % 1000;
        const float4* p = art + ((b * 2000 + g * 2) * 75 + wi);
        ((float4*)(ws + OFF_GATE))[row * 75 + wi] = f4add(p[0], p[75]);
    } else if (id < 1680000) {                 // S5: 6400 rows x 75 f4
        size_t i2 = id - 1200000;
        size_t row = i2 / 75; int wi = (int)(i2 % 75);
        size_t b = row / 400, g = row % 400;
        const float4* p = art + ((b * 2000 + g * 5) * 75 + wi);
        float4 s = f4add(f4add(p[0], p[75]), f4add(p[150], p[225]));
        s = f4add(s, p[300]);
        ((float4*)(ws + OFF_R2))[row * 75 + wi] = s;
    }
}

// ---------------- coarse CE (r=2,4,10,25): unrolled staged sums + MFMA ----------------
// blocks: [0,80) r25 | [80,280) r10 | [280,780) r4 | [780,1780) r2  (heavy first)
__global__ __launch_bounds__(256) void k_ce_coarse(float* ws, const float* ceb){
    int gb = blockIdx.x;
    int kind, rows0, wi, rowLocal0;
    if (gb < 80)       { kind = 3; rows0 = 27200; wi = 4; rowLocal0 = gb * 16; }
    else if (gb < 280) { kind = 2; rows0 = 24000; wi = 3; rowLocal0 = (gb - 80) * 16; }
    else if (gb < 780) { kind = 1; rows0 = 16000; wi = 2; rowLocal0 = (gb - 280) * 16; }
    else               { kind = 0; rows0 = 0;     wi = 1; rowLocal0 = (gb - 780) * 16; }

    __shared__ float X[16 * 324];
    int tid = threadIdx.x;
    const float4* S2v = (const float4*)(ws + OFF_GATE);
    const float4* S5v = (const float4*)(ws + OFF_R2);
    for (int v = tid; v < 1200; v += 256) {
        int rl = v / 75, dc = v % 75;
        int R = rowLocal0 + rl;
        float4 s;
        if (kind == 0) {                       // r=2: direct S2 row
            s = S2v[(size_t)R * 75 + dc];
        } else if (kind == 1) {                // r=4: 2 x S2
            int b = R / 500, g = R % 500;
            const float4* p = S2v + ((size_t)b * 1000 + 2 * g) * 75 + dc;
            s = f4add(p[0], p[75]);
        } else if (kind == 2) {                // r=10: 2 x S5
            int b = R / 200, g = R % 200;
            const float4* p = S5v + ((size_t)b * 400 + 2 * g) * 75 + dc;
            s = f4add(p[0], p[75]);
        } else {                               // r=25: 5 x S5
            int b = R / 80, g = R % 80;
            const float4* p = S5v + ((size_t)b * 400 + 5 * g) * 75 + dc;
            s = f4add(f4add(p[0], p[75]), f4add(p[150], p[225]));
            s = f4add(s, p[300]);
        }
        *(float4*)&X[rl * 324 + dc * 4] = s;
    }
    for (int i = tid; i < 16 * 24; i += 256) X[(i / 24) * 324 + 300 + (i % 24)] = 0.f;
    __syncthreads();

    int lane = tid & 63, wave = tid >> 6;
    int mrow = lane & 15, quad = lane >> 4;
    bf8 Ah[10], Al[10];
    prep_afrags(X, lane, Ah, Al);

    const ushortT* wb = (const ushortT*)(ws + OFF_WB);
    int mpH = wi * 20, mpL = wi * 20 + 10;
    for (int nt = wave; nt < 19; nt += 4) {
        f32x4 acc = {0.f, 0.f, 0.f, 0.f};
        #pragma unroll
        for (int kt = 0; kt < 10; kt++) {
            bf8 Bh = load_bfrag(wb, mpH, kt, nt, lane);
            bf8 Bl = load_bfrag(wb, mpL, kt, nt, lane);
            acc = __builtin_amdgcn_mfma_f32_16x16x32_bf16(Ah[kt], Bh, acc, 0, 0, 0);
            acc = __builtin_amdgcn_mfma_f32_16x16x32_bf16(Ah[kt], Bl, acc, 0, 0, 0);
            acc = __builtin_amdgcn_mfma_f32_16x16x32_bf16(Al[kt], Bh, acc, 0, 0, 0);
        }
        int e = nt * 16 + mrow;
        if (e < 300) {
            float bv = ceb[wi * 300 + e];
            #pragma unroll
            for (int q = 0; q < 4; q++) {
                int mm = quad * 4 + q;
                ws[OFF_HC + (size_t)(rows0 + rowLocal0 + mm) * 300 + e] = fmaxf(acc[q] + bv, 0.f);
            }
        }
    }
}

// ---------------- fused: ce0 + Wz MFMA (shared A-frags) + gate MLP epilogue ----------------
__global__ __launch_bounds__(256) void k_fused(float* ws, const float* ceb,
                                               const float* m1W, const float* m1b,
                                               const float* m2W, const float* m2b,
                                               const float* bz){
    int row0 = blockIdx.x * 16;
    __shared__ float X[16 * 324];
    int tid = threadIdx.x;
    for (int v = tid; v < 1200; v += 256) {
        int rl = v / 75, dc = (v % 75) * 4;
        *(float4*)&X[rl * 324 + dc] = *(const float4*)&ws[OFF_ART + (size_t)row0 * 300 + (size_t)v * 4];
    }
    for (int i = tid; i < 16 * 24; i += 256) X[(i / 24) * 324 + 300 + (i % 24)] = 0.f;
    __syncthreads();

    float w1[3][5], b1[3], w2[3], b2;
    #pragma unroll
    for (int k = 0; k < 3; k++) {
        #pragma unroll
        for (int i = 0; i < 5; i++) w1[k][i] = m1W[k * 5 + i];
        b1[k] = m1b[k]; w2[k] = m2W[k];
    }
    b2 = m2b[0];

    int lane = tid & 63, wave = tid >> 6;
    int mrow = lane & 15, quad = lane >> 4;
    bf8 Ah[10], Al[10];
    prep_afrags(X, lane, Ah, Al);

    const ushortT* wb = (const ushortT*)(ws + OFF_WB);
    for (int nt = wave; nt < 19; nt += 4) {
        f32x4 accA = {0.f, 0.f, 0.f, 0.f};
        f32x4 accZ = {0.f, 0.f, 0.f, 0.f};
        #pragma unroll
        for (int kt = 0; kt < 10; kt++) {
            bf8 B0h = load_bfrag(wb, 0,   kt, nt, lane);
            bf8 B0l = load_bfrag(wb, 10,  kt, nt, lane);
            bf8 B5h = load_bfrag(wb, 100, kt, nt, lane);
            bf8 B5l = load_bfrag(wb, 110, kt, nt, lane);
            accA = __builtin_amdgcn_mfma_f32_16x16x32_bf16(Ah[kt], B0h, accA, 0, 0, 0);
            accZ = __builtin_amdgcn_mfma_f32_16x16x32_bf16(Ah[kt], B5h, accZ, 0, 0, 0);
            accA = __builtin_amdgcn_mfma_f32_16x16x32_bf16(Ah[kt], B0l, accA, 0, 0, 0);
            accZ = __builtin_amdgcn_mfma_f32_16x16x32_bf16(Ah[kt], B5l, accZ, 0, 0, 0);
            accA = __builtin_amdgcn_mfma_f32_16x16x32_bf16(Al[kt], B0h, accA, 0, 0, 0);
            accZ = __builtin_amdgcn_mfma_f32_16x16x32_bf16(Al[kt], B5h, accZ, 0, 0, 0);
        }
        int e = nt * 16 + mrow;
        if (e < 300) {
            float cebe = ceb[e], bze = bz[e];
            #pragma unroll
            for (int q = 0; q < 4; q++) {
                int row = row0 + quad * 4 + q;
                int bb = row / 2000, t = row % 2000;
                size_t c1 = OFF_HC + ((size_t)bb * 1000 + t / 2) * 300;
                size_t c2 = OFF_HC + (16000 + (size_t)bb * 500 + t / 4) * 300;
                size_t c3 = OFF_HC + (24000 + (size_t)bb * 200 + t / 10) * 300;
                size_t c4 = OFF_HC + (27200 + (size_t)bb * 80 + t / 25) * 300;
                float y0 = fmaxf(accA[q] + cebe, 0.f);
                float y1 = ws[c1 + e] * 0.5f;
                float y2 = ws[c2 + e] * 0.25f;
                float y3 = ws[c3 + e] * 0.1f;
                float y4 = ws[c4 + e] * 0.04f;
                float gacc = b2;
                #pragma unroll
                for (int k = 0; k < 3; k++) {
                    float a = b1[k] + y0 * w1[k][0] + y1 * w1[k][1] + y2 * w1[k][2]
                            + y3 * w1[k][3] + y4 * w1[k][4];
                    gacc += fmaxf(a, 0.f) * w2[k];
                }
                ws[OFF_GATE + (size_t)row * 300 + e] = fmaxf(gacc, 0.f);
                ws[OFF_R2 + (size_t)row * 300 + e] = tanhf(accZ[q] + bze);
            }
        }
    }
}

// ---------------- MRU scan: 40 chunks x 50 steps ----------------
__global__ void k_scan1(float* ws){
    int tid = blockIdx.x * 256 + threadIdx.x;
    if (tid >= 192000) return;
    int c = tid / 4800, ch = tid % 4800;
    int b = ch / 300, d = ch % 300;
    size_t base = (size_t)b * 2000 * 300 + d;
    float A = 1.f, Bv = 0.f;
    int t0 = c * 50;
    for (int k = 0; k < 50; k++) {
        size_t ix = base + (size_t)(t0 + k) * 300;
        float g = ws[OFF_GATE + ix], zz = ws[OFF_R2 + ix];
        Bv = g * Bv + (1.f - g) * zz;
        A *= g;
    }
    ws[OFF_SCANA + tid] = A;
    ws[OFF_SCANB + tid] = Bv;
}

__global__ void k_scan2(float* ws){
    int ch = blockIdx.x * 256 + threadIdx.x;
    if (ch >= 4800) return;
    float c = 0.f;
    for (int j = 0; j < 40; j++) {
        ws[OFF_CST + (size_t)j * 4800 + ch] = c;
        c = ws[OFF_SCANA + (size_t)j * 4800 + ch] * c + ws[OFF_SCANB + (size_t)j * 4800 + ch];
    }
}

__global__ void k_scan3(float* ws){
    int tid = blockIdx.x * 256 + threadIdx.x;
    if (tid >= 192000) return;
    int c = tid / 4800, ch = tid % 4800;
    int b = ch / 300, d = ch % 300;
    size_t base = (size_t)b * 2000 * 300 + d;
    float cc = ws[OFF_CST + tid];
    int t0 = c * 50;
    for (int k = 0; k < 50; k++) {
        size_t ix = base + (size_t)(t0 + k) * 300;
        float g = ws[OFF_GATE + ix], zz = ws[OFF_R2 + ix];
        cc = g * cc + (1.f - g) * zz;
        ws[OFF_R2 + ix] = cc;   // cs in place of z
    }
}

// ---------------- Wo MFMA fused with enc = tanh(o)*cs (in place) ----------------
__global__ __launch_bounds__(256) void k_oenc(float* ws, const float* bo){
    int row0 = blockIdx.x * 16;
    __shared__ float X[16 * 324];
    int tid = threadIdx.x;
    for (int v = tid; v < 1200; v += 256) {
        int rl = v / 75, dc = (v % 75) * 4;
        *(float4*)&X[rl * 324 + dc] = *(const float4*)&ws[OFF_ART + (size_t)row0 * 300 + (size_t)v * 4];
    }
    for (int i = tid; i < 16 * 24; i += 256) X[(i / 24) * 324 + 300 + (i % 24)] = 0.f;
    __syncthreads();

    int lane = tid & 63, wave = tid >> 6;
    int mrow = lane & 15, quad = lane >> 4;
    bf8 Ah[10], Al[10];
    prep_afrags(X, lane, Ah, Al);

    const ushortT* wb = (const ushortT*)(ws + OFF_WB);
    for (int nt = wave; nt < 19; nt += 4) {
        f32x4 acc = {0.f, 0.f, 0.f, 0.f};
        #pragma unroll
        for (int kt = 0; kt < 10; kt++) {
            bf8 Bh = load_bfrag(wb, 120, kt, nt, lane);
            bf8 Bl = load_bfrag(wb, 130, kt, nt, lane);
            acc = __builtin_amdgcn_mfma_f32_16x16x32_bf16(Ah[kt], Bh, acc, 0, 0, 0);
            acc = __builtin_amdgcn_mfma_f32_16x16x32_bf16(Ah[kt], Bl, acc, 0, 0, 0);
            acc = __builtin_amdgcn_mfma_f32_16x16x32_bf16(Al[kt], Bh, acc, 0, 0, 0);
        }
        int e = nt * 16 + mrow;
        if (e < 300) {
            float bv = bo[e];
            #pragma unroll
            for (int q = 0; q < 4; q++) {
                size_t idx = OFF_R2 + (size_t)(row0 + quad * 4 + q) * 300 + e;
                ws[idx] = tanhf(acc[q] + bv) * ws[idx];
            }
        }
    }
}

// ---------------- key projections ----------------
__global__ __launch_bounds__(320) void k_keys(float* ws, const float* f1W, const float* f1b,
                                              const float* f2W, const float* f2b,
                                              const float* f3W, const float* f3b){
    int rid = blockIdx.x;
    const float* src; const float* W; const float* bias; float* out;
    if (rid < 480)       { src = ws + OFF_QEMB + (size_t)rid * 300;               W = f1W; bias = f1b; out = ws + OFF_KEYSQ + (size_t)rid * 300; }
    else if (rid < 1504) { int rr = rid - 480;  src = ws + OFF_OPTE + (size_t)rr * 300; W = f2W; bias = f2b; out = ws + OFF_KEYS2 + (size_t)rr * 300; }
    else                 { int rr = rid - 1504; src = ws + OFF_OPTE + (size_t)rr * 300; W = f3W; bias = f3b; out = ws + OFF_KEYS3 + (size_t)rr * 300; }
    __shared__ float X[300];
    int tid = threadIdx.x;
    for (int i = tid; i < 300; i += 320) X[i] = src[i];
    __syncthreads();
    if (tid < 300) {
        float acc = bias[tid];
        const float* wr = W + (size_t)tid * 300;
        for (int d = 0; d < 300; d++) acc += X[d] * wr[d];
        out[tid] = acc;
    }
}

// ---------------- fused attention: aoq tile in LDS, then 8 option combos ----------------
__global__ __launch_bounds__(256) void k_attn(float* ws){
    int tile = blockIdx.x, b = blockIdx.y;
    int t0 = tile * 32;
    __shared__ __align__(16) float Xe[32 * 300];
    __shared__ __align__(16) float Kb[30 * 300];
    __shared__ float S[32 * 30];
    int tid = threadIdx.x;
    int lim = (2000 - t0 < 32) ? (2000 - t0) : 32;

    for (int i = tid; i < 9600; i += 256) {
        int r = i / 300; int t = t0 + r;
        Xe[i] = (t < 2000) ? ws[OFF_R2 + ((size_t)b * 2000 + t) * 300 + (i % 300)] : 0.f;
    }
    for (int i = tid; i < 9000; i += 256) Kb[i] = ws[OFF_KEYSQ + (size_t)b * 9000 + i];
    __syncthreads();

    // S1 = Xe . f1keys, 2x2 register blocking (16x15 units)
    for (int p = tid; p < 240; p += 256) {
        int tl = (p / 15) * 2, w = (p % 15) * 2;
        const float4* x0 = (const float4*)&Xe[tl * 300];
        const float4* x1 = (const float4*)&Xe[(tl + 1) * 300];
        const float4* k0 = (const float4*)&Kb[w * 300];
        const float4* k1 = (const float4*)&Kb[(w + 1) * 300];
        float a00 = 0.f, a01 = 0.f, a10 = 0.f, a11 = 0.f;
        #pragma unroll 5
        for (int q = 0; q < 75; q++) {
            float4 xa = x0[q], xb = x1[q], ka = k0[q], kb = k1[q];
            a00 += xa.x * ka.x + xa.y * ka.y + xa.z * ka.z + xa.w * ka.w;
            a01 += xa.x * kb.x + xa.y * kb.y + xa.z * kb.z + xa.w * kb.w;
            a10 += xb.x * ka.x + xb.y * ka.y + xb.z * ka.z + xb.w * ka.w;
            a11 += xb.x * kb.x + xb.y * kb.y + xb.z * kb.z + xb.w * kb.w;
        }
        S[tl * 30 + w] = a00; S[tl * 30 + w + 1] = a01;
        S[(tl + 1) * 30 + w] = a10; S[(tl + 1) * 30 + w + 1] = a11;
    }
    __syncthreads();
    for (int i = tid; i < 9000; i += 256) Kb[i] = ws[OFF_QEMB + (size_t)b * 9000 + i];
    if (tid < 32) {
        float m = -1e30f;
        for (int w = 0; w < 30; w++) m = fmaxf(m, S[tid * 30 + w]);
        float s = 0.f;
        for (int w = 0; w < 30; w++) { float e = expf(S[tid * 30 + w] - m); S[tid * 30 + w] = e; s += e; }
        float inv = 1.f / s;
        for (int w = 0; w < 30; w++) S[tid * 30 + w] *= inv;
    }
    __syncthreads();
    // aoq = S1 . Q over Xe, 4-row blocking (8 groups x 300 cols)
    for (int p = tid; p < 2400; p += 256) {
        int e = p % 300, tl0 = (p / 300) * 4;
        float a0 = 0.f, a1 = 0.f, a2 = 0.f, a3 = 0.f;
        #pragma unroll 6
        for (int w = 0; w < 30; w++) {
            float qv = Kb[w * 300 + e];
            a0 += S[tl0 * 30 + w] * qv;
            a1 += S[(tl0 + 1) * 30 + w] * qv;
            a2 += S[(tl0 + 2) * 30 + w] * qv;
            a3 += S[(tl0 + 3) * 30 + w] * qv;
        }
        Xe[tl0 * 300 + e] = a0; Xe[(tl0 + 1) * 300 + e] = a1;
        Xe[(tl0 + 2) * 300 + e] = a2; Xe[(tl0 + 3) * 300 + e] = a3;
    }
    __syncthreads();

    // 8 combos: f2/f3 keys x 4 options; 2x2 register blocking (16x8 units)
    for (int combo = 0; combo < 8; combo++) {
        int opt = combo & 3; bool f3 = combo >= 4;
        size_t kbase = (f3 ? OFF_KEYS3 : OFF_KEYS2) + ((size_t)opt * 256 + (size_t)b * 16) * 300;
        for (int i = tid; i < 4800; i += 256) Kb[i] = ws[kbase + i];
        __syncthreads();
        for (int p = tid; p < 128; p += 256) {
            int tl = (p / 8) * 2, w = (p % 8) * 2;
            const float4* x0 = (const float4*)&Xe[tl * 300];
            const float4* x1 = (const float4*)&Xe[(tl + 1) * 300];
            const float4* k0 = (const float4*)&Kb[w * 300];
            const float4* k1 = (const float4*)&Kb[(w + 1) * 300];
            float a00 = 0.f, a01 = 0.f, a10 = 0.f, a11 = 0.f;
            #pragma unroll 5
            for (int q = 0; q < 75; q++) {
                float4 xa = x0[q], xb = x1[q], ka = k0[q], kb = k1[q];
                a00 += xa.x * ka.x + xa.y * ka.y + xa.z * ka.z + xa.w * ka.w;
                a01 += xa.x * kb.x + xa.y * kb.y + xa.z * kb.z + xa.w * kb.w;
                a10 += xb.x * ka.x + xb.y * ka.y + xb.z * ka.z + xb.w * ka.w;
                a11 += xb.x * kb.x + xb.y * kb.y + xb.z * kb.z + xb.w * kb.w;
            }
            S[tl * 16 + w] = a00; S[tl * 16 + w + 1] = a01;
            S[(tl + 1) * 16 + w] = a10; S[(tl + 1) * 16 + w + 1] = a11;
        }
        __syncthreads();
        if (tid < 32) {
            float m = -1e30f;
            for (int w = 0; w < 16; w++) m = fmaxf(m, S[tid * 16 + w]);
            float s = 0.f;
            for (int w = 0; w < 16; w++) { float e = expf(S[tid * 16 + w] - m); S[tid * 16 + w] = e; s += e; }
            float inv = 1.f / s;
            for (int w = 0; w < 16; w++) S[tid * 16 + w] *= inv;
        }
        __syncthreads();
        if (tid < 16) {
            float s = 0.f;
            for (int tl = 0; tl < lim; tl++) s += S[tl * 16 + tid];
            ws[OFF_PART + (((size_t)combo * 16 + b) * 63 + tile) * 16 + tid] = s;
        }
        __syncthreads();
    }
}

// ---------------- final: reduce PART, (2D)->75->1 ----------------
__global__ __launch_bounds__(256) void k_final(float* ws, const float* as1W, const float* as1b,
                                               const float* as2W, const float* as2b, float* out){
    int blk = blockIdx.x; int o = blk >> 4, b = blk & 15;
    __shared__ float vec[600]; __shared__ float cm[32]; __shared__ float hb[80];
    int tid = threadIdx.x;
    if (tid < 32) {
        int half = tid / 16, wk = tid % 16;
        int combo = half ? (4 + o) : o;
        float s = 0.f;
        size_t base = OFF_PART + (((size_t)combo * 16 + b) * 63) * 16 + wk;
        for (int t = 0; t < 63; t++) s += ws[base + (size_t)t * 16];
        cm[tid] = s * (1.f / 2000.f);
    }
    __syncthreads();
    const float* oe = ws + OFF_OPTE + ((size_t)o * 256 + (size_t)b * 16) * 300;
    for (int idx = tid; idx < 600; idx += 256) {
        int half = idx / 300, e = idx % 300;
        float acc = 0.f;
        for (int w = 0; w < 16; w++) acc += cm[half * 16 + w] * oe[(size_t)w * 300 + e];
        vec[idx] = acc;
    }
    __syncthreads();
    if (tid < 75) {
        float acc = as1b[tid];
        for (int m = 0; m < 600; m++) acc += vec[m] * as1W[(size_t)tid * 600 + m];
        hb[tid] = fmaxf(acc, 0.f);
    }
    __syncthreads();
    if (tid == 0) {
        float s = as2b[0];
        for (int j = 0; j < 75; j++) s += hb[j] * as2W[j];
        out[b * 4 + o] = s;
    }
}

extern "C" void kernel_launch(void* const* d_in, const int* in_sizes, int n_in,
                              void* d_out, int out_size, void* d_ws, size_t ws_size,
                              hipStream_t stream) {
    float* ws = (float*)d_ws;
    const int* o1 = (const int*)d_in[0];
    const int* o2 = (const int*)d_in[1];
    const int* o3 = (const int*)d_in[2];
    const int* o4 = (const int*)d_in[3];
    const int* qin = (const int*)d_in[4];
    const int* ain = (const int*)d_in[5];
    const float* emb  = (const float*)d_in[6];
    const float* ceW  = (const float*)d_in[7];
    const float* ceb  = (const float*)d_in[8];
    const float* m1W  = (const float*)d_in[9];
    const float* m1b  = (const float*)d_in[10];
    const float* m2W  = (const float*)d_in[11];
    const float* m2b  = (const float*)d_in[12];
    const float* Wz   = (const float*)d_in[13];
    const float* bz   = (const float*)d_in[14];
    const float* Wo   = (const float*)d_in[15];
    const float* bo   = (const float*)d_in[16];
    const float* f1W  = (const float*)d_in[17];
    const float* f1b  = (const float*)d_in[18];
    const float* f2W  = (const float*)d_in[19];
    const float* f2b  = (const float*)d_in[20];
    const float* f3W  = (const float*)d_in[21];
    const float* f3b  = (const float*)d_in[22];
    const float* as1W = (const float*)d_in[23];
    const float* as1b = (const float*)d_in[24];
    const float* as2W = (const float*)d_in[25];
    const float* as2b = (const float*)d_in[26];

    k_pack<<<(680960 + 255) / 256, 256, 0, stream>>>(ws, ceW, Wz, Wo);
    k_gather<<<(2512800 + 255) / 256, 256, 0, stream>>>(ws, emb, ain, qin, o1, o2, o3, o4);
    k_s2s5<<<(1680000 + 255) / 256, 256, 0, stream>>>(ws);
    k_ce_coarse<<<1780, 256, 0, stream>>>(ws, ceb);
    k_fused<<<2000, 256, 0, stream>>>(ws, ceb, m1W, m1b, m2W, m2b, bz);
    k_scan1<<<750, 256, 0, stream>>>(ws);
    k_scan2<<<19, 256, 0, stream>>>(ws);
    k_scan3<<<750, 256, 0, stream>>>(ws);
    k_oenc<<<2000, 256, 0, stream>>>(ws, bo);
    k_keys<<<2528, 320, 0, stream>>>(ws, f1W, f1b, f2W, f2b, f3W, f3b);
    k_attn<<<dim3(63, 16), 256, 0, stream>>>(ws);
    k_final<<<64, 256, 0, stream>>>(ws, as1W, as1b, as2W, as2b, (float*)d_out);
}

// Round 6
// 706.827 us; speedup vs baseline: 1.7555x; 1.1128x over previous
//
#include <hip/hip_runtime.h>
#include <math.h>

typedef unsigned short ushortT;
typedef short bf8 __attribute__((ext_vector_type(8)));
typedef float f32x4 __attribute__((ext_vector_type(4)));

__device__ __forceinline__ float bf2f(ushortT u){
    union { unsigned int i; float f; } v; v.i = ((unsigned int)u) << 16; return v.f;
}
__device__ __forceinline__ ushortT f2bf(float f){
    union { float f; unsigned int i; } v; v.f = f;
    unsigned int x = v.i;
    return (ushortT)((x + 0x7fffu + ((x >> 16) & 1u)) >> 16);
}
__device__ __forceinline__ float4 f4add(float4 a, float4 b){
    return make_float4(a.x + b.x, a.y + b.y, a.z + b.z, a.w + b.w);
}

// B=16, T=2000, D=300, TQ=30, TOPT=16, ranges {1,2,4,10,25}; all fp32 I/O.
// Matvecs: bf16-split MFMA. Attention: S2 = P1·(Q·K^T) factorization (no aoq).

// ---------------- workspace layout (float indices), ~160.0 MB ----------------
constexpr size_t OFF_ART   = 0;           // 9,600,000  article embeddings
constexpr size_t OFF_R2    = 9600000;     // 9,600,000  S5 -> z -> cs -> enc
constexpr size_t OFF_GATE  = 19200000;    // 9,600,000  S2 -> gate
constexpr size_t OFF_HC    = 28800000;    // 8,544,000  coarse CE outputs
constexpr size_t OFF_WB    = 37344000;    //   680,960 f32 = 1,361,920 bf16 B-fragments
constexpr size_t OFF_QEMB  = 38024960;    //   144,000
constexpr size_t OFF_KEYSQ = 38168960;    //   144,000
constexpr size_t OFF_OPTE  = 38312960;    //   307,200
constexpr size_t OFF_KEYS2 = 38620160;    //   307,200
constexpr size_t OFF_KEYS3 = 38927360;    //   307,200
constexpr size_t OFF_SCANA = 39234560;    //   192,000
constexpr size_t OFF_SCANB = 39426560;    //   192,000
constexpr size_t OFF_CST   = 39618560;    //   192,000
constexpr size_t OFF_PART  = 39810560;    //   129,024
constexpr size_t OFF_MALL  = 39939584;    //    61,440  M_all = Q·K_all^T (16 x 30 x 128)
// end = 40,001,024 floats = 160.0 MB

// HC rows: r2 [0,16000)=b*1000+g | r4 [16000,24000)=b*500+g
//          r10 [24000,27200)=b*200+g | r25 [27200,28480)=b*80+g
// S2 (at OFF_GATE): 16000 rows = b*1000+g | S5 (at OFF_R2): 6400 rows = b*400+g

// WB layout (ushort units): ((mp + kt)*19 + nt)*512 + lane*8 + j
//   mp = matrix*20 + part*10;  matrix: 0..4 ce, 5 Wz, 6 Wo; part: 0 hi, 1 lo

__global__ void k_pack(float* ws, const float* ceW, const float* Wz, const float* Wo){
    int id = blockIdx.x * 256 + threadIdx.x;
    if (id >= 680960) return;          // 7 * 97280
    int m = id / 97280; int rr = id % 97280;
    int kt = rr / 9728; rr %= 9728;    // 19*512
    int nt = rr / 512;  rr %= 512;
    int lane = rr / 8; int j = rr % 8;
    int d = kt * 32 + (lane >> 4) * 8 + j;
    int e = nt * 16 + (lane & 15);
    float w = 0.f;
    if (d < 300 && e < 300) {
        const float* src = (m < 5) ? (ceW + (size_t)m * 90000) : (m == 5 ? Wz : Wo);
        w = src[(size_t)e * 300 + d];
    }
    ushortT hi = f2bf(w);
    ushortT lo = f2bf(w - bf2f(hi));
    ushortT* wb = (ushortT*)(ws + OFF_WB);
    wb[((size_t)(m * 20 + kt) * 19 + nt) * 512 + lane * 8 + j] = hi;
    wb[((size_t)(m * 20 + 10 + kt) * 19 + nt) * 512 + lane * 8 + j] = lo;
}

__device__ __forceinline__ bf8 load_bfrag(const ushortT* wb, int mp, int kt, int nt, int lane){
    return *(const bf8*)(wb + (((size_t)(mp + kt) * 19 + nt) * 512 + lane * 8));
}

__device__ __forceinline__ void prep_afrags(const float* X, int lane, bf8* Ah, bf8* Al){
    int mrow = lane & 15, quad = lane >> 4;
    #pragma unroll
    for (int kt = 0; kt < 10; kt++) {
        const float* xp = &X[mrow * 324 + kt * 32 + quad * 8];
        float4 x0 = *(const float4*)xp;
        float4 x1 = *(const float4*)(xp + 4);
        float xv[8] = {x0.x, x0.y, x0.z, x0.w, x1.x, x1.y, x1.z, x1.w};
        bf8 h, l;
        #pragma unroll
        for (int j = 0; j < 8; j++) {
            ushortT hh = f2bf(xv[j]);
            h[j] = (short)hh;
            l[j] = (short)f2bf(xv[j] - bf2f(hh));
        }
        Ah[kt] = h; Al[kt] = l;
    }
}

// ---------------- float4 embedding gathers ----------------
__global__ void k_gather(float* ws, const float* emb, const int* art_in, const int* q_in,
                         const int* o1, const int* o2, const int* o3, const int* o4){
    size_t id = (size_t)blockIdx.x * 256 + threadIdx.x;
    const float4* embv = (const float4*)emb;
    if (id < 2400000) {                       // article: 32000 rows x 75 f4
        size_t row = id / 75; int wi = (int)(id % 75);
        ((float4*)(ws + OFF_ART))[id] = embv[(size_t)art_in[row] * 75 + wi];
    } else if (id < 2436000) {                // question: 480 rows
        size_t i2 = id - 2400000; size_t row = i2 / 75; int wi = (int)(i2 % 75);
        ((float4*)(ws + OFF_QEMB))[i2] = embv[(size_t)q_in[row] * 75 + wi];
    } else if (id < 2512800) {                // options: 1024 rows = opt*256+b*16+w
        size_t i3 = id - 2436000; size_t row = i3 / 75; int wi = (int)(i3 % 75);
        int opt = (int)(row / 256); int rr = (int)(row % 256);
        const int* op = (opt == 0) ? o1 : (opt == 1) ? o2 : (opt == 2) ? o3 : o4;
        ((float4*)(ws + OFF_OPTE))[i3] = embv[(size_t)op[rr] * 75 + wi];
    }
}

// ---------------- hierarchical group sums: S2 and S5 from ART ----------------
__global__ void k_s2s5(float* ws){
    size_t id = (size_t)blockIdx.x * 256 + threadIdx.x;
    const float4* art = (const float4*)(ws + OFF_ART);
    if (id < 1200000) {                        // S2: 16000 rows x 75 f4
        size_t row = id / 75; int wi = (int)(id % 75);
        size_t b = row / 1000, g = row % 1000;
        const float4* p = art + ((b * 2000 + g * 2) * 75 + wi);
        ((float4*)(ws + OFF_GATE))[row * 75 + wi] = f4add(p[0], p[75]);
    } else if (id < 1680000) {                 // S5: 6400 rows x 75 f4
        size_t i2 = id - 1200000;
        size_t row = i2 / 75; int wi = (int)(i2 % 75);
        size_t b = row / 400, g = row % 400;
        const float4* p = art + ((b * 2000 + g * 5) * 75 + wi);
        float4 s = f4add(f4add(p[0], p[75]), f4add(p[150], p[225]));
        s = f4add(s, p[300]);
        ((float4*)(ws + OFF_R2))[row * 75 + wi] = s;
    }
}

// ---------------- coarse CE (r=2,4,10,25): unrolled staged sums + MFMA ----------------
// blocks: [0,80) r25 | [80,280) r10 | [280,780) r4 | [780,1780) r2  (heavy first)
__global__ __launch_bounds__(256) void k_ce_coarse(float* ws, const float* ceb){
    int gb = blockIdx.x;
    int kind, rows0, wi, rowLocal0;
    if (gb < 80)       { kind = 3; rows0 = 27200; wi = 4; rowLocal0 = gb * 16; }
    else if (gb < 280) { kind = 2; rows0 = 24000; wi = 3; rowLocal0 = (gb - 80) * 16; }
    else if (gb < 780) { kind = 1; rows0 = 16000; wi = 2; rowLocal0 = (gb - 280) * 16; }
    else               { kind = 0; rows0 = 0;     wi = 1; rowLocal0 = (gb - 780) * 16; }

    __shared__ float X[16 * 324];
    int tid = threadIdx.x;
    const float4* S2v = (const float4*)(ws + OFF_GATE);
    const float4* S5v = (const float4*)(ws + OFF_R2);
    for (int v = tid; v < 1200; v += 256) {
        int rl = v / 75, dc = v % 75;
        int R = rowLocal0 + rl;
        float4 s;
        if (kind == 0) {                       // r=2: direct S2 row
            s = S2v[(size_t)R * 75 + dc];
        } else if (kind == 1) {                // r=4: 2 x S2
            int b = R / 500, g = R % 500;
            const float4* p = S2v + ((size_t)b * 1000 + 2 * g) * 75 + dc;
            s = f4add(p[0], p[75]);
        } else if (kind == 2) {                // r=10: 2 x S5
            int b = R / 200, g = R % 200;
            const float4* p = S5v + ((size_t)b * 400 + 2 * g) * 75 + dc;
            s = f4add(p[0], p[75]);
        } else {                               // r=25: 5 x S5
            int b = R / 80, g = R % 80;
            const float4* p = S5v + ((size_t)b * 400 + 5 * g) * 75 + dc;
            s = f4add(f4add(p[0], p[75]), f4add(p[150], p[225]));
            s = f4add(s, p[300]);
        }
        *(float4*)&X[rl * 324 + dc * 4] = s;
    }
    for (int i = tid; i < 16 * 24; i += 256) X[(i / 24) * 324 + 300 + (i % 24)] = 0.f;
    __syncthreads();

    int lane = tid & 63, wave = tid >> 6;
    int mrow = lane & 15, quad = lane >> 4;
    bf8 Ah[10], Al[10];
    prep_afrags(X, lane, Ah, Al);

    const ushortT* wb = (const ushortT*)(ws + OFF_WB);
    int mpH = wi * 20, mpL = wi * 20 + 10;
    for (int nt = wave; nt < 19; nt += 4) {
        f32x4 acc = {0.f, 0.f, 0.f, 0.f};
        #pragma unroll
        for (int kt = 0; kt < 10; kt++) {
            bf8 Bh = load_bfrag(wb, mpH, kt, nt, lane);
            bf8 Bl = load_bfrag(wb, mpL, kt, nt, lane);
            acc = __builtin_amdgcn_mfma_f32_16x16x32_bf16(Ah[kt], Bh, acc, 0, 0, 0);
            acc = __builtin_amdgcn_mfma_f32_16x16x32_bf16(Ah[kt], Bl, acc, 0, 0, 0);
            acc = __builtin_amdgcn_mfma_f32_16x16x32_bf16(Al[kt], Bh, acc, 0, 0, 0);
        }
        int e = nt * 16 + mrow;
        if (e < 300) {
            float bv = ceb[wi * 300 + e];
            #pragma unroll
            for (int q = 0; q < 4; q++) {
                int mm = quad * 4 + q;
                ws[OFF_HC + (size_t)(rows0 + rowLocal0 + mm) * 300 + e] = fmaxf(acc[q] + bv, 0.f);
            }
        }
    }
}

// ---------------- fused: ce0 + Wz MFMA (shared A-frags) + gate MLP epilogue ----------------
__global__ __launch_bounds__(256) void k_fused(float* ws, const float* ceb,
                                               const float* m1W, const float* m1b,
                                               const float* m2W, const float* m2b,
                                               const float* bz){
    int row0 = blockIdx.x * 16;
    __shared__ float X[16 * 324];
    int tid = threadIdx.x;
    for (int v = tid; v < 1200; v += 256) {
        int rl = v / 75, dc = (v % 75) * 4;
        *(float4*)&X[rl * 324 + dc] = *(const float4*)&ws[OFF_ART + (size_t)row0 * 300 + (size_t)v * 4];
    }
    for (int i = tid; i < 16 * 24; i += 256) X[(i / 24) * 324 + 300 + (i % 24)] = 0.f;
    __syncthreads();

    float w1[3][5], b1[3], w2[3], b2;
    #pragma unroll
    for (int k = 0; k < 3; k++) {
        #pragma unroll
        for (int i = 0; i < 5; i++) w1[k][i] = m1W[k * 5 + i];
        b1[k] = m1b[k]; w2[k] = m2W[k];
    }
    b2 = m2b[0];

    int lane = tid & 63, wave = tid >> 6;
    int mrow = lane & 15, quad = lane >> 4;
    bf8 Ah[10], Al[10];
    prep_afrags(X, lane, Ah, Al);

    const ushortT* wb = (const ushortT*)(ws + OFF_WB);
    for (int nt = wave; nt < 19; nt += 4) {
        f32x4 accA = {0.f, 0.f, 0.f, 0.f};
        f32x4 accZ = {0.f, 0.f, 0.f, 0.f};
        #pragma unroll
        for (int kt = 0; kt < 10; kt++) {
            bf8 B0h = load_bfrag(wb, 0,   kt, nt, lane);
            bf8 B0l = load_bfrag(wb, 10,  kt, nt, lane);
            bf8 B5h = load_bfrag(wb, 100, kt, nt, lane);
            bf8 B5l = load_bfrag(wb, 110, kt, nt, lane);
            accA = __builtin_amdgcn_mfma_f32_16x16x32_bf16(Ah[kt], B0h, accA, 0, 0, 0);
            accZ = __builtin_amdgcn_mfma_f32_16x16x32_bf16(Ah[kt], B5h, accZ, 0, 0, 0);
            accA = __builtin_amdgcn_mfma_f32_16x16x32_bf16(Ah[kt], B0l, accA, 0, 0, 0);
            accZ = __builtin_amdgcn_mfma_f32_16x16x32_bf16(Ah[kt], B5l, accZ, 0, 0, 0);
            accA = __builtin_amdgcn_mfma_f32_16x16x32_bf16(Al[kt], B0h, accA, 0, 0, 0);
            accZ = __builtin_amdgcn_mfma_f32_16x16x32_bf16(Al[kt], B5h, accZ, 0, 0, 0);
        }
        int e = nt * 16 + mrow;
        if (e < 300) {
            float cebe = ceb[e], bze = bz[e];
            #pragma unroll
            for (int q = 0; q < 4; q++) {
                int row = row0 + quad * 4 + q;
                int bb = row / 2000, t = row % 2000;
                size_t c1 = OFF_HC + ((size_t)bb * 1000 + t / 2) * 300;
                size_t c2 = OFF_HC + (16000 + (size_t)bb * 500 + t / 4) * 300;
                size_t c3 = OFF_HC + (24000 + (size_t)bb * 200 + t / 10) * 300;
                size_t c4 = OFF_HC + (27200 + (size_t)bb * 80 + t / 25) * 300;
                float y0 = fmaxf(accA[q] + cebe, 0.f);
                float y1 = ws[c1 + e] * 0.5f;
                float y2 = ws[c2 + e] * 0.25f;
                float y3 = ws[c3 + e] * 0.1f;
                float y4 = ws[c4 + e] * 0.04f;
                float gacc = b2;
                #pragma unroll
                for (int k = 0; k < 3; k++) {
                    float a = b1[k] + y0 * w1[k][0] + y1 * w1[k][1] + y2 * w1[k][2]
                            + y3 * w1[k][3] + y4 * w1[k][4];
                    gacc += fmaxf(a, 0.f) * w2[k];
                }
                ws[OFF_GATE + (size_t)row * 300 + e] = fmaxf(gacc, 0.f);
                ws[OFF_R2 + (size_t)row * 300 + e] = tanhf(accZ[q] + bze);
            }
        }
    }
}

// ---------------- MRU scan: 40 chunks x 50 steps ----------------
__global__ void k_scan1(float* ws){
    int tid = blockIdx.x * 256 + threadIdx.x;
    if (tid >= 192000) return;
    int c = tid / 4800, ch = tid % 4800;
    int b = ch / 300, d = ch % 300;
    size_t base = (size_t)b * 2000 * 300 + d;
    float A = 1.f, Bv = 0.f;
    int t0 = c * 50;
    for (int k = 0; k < 50; k++) {
        size_t ix = base + (size_t)(t0 + k) * 300;
        float g = ws[OFF_GATE + ix], zz = ws[OFF_R2 + ix];
        Bv = g * Bv + (1.f - g) * zz;
        A *= g;
    }
    ws[OFF_SCANA + tid] = A;
    ws[OFF_SCANB + tid] = Bv;
}

__global__ void k_scan2(float* ws){
    int ch = blockIdx.x * 256 + threadIdx.x;
    if (ch >= 4800) return;
    float c = 0.f;
    for (int j = 0; j < 40; j++) {
        ws[OFF_CST + (size_t)j * 4800 + ch] = c;
        c = ws[OFF_SCANA + (size_t)j * 4800 + ch] * c + ws[OFF_SCANB + (size_t)j * 4800 + ch];
    }
}

__global__ void k_scan3(float* ws){
    int tid = blockIdx.x * 256 + threadIdx.x;
    if (tid >= 192000) return;
    int c = tid / 4800, ch = tid % 4800;
    int b = ch / 300, d = ch % 300;
    size_t base = (size_t)b * 2000 * 300 + d;
    float cc = ws[OFF_CST + tid];
    int t0 = c * 50;
    for (int k = 0; k < 50; k++) {
        size_t ix = base + (size_t)(t0 + k) * 300;
        float g = ws[OFF_GATE + ix], zz = ws[OFF_R2 + ix];
        cc = g * cc + (1.f - g) * zz;
        ws[OFF_R2 + ix] = cc;   // cs in place of z
    }
}

// ---------------- Wo MFMA fused with enc = tanh(o)*cs (in place) ----------------
__global__ __launch_bounds__(256) void k_oenc(float* ws, const float* bo){
    int row0 = blockIdx.x * 16;
    __shared__ float X[16 * 324];
    int tid = threadIdx.x;
    for (int v = tid; v < 1200; v += 256) {
        int rl = v / 75, dc = (v % 75) * 4;
        *(float4*)&X[rl * 324 + dc] = *(const float4*)&ws[OFF_ART + (size_t)row0 * 300 + (size_t)v * 4];
    }
    for (int i = tid; i < 16 * 24; i += 256) X[(i / 24) * 324 + 300 + (i % 24)] = 0.f;
    __syncthreads();

    int lane = tid & 63, wave = tid >> 6;
    int mrow = lane & 15, quad = lane >> 4;
    bf8 Ah[10], Al[10];
    prep_afrags(X, lane, Ah, Al);

    const ushortT* wb = (const ushortT*)(ws + OFF_WB);
    for (int nt = wave; nt < 19; nt += 4) {
        f32x4 acc = {0.f, 0.f, 0.f, 0.f};
        #pragma unroll
        for (int kt = 0; kt < 10; kt++) {
            bf8 Bh = load_bfrag(wb, 120, kt, nt, lane);
            bf8 Bl = load_bfrag(wb, 130, kt, nt, lane);
            acc = __builtin_amdgcn_mfma_f32_16x16x32_bf16(Ah[kt], Bh, acc, 0, 0, 0);
            acc = __builtin_amdgcn_mfma_f32_16x16x32_bf16(Ah[kt], Bl, acc, 0, 0, 0);
            acc = __builtin_amdgcn_mfma_f32_16x16x32_bf16(Al[kt], Bh, acc, 0, 0, 0);
        }
        int e = nt * 16 + mrow;
        if (e < 300) {
            float bv = bo[e];
            #pragma unroll
            for (int q = 0; q < 4; q++) {
                size_t idx = OFF_R2 + (size_t)(row0 + quad * 4 + q) * 300 + e;
                ws[idx] = tanhf(acc[q] + bv) * ws[idx];
            }
        }
    }
}

// ---------------- key projections ----------------
__global__ __launch_bounds__(320) void k_keys(float* ws, const float* f1W, const float* f1b,
                                              const float* f2W, const float* f2b,
                                              const float* f3W, const float* f3b){
    int rid = blockIdx.x;
    const float* src; const float* W; const float* bias; float* out;
    if (rid < 480)       { src = ws + OFF_QEMB + (size_t)rid * 300;               W = f1W; bias = f1b; out = ws + OFF_KEYSQ + (size_t)rid * 300; }
    else if (rid < 1504) { int rr = rid - 480;  src = ws + OFF_OPTE + (size_t)rr * 300; W = f2W; bias = f2b; out = ws + OFF_KEYS2 + (size_t)rr * 300; }
    else                 { int rr = rid - 1504; src = ws + OFF_OPTE + (size_t)rr * 300; W = f3W; bias = f3b; out = ws + OFF_KEYS3 + (size_t)rr * 300; }
    __shared__ float X[300];
    int tid = threadIdx.x;
    for (int i = tid; i < 300; i += 320) X[i] = src[i];
    __syncthreads();
    if (tid < 300) {
        float acc = bias[tid];
        const float* wr = W + (size_t)tid * 300;
        for (int d = 0; d < 300; d++) acc += X[d] * wr[d];
        out[tid] = acc;
    }
}

// ---------------- M_all = Q · K_all^T per batch (30 x 128, K=300) ----------------
__global__ __launch_bounds__(256) void k_matt(float* ws){
    int b = blockIdx.x;
    __shared__ float Q[30 * 300];
    int tid = threadIdx.x;
    for (int v = tid; v < 2250; v += 256)
        *(float4*)&Q[v * 4] = *(const float4*)&ws[OFF_QEMB + (size_t)b * 9000 + (size_t)v * 4];
    __syncthreads();
    int cw = tid & 127, half = tid >> 7;       // 128 key-cols x 2 halves of w'
    int combo = cw >> 4, w = cw & 15;
    size_t kbase = (combo < 4)
        ? OFF_KEYS2 + ((size_t)combo * 256 + (size_t)b * 16 + w) * 300
        : OFF_KEYS3 + ((size_t)(combo - 4) * 256 + (size_t)b * 16 + w) * 300;
    const float4* kr = (const float4*)&ws[kbase];
    for (int wp = half * 15; wp < half * 15 + 15; wp++) {
        const float4* qr = (const float4*)&Q[wp * 300];
        float a = 0.f;
        #pragma unroll 5
        for (int j = 0; j < 75; j++) {
            float4 k = kr[j], q = qr[j];
            a += k.x * q.x + k.y * q.y + k.z * q.z + k.w * q.w;
        }
        ws[OFF_MALL + (size_t)b * 3840 + (size_t)wp * 128 + cw] = a;
    }
}

// ---------------- attention: S1+softmax, then S_all = P1·M_all + softmax + colsums ----------------
__global__ __launch_bounds__(256) void k_attn(float* ws){
    int tile = blockIdx.x, b = blockIdx.y;
    int t0 = tile * 32;
    // U phase1: enc tile 32 x 304.  U phase2: M_all[3840] at 0, Sbuf 32x132 at 4224.
    __shared__ __align__(16) float U[9728];
    __shared__ float S[32 * 30];
    int tid = threadIdx.x;

    // phase 1a: stage enc tile (stride 304, zero-padded)
    for (int v = tid; v < 2432; v += 256) {    // 32 rows x 76 f4
        int r = v / 76, c = v % 76;
        int t = t0 + r;
        float4 val = make_float4(0.f, 0.f, 0.f, 0.f);
        if (c < 75 && t < 2000)
            val = *(const float4*)&ws[OFF_R2 + ((size_t)b * 2000 + t) * 300 + (size_t)c * 4];
        *(float4*)&U[r * 304 + c * 4] = val;
    }
    __syncthreads();

    // phase 1b: S1 = enc_tile · K1^T (32x30), K1 rows from global (L1/L2-hot)
    if (tid < 240) {
        int q = tid / 30, w = tid % 30;
        const float4* kr = (const float4*)&ws[OFF_KEYSQ + (size_t)b * 9000 + (size_t)w * 300];
        const float4* x0 = (const float4*)&U[(q * 4 + 0) * 304];
        const float4* x1 = (const float4*)&U[(q * 4 + 1) * 304];
        const float4* x2 = (const float4*)&U[(q * 4 + 2) * 304];
        const float4* x3 = (const float4*)&U[(q * 4 + 3) * 304];
        float a0 = 0.f, a1 = 0.f, a2 = 0.f, a3 = 0.f;
        #pragma unroll 5
        for (int j = 0; j < 75; j++) {
            float4 k = kr[j];
            float4 v0 = x0[j], v1 = x1[j], v2 = x2[j], v3 = x3[j];
            a0 += v0.x * k.x + v0.y * k.y + v0.z * k.z + v0.w * k.w;
            a1 += v1.x * k.x + v1.y * k.y + v1.z * k.z + v1.w * k.w;
            a2 += v2.x * k.x + v2.y * k.y + v2.z * k.z + v2.w * k.w;
            a3 += v3.x * k.x + v3.y * k.y + v3.z * k.z + v3.w * k.w;
        }
        S[(q * 4 + 0) * 30 + w] = a0;
        S[(q * 4 + 1) * 30 + w] = a1;
        S[(q * 4 + 2) * 30 + w] = a2;
        S[(q * 4 + 3) * 30 + w] = a3;
    }
    __syncthreads();   // Xe dead from here; U reused for M_all + Sbuf

    // phase 2a: stage M_all (3840 f) + row-softmax of S (32 threads)
    for (int v = tid; v < 960; v += 256)
        *(float4*)&U[v * 4] = *(const float4*)&ws[OFF_MALL + (size_t)b * 3840 + (size_t)v * 4];
    if (tid < 32) {
        float m = -1e30f;
        for (int w = 0; w < 30; w++) m = fmaxf(m, S[tid * 30 + w]);
        float s = 0.f;
        for (int w = 0; w < 30; w++) { float e = expf(S[tid * 30 + w] - m); S[tid * 30 + w] = e; s += e; }
        float inv = 1.f / s;
        for (int w = 0; w < 30; w++) S[tid * 30 + w] *= inv;
    }
    __syncthreads();

    // phase 2b: per (row, combo): v[16] = P1[row]·M[:, c*16..], softmax16, store
    {
        int c = tid >> 5, tl = tid & 31;
        float v[16];
        #pragma unroll
        for (int w = 0; w < 16; w++) v[w] = 0.f;
        for (int wp = 0; wp < 30; wp++) {
            float p1 = S[tl * 30 + wp];
            const float* Mr = &U[wp * 128 + c * 16];
            #pragma unroll
            for (int w = 0; w < 16; w++) v[w] += p1 * Mr[w];
        }
        float mx = v[0];
        #pragma unroll
        for (int w = 1; w < 16; w++) mx = fmaxf(mx, v[w]);
        float sum = 0.f;
        #pragma unroll
        for (int w = 0; w < 16; w++) { v[w] = expf(v[w] - mx); sum += v[w]; }
        float inv = ((t0 + tl) < 2000) ? (1.f / sum) : 0.f;
        #pragma unroll
        for (int w = 0; w < 16; w += 4) {
            float4 o = make_float4(v[w] * inv, v[w+1] * inv, v[w+2] * inv, v[w+3] * inv);
            *(float4*)&U[4224 + tl * 132 + c * 16 + w] = o;
        }
    }
    __syncthreads();

    // phase 2c: column sums over 32 rows -> PART (layout unchanged)
    if (tid < 128) {
        int combo = tid >> 4, w = tid & 15;
        float s = 0.f;
        for (int r = 0; r < 32; r++) s += U[4224 + r * 132 + tid];
        ws[OFF_PART + (((size_t)combo * 16 + b) * 63 + tile) * 16 + w] = s;
    }
}

// ---------------- final: reduce PART, (2D)->75->1 ----------------
__global__ __launch_bounds__(256) void k_final(float* ws, const float* as1W, const float* as1b,
                                               const float* as2W, const float* as2b, float* out){
    int blk = blockIdx.x; int o = blk >> 4, b = blk & 15;
    __shared__ float vec[600]; __shared__ float cm[32]; __shared__ float hb[80];
    int tid = threadIdx.x;
    if (tid < 32) {
        int half = tid / 16, wk = tid % 16;
        int combo = half ? (4 + o) : o;
        float s = 0.f;
        size_t base = OFF_PART + (((size_t)combo * 16 + b) * 63) * 16 + wk;
        for (int t = 0; t < 63; t++) s += ws[base + (size_t)t * 16];
        cm[tid] = s * (1.f / 2000.f);
    }
    __syncthreads();
    const float* oe = ws + OFF_OPTE + ((size_t)o * 256 + (size_t)b * 16) * 300;
    for (int idx = tid; idx < 600; idx += 256) {
        int half = idx / 300, e = idx % 300;
        float acc = 0.f;
        for (int w = 0; w < 16; w++) acc += cm[half * 16 + w] * oe[(size_t)w * 300 + e];
        vec[idx] = acc;
    }
    __syncthreads();
    if (tid < 75) {
        float acc = as1b[tid];
        for (int m = 0; m < 600; m++) acc += vec[m] * as1W[(size_t)tid * 600 + m];
        hb[tid] = fmaxf(acc, 0.f);
    }
    __syncthreads();
    if (tid == 0) {
        float s = as2b[0];
        for (int j = 0; j < 75; j++) s += hb[j] * as2W[j];
        out[b * 4 + o] = s;
    }
}

extern "C" void kernel_launch(void* const* d_in, const int* in_sizes, int n_in,
                              void* d_out, int out_size, void* d_ws, size_t ws_size,
                              hipStream_t stream) {
    float* ws = (float*)d_ws;
    const int* o1 = (const int*)d_in[0];
    const int* o2 = (const int*)d_in[1];
    const int* o3 = (const int*)d_in[2];
    const int* o4 = (const int*)d_in[3];
    const int* qin = (const int*)d_in[4];
    const int* ain = (const int*)d_in[5];
    const float* emb  = (const float*)d_in[6];
    const float* ceW  = (const float*)d_in[7];
    const float* ceb  = (const float*)d_in[8];
    const float* m1W  = (const float*)d_in[9];
    const float* m1b  = (const float*)d_in[10];
    const float* m2W  = (const float*)d_in[11];
    const float* m2b  = (const float*)d_in[12];
    const float* Wz   = (const float*)d_in[13];
    const float* bz   = (const float*)d_in[14];
    const float* Wo   = (const float*)d_in[15];
    const float* bo   = (const float*)d_in[16];
    const float* f1W  = (const float*)d_in[17];
    const float* f1b  = (const float*)d_in[18];
    const float* f2W  = (const float*)d_in[19];
    const float* f2b  = (const float*)d_in[20];
    const float* f3W  = (const float*)d_in[21];
    const float* f3b  = (const float*)d_in[22];
    const float* as1W = (const float*)d_in[23];
    const float* as1b = (const float*)d_in[24];
    const float* as2W = (const float*)d_in[25];
    const float* as2b = (const float*)d_in[26];

    k_pack<<<(680960 + 255) / 256, 256, 0, stream>>>(ws, ceW, Wz, Wo);
    k_gather<<<(2512800 + 255) / 256, 256, 0, stream>>>(ws, emb, ain, qin, o1, o2, o3, o4);
    k_s2s5<<<(1680000 + 255) / 256, 256, 0, stream>>>(ws);
    k_ce_coarse<<<1780, 256, 0, stream>>>(ws, ceb);
    k_fused<<<2000, 256, 0, stream>>>(ws, ceb, m1W, m1b, m2W, m2b, bz);
    k_scan1<<<750, 256, 0, stream>>>(ws);
    k_scan2<<<19, 256, 0, stream>>>(ws);
    k_scan3<<<750, 256, 0, stream>>>(ws);
    k_oenc<<<2000, 256, 0, stream>>>(ws, bo);
    k_keys<<<2528, 320, 0, stream>>>(ws, f1W, f1b, f2W, f2b, f3W, f3b);
    k_matt<<<16, 256, 0, stream>>>(ws);
    k_attn<<<dim3(63, 16), 256, 0, stream>>>(ws);
    k_final<<<64, 256, 0, stream>>>(ws, as1W, as1b, as2W, as2b, (float*)d_out);
}

// Round 7
// 645.307 us; speedup vs baseline: 1.9229x; 1.0953x over previous
//
#include <hip/hip_runtime.h>
#include <math.h>

typedef unsigned short ushortT;
typedef short bf8 __attribute__((ext_vector_type(8)));
typedef float f32x4 __attribute__((ext_vector_type(4)));
typedef unsigned short us4 __attribute__((ext_vector_type(4)));

__device__ __forceinline__ float bf2f(ushortT u){
    union { unsigned int i; float f; } v; v.i = ((unsigned int)u) << 16; return v.f;
}
__device__ __forceinline__ ushortT f2bf(float f){
    union { float f; unsigned int i; } v; v.f = f;
    unsigned int x = v.i;
    return (ushortT)((x + 0x7fffu + ((x >> 16) & 1u)) >> 16);
}
__device__ __forceinline__ float4 f4add(float4 a, float4 b){
    return make_float4(a.x + b.x, a.y + b.y, a.z + b.z, a.w + b.w);
}

// B=16, T=2000, D=300; fp32 I/O. Matvecs: bf16-split MFMA (xh*wh+xh*wl+xl*wh),
// M=32 row-tiles, A pre-split into LDS fragments, B frags from L2.

// ---------------- workspace layout (float indices), ~160.0 MB ----------------
constexpr size_t OFF_ART   = 0;           // 9,600,000  article embeddings
constexpr size_t OFF_R2    = 9600000;     // 9,600,000  S5 -> z -> cs -> enc
constexpr size_t OFF_GATE  = 19200000;    // 9,600,000  S2 -> gate
constexpr size_t OFF_HC    = 28800000;    // 8,544,000  coarse CE outputs
constexpr size_t OFF_WB    = 37344000;    //   680,960 f32 B-fragments (bf16 hi/lo)
constexpr size_t OFF_QEMB  = 38024960;    //   144,000
constexpr size_t OFF_KEYSQ = 38168960;    //   144,000
constexpr size_t OFF_OPTE  = 38312960;    //   307,200
constexpr size_t OFF_KEYS2 = 38620160;    //   307,200
constexpr size_t OFF_KEYS3 = 38927360;    //   307,200
constexpr size_t OFF_SCANA = 39234560;    //   192,000
constexpr size_t OFF_SCANB = 39426560;    //   192,000
constexpr size_t OFF_CST   = 39618560;    //   192,000
constexpr size_t OFF_PART  = 39810560;    //   129,024
constexpr size_t OFF_MALL  = 39939584;    //    61,440  M_all = Q·K_all^T
// end = 40,001,024 floats

// HC rows: r2 [0,16000)=b*1000+g | r4 [16000,24000)=b*500+g
//          r10 [24000,27200)=b*200+g | r25 [27200,28480)=b*80+g
// S2 (at OFF_GATE): 16000 rows | S5 (at OFF_R2): 6400 rows

// WB (ushort units): ((mp + kt)*19 + nt)*512 + lane*8 + j
//   mp = matrix*20 + part*10; matrix: 0..4 ce, 5 Wz, 6 Wo; part: 0 hi, 1 lo

__global__ void k_pack(float* ws, const float* ceW, const float* Wz, const float* Wo){
    int id = blockIdx.x * 256 + threadIdx.x;
    if (id >= 680960) return;          // 7 * 97280
    int m = id / 97280; int rr = id % 97280;
    int kt = rr / 9728; rr %= 9728;
    int nt = rr / 512;  rr %= 512;
    int lane = rr / 8; int j = rr % 8;
    int d = kt * 32 + (lane >> 4) * 8 + j;
    int e = nt * 16 + (lane & 15);
    float w = 0.f;
    if (d < 300 && e < 300) {
        const float* src = (m < 5) ? (ceW + (size_t)m * 90000) : (m == 5 ? Wz : Wo);
        w = src[(size_t)e * 300 + d];
    }
    ushortT hi = f2bf(w);
    ushortT lo = f2bf(w - bf2f(hi));
    ushortT* wb = (ushortT*)(ws + OFF_WB);
    wb[((size_t)(m * 20 + kt) * 19 + nt) * 512 + lane * 8 + j] = hi;
    wb[((size_t)(m * 20 + 10 + kt) * 19 + nt) * 512 + lane * 8 + j] = lo;
}

__device__ __forceinline__ bf8 load_bfrag(const ushortT* wb, int mp, int kt, int nt, int lane){
    return *(const bf8*)(wb + (((size_t)(mp + kt) * 19 + nt) * 512 + lane * 8));
}
// LDS A-frags: LA[((tile*10+kt)*2+part)*512 + lane*8 + j]
__device__ __forceinline__ bf8 lds_afrag(const ushortT* LA, int tile, int kt, int part, int lane){
    return *(const bf8*)(LA + ((tile * 10 + kt) * 2 + part) * 512 + lane * 8);
}
// store one float4 (row r, cols dc4*4..+3) as split hi/lo fragments into LDS
__device__ __forceinline__ void lds_store_split(ushortT* LA, int r, int dc4, float4 s){
    int kt = dc4 / 8;
    int kk = (dc4 % 8) * 4;           // within-kt element offset
    int quad = kk / 8, j = kk % 8;    // j in {0,4}
    int lane = quad * 16 + (r & 15), tile = r >> 4;
    us4 h, l;
    h.x = f2bf(s.x); l.x = f2bf(s.x - bf2f(h.x));
    h.y = f2bf(s.y); l.y = f2bf(s.y - bf2f(h.y));
    h.z = f2bf(s.z); l.z = f2bf(s.z - bf2f(h.z));
    h.w = f2bf(s.w); l.w = f2bf(s.w - bf2f(h.w));
    int base = ((tile * 10 + kt) * 2) * 512 + lane * 8 + j;
    *(us4*)&LA[base] = h;
    *(us4*)&LA[base + 512] = l;
}
// zero the kt=9 slices (cols 288..319 padding), call before staging
__device__ __forceinline__ void lds_zero_kt9(ushortT* LA, int tid){
    // slices 18,19 (tile0 hi/lo), 38,39 (tile1 hi/lo); 512 ushorts each
    for (int i = tid; i < 1024; i += 256) {
        int sl = i >> 8, u = i & 255;                 // 4 slices x 256 uints
        int slice = (sl < 2) ? (18 + sl) : (36 + sl); // 18,19,38,39
        *(unsigned int*)&LA[slice * 512 + u * 2] = 0u;
    }
}

// ---------------- float4 embedding gathers ----------------
__global__ void k_gather(float* ws, const float* emb, const int* art_in, const int* q_in,
                         const int* o1, const int* o2, const int* o3, const int* o4){
    size_t id = (size_t)blockIdx.x * 256 + threadIdx.x;
    const float4* embv = (const float4*)emb;
    if (id < 2400000) {
        size_t row = id / 75; int wi = (int)(id % 75);
        ((float4*)(ws + OFF_ART))[id] = embv[(size_t)art_in[row] * 75 + wi];
    } else if (id < 2436000) {
        size_t i2 = id - 2400000; size_t row = i2 / 75; int wi = (int)(i2 % 75);
        ((float4*)(ws + OFF_QEMB))[i2] = embv[(size_t)q_in[row] * 75 + wi];
    } else if (id < 2512800) {
        size_t i3 = id - 2436000; size_t row = i3 / 75; int wi = (int)(i3 % 75);
        int opt = (int)(row / 256); int rr = (int)(row % 256);
        const int* op = (opt == 0) ? o1 : (opt == 1) ? o2 : (opt == 2) ? o3 : o4;
        ((float4*)(ws + OFF_OPTE))[i3] = embv[(size_t)op[rr] * 75 + wi];
    }
}

// ---------------- hierarchical group sums: S2 and S5 from ART ----------------
__global__ void k_s2s5(float* ws){
    size_t id = (size_t)blockIdx.x * 256 + threadIdx.x;
    const float4* art = (const float4*)(ws + OFF_ART);
    if (id < 1200000) {
        size_t row = id / 75; int wi = (int)(id % 75);
        size_t b = row / 1000, g = row % 1000;
        const float4* p = art + ((b * 2000 + g * 2) * 75 + wi);
        ((float4*)(ws + OFF_GATE))[row * 75 + wi] = f4add(p[0], p[75]);
    } else if (id < 1680000) {
        size_t i2 = id - 1200000;
        size_t row = i2 / 75; int wi = (int)(i2 % 75);
        size_t b = row / 400, g = row % 400;
        const float4* p = art + ((b * 2000 + g * 5) * 75 + wi);
        float4 s = f4add(f4add(p[0], p[75]), f4add(p[150], p[225]));
        s = f4add(s, p[300]);
        ((float4*)(ws + OFF_R2))[row * 75 + wi] = s;
    }
}

// ---------------- coarse CE (r=2,4,10,25): M=32, LDS-split A, MFMA ----------------
// blocks: [0,40) r25 | [40,140) r10 | [140,390) r4 | [390,890) r2
__global__ __launch_bounds__(256) void k_ce_coarse(float* ws, const float* ceb){
    int gb = blockIdx.x;
    int kind, rows0, wi, rowLocal0;
    if (gb < 40)       { kind = 3; rows0 = 27200; wi = 4; rowLocal0 = gb * 32; }
    else if (gb < 140) { kind = 2; rows0 = 24000; wi = 3; rowLocal0 = (gb - 40) * 32; }
    else if (gb < 390) { kind = 1; rows0 = 16000; wi = 2; rowLocal0 = (gb - 140) * 32; }
    else               { kind = 0; rows0 = 0;     wi = 1; rowLocal0 = (gb - 390) * 32; }

    __shared__ ushortT LA[20480];  // 40 KB: 2 tiles x 10 kt x {hi,lo} x 512
    int tid = threadIdx.x;
    lds_zero_kt9(LA, tid);
    __syncthreads();
    const float4* S2v = (const float4*)(ws + OFF_GATE);
    const float4* S5v = (const float4*)(ws + OFF_R2);
    for (int v = tid; v < 2400; v += 256) {
        int r = v / 75, dc4 = v % 75;
        int R = rowLocal0 + r;
        float4 s;
        if (kind == 0) {
            s = S2v[(size_t)R * 75 + dc4];
        } else if (kind == 1) {
            int b = R / 500, g = R % 500;
            const float4* p = S2v + ((size_t)b * 1000 + 2 * g) * 75 + dc4;
            s = f4add(p[0], p[75]);
        } else if (kind == 2) {
            int b = R / 200, g = R % 200;
            const float4* p = S5v + ((size_t)b * 400 + 2 * g) * 75 + dc4;
            s = f4add(p[0], p[75]);
        } else {
            int b = R / 80, g = R % 80;
            const float4* p = S5v + ((size_t)b * 400 + 5 * g) * 75 + dc4;
            s = f4add(f4add(p[0], p[75]), f4add(p[150], p[225]));
            s = f4add(s, p[300]);
        }
        lds_store_split(LA, r, dc4, s);
    }
    __syncthreads();

    int lane = tid & 63, wv = tid >> 6;
    int mrow = lane & 15, quad = lane >> 4;
    const ushortT* wb = (const ushortT*)(ws + OFF_WB);
    int mpH = wi * 20, mpL = wi * 20 + 10;

    for (int p = 0; p < 3; p++) {
        int n0 = wv + p * 8; if (n0 >= 19) break;
        int n1 = n0 + 4; bool has1 = (n1 < 19);
        f32x4 acc[2][2] = {{{0.f,0.f,0.f,0.f},{0.f,0.f,0.f,0.f}},
                           {{0.f,0.f,0.f,0.f},{0.f,0.f,0.f,0.f}}};  // [ni][tile]
        #pragma unroll
        for (int kt = 0; kt < 10; kt++) {
            bf8 Ah0 = lds_afrag(LA, 0, kt, 0, lane), Al0 = lds_afrag(LA, 0, kt, 1, lane);
            bf8 Ah1 = lds_afrag(LA, 1, kt, 0, lane), Al1 = lds_afrag(LA, 1, kt, 1, lane);
            bf8 Bh = load_bfrag(wb, mpH, kt, n0, lane);
            bf8 Bl = load_bfrag(wb, mpL, kt, n0, lane);
            acc[0][0] = __builtin_amdgcn_mfma_f32_16x16x32_bf16(Ah0, Bh, acc[0][0], 0, 0, 0);
            acc[0][0] = __builtin_amdgcn_mfma_f32_16x16x32_bf16(Ah0, Bl, acc[0][0], 0, 0, 0);
            acc[0][0] = __builtin_amdgcn_mfma_f32_16x16x32_bf16(Al0, Bh, acc[0][0], 0, 0, 0);
            acc[0][1] = __builtin_amdgcn_mfma_f32_16x16x32_bf16(Ah1, Bh, acc[0][1], 0, 0, 0);
            acc[0][1] = __builtin_amdgcn_mfma_f32_16x16x32_bf16(Ah1, Bl, acc[0][1], 0, 0, 0);
            acc[0][1] = __builtin_amdgcn_mfma_f32_16x16x32_bf16(Al1, Bh, acc[0][1], 0, 0, 0);
            if (has1) {
                bf8 Bh1 = load_bfrag(wb, mpH, kt, n1, lane);
                bf8 Bl1 = load_bfrag(wb, mpL, kt, n1, lane);
                acc[1][0] = __builtin_amdgcn_mfma_f32_16x16x32_bf16(Ah0, Bh1, acc[1][0], 0, 0, 0);
                acc[1][0] = __builtin_amdgcn_mfma_f32_16x16x32_bf16(Ah0, Bl1, acc[1][0], 0, 0, 0);
                acc[1][0] = __builtin_amdgcn_mfma_f32_16x16x32_bf16(Al0, Bh1, acc[1][0], 0, 0, 0);
                acc[1][1] = __builtin_amdgcn_mfma_f32_16x16x32_bf16(Ah1, Bh1, acc[1][1], 0, 0, 0);
                acc[1][1] = __builtin_amdgcn_mfma_f32_16x16x32_bf16(Ah1, Bl1, acc[1][1], 0, 0, 0);
                acc[1][1] = __builtin_amdgcn_mfma_f32_16x16x32_bf16(Al1, Bh1, acc[1][1], 0, 0, 0);
            }
        }
        #pragma unroll
        for (int ni = 0; ni < 2; ni++) {
            int nt = ni ? n1 : n0;
            if (ni && !has1) break;
            int e = nt * 16 + mrow;
            if (e >= 300) continue;
            float bv = ceb[wi * 300 + e];
            #pragma unroll
            for (int tile = 0; tile < 2; tile++)
                #pragma unroll
                for (int q = 0; q < 4; q++) {
                    int row = rows0 + rowLocal0 + tile * 16 + quad * 4 + q;
                    ws[OFF_HC + (size_t)row * 300 + e] = fmaxf(acc[ni][tile][q] + bv, 0.f);
                }
        }
    }
}

// ---------------- fused: ce0 + Wz MFMA (shared A) + gate MLP epilogue, M=32 ----------------
__global__ __launch_bounds__(256) void k_fused(float* ws, const float* ceb,
                                               const float* m1W, const float* m1b,
                                               const float* m2W, const float* m2b,
                                               const float* bz){
    int row0 = blockIdx.x * 32;
    __shared__ ushortT LA[20480];
    int tid = threadIdx.x;
    lds_zero_kt9(LA, tid);
    __syncthreads();
    for (int v = tid; v < 2400; v += 256) {
        int r = v / 75, dc4 = v % 75;
        float4 s = *(const float4*)&ws[OFF_ART + (size_t)(row0 + r) * 300 + dc4 * 4];
        lds_store_split(LA, r, dc4, s);
    }
    __syncthreads();

    float w1[3][5], b1[3], w2[3], b2;
    #pragma unroll
    for (int k = 0; k < 3; k++) {
        #pragma unroll
        for (int i = 0; i < 5; i++) w1[k][i] = m1W[k * 5 + i];
        b1[k] = m1b[k]; w2[k] = m2W[k];
    }
    b2 = m2b[0];

    int lane = tid & 63, wv = tid >> 6;
    int mrow = lane & 15, quad = lane >> 4;
    const ushortT* wb = (const ushortT*)(ws + OFF_WB);

    for (int p = 0; p < 3; p++) {
        int n0 = wv + p * 8; if (n0 >= 19) break;
        int n1 = n0 + 4; bool has1 = (n1 < 19);
        f32x4 aA[2][2] = {{{0.f,0.f,0.f,0.f},{0.f,0.f,0.f,0.f}},
                          {{0.f,0.f,0.f,0.f},{0.f,0.f,0.f,0.f}}};
        f32x4 aZ[2][2] = {{{0.f,0.f,0.f,0.f},{0.f,0.f,0.f,0.f}},
                          {{0.f,0.f,0.f,0.f},{0.f,0.f,0.f,0.f}}};
        #pragma unroll
        for (int kt = 0; kt < 10; kt++) {
            bf8 Ah0 = lds_afrag(LA, 0, kt, 0, lane), Al0 = lds_afrag(LA, 0, kt, 1, lane);
            bf8 Ah1 = lds_afrag(LA, 1, kt, 0, lane), Al1 = lds_afrag(LA, 1, kt, 1, lane);
            {
                bf8 B0h = load_bfrag(wb, 0,   kt, n0, lane);
                bf8 B0l = load_bfrag(wb, 10,  kt, n0, lane);
                bf8 B5h = load_bfrag(wb, 100, kt, n0, lane);
                bf8 B5l = load_bfrag(wb, 110, kt, n0, lane);
                aA[0][0] = __builtin_amdgcn_mfma_f32_16x16x32_bf16(Ah0, B0h, aA[0][0], 0, 0, 0);
                aZ[0][0] = __builtin_amdgcn_mfma_f32_16x16x32_bf16(Ah0, B5h, aZ[0][0], 0, 0, 0);
                aA[0][0] = __builtin_amdgcn_mfma_f32_16x16x32_bf16(Ah0, B0l, aA[0][0], 0, 0, 0);
                aZ[0][0] = __builtin_amdgcn_mfma_f32_16x16x32_bf16(Ah0, B5l, aZ[0][0], 0, 0, 0);
                aA[0][0] = __builtin_amdgcn_mfma_f32_16x16x32_bf16(Al0, B0h, aA[0][0], 0, 0, 0);
                aZ[0][0] = __builtin_amdgcn_mfma_f32_16x16x32_bf16(Al0, B5h, aZ[0][0], 0, 0, 0);
                aA[0][1] = __builtin_amdgcn_mfma_f32_16x16x32_bf16(Ah1, B0h, aA[0][1], 0, 0, 0);
                aZ[0][1] = __builtin_amdgcn_mfma_f32_16x16x32_bf16(Ah1, B5h, aZ[0][1], 0, 0, 0);
                aA[0][1] = __builtin_amdgcn_mfma_f32_16x16x32_bf16(Ah1, B0l, aA[0][1], 0, 0, 0);
                aZ[0][1] = __builtin_amdgcn_mfma_f32_16x16x32_bf16(Ah1, B5l, aZ[0][1], 0, 0, 0);
                aA[0][1] = __builtin_amdgcn_mfma_f32_16x16x32_bf16(Al1, B0h, aA[0][1], 0, 0, 0);
                aZ[0][1] = __builtin_amdgcn_mfma_f32_16x16x32_bf16(Al1, B5h, aZ[0][1], 0, 0, 0);
            }
            if (has1) {
                bf8 B0h = load_bfrag(wb, 0,   kt, n1, lane);
                bf8 B0l = load_bfrag(wb, 10,  kt, n1, lane);
                bf8 B5h = load_bfrag(wb, 100, kt, n1, lane);
                bf8 B5l = load_bfrag(wb, 110, kt, n1, lane);
                aA[1][0] = __builtin_amdgcn_mfma_f32_16x16x32_bf16(Ah0, B0h, aA[1][0], 0, 0, 0);
                aZ[1][0] = __builtin_amdgcn_mfma_f32_16x16x32_bf16(Ah0, B5h, aZ[1][0], 0, 0, 0);
                aA[1][0] = __builtin_amdgcn_mfma_f32_16x16x32_bf16(Ah0, B0l, aA[1][0], 0, 0, 0);
                aZ[1][0] = __builtin_amdgcn_mfma_f32_16x16x32_bf16(Ah0, B5l, aZ[1][0], 0, 0, 0);
                aA[1][0] = __builtin_amdgcn_mfma_f32_16x16x32_bf16(Al0, B0h, aA[1][0], 0, 0, 0);
                aZ[1][0] = __builtin_amdgcn_mfma_f32_16x16x32_bf16(Al0, B5h, aZ[1][0], 0, 0, 0);
                aA[1][1] = __builtin_amdgcn_mfma_f32_16x16x32_bf16(Ah1, B0h, aA[1][1], 0, 0, 0);
                aZ[1][1] = __builtin_amdgcn_mfma_f32_16x16x32_bf16(Ah1, B5h, aZ[1][1], 0, 0, 0);
                aA[1][1] = __builtin_amdgcn_mfma_f32_16x16x32_bf16(Ah1, B0l, aA[1][1], 0, 0, 0);
                aZ[1][1] = __builtin_amdgcn_mfma_f32_16x16x32_bf16(Ah1, B5l, aZ[1][1], 0, 0, 0);
                aA[1][1] = __builtin_amdgcn_mfma_f32_16x16x32_bf16(Al1, B0h, aA[1][1], 0, 0, 0);
                aZ[1][1] = __builtin_amdgcn_mfma_f32_16x16x32_bf16(Al1, B5h, aZ[1][1], 0, 0, 0);
            }
        }
        #pragma unroll
        for (int ni = 0; ni < 2; ni++) {
            if (ni && !has1) break;
            int nt = ni ? n1 : n0;
            int e = nt * 16 + mrow;
            if (e >= 300) continue;
            float cebe = ceb[e], bze = bz[e];
            #pragma unroll
            for (int tile = 0; tile < 2; tile++) {
                #pragma unroll
                for (int q = 0; q < 4; q++) {
                    int row = row0 + tile * 16 + quad * 4 + q;
                    int bb = row / 2000, t = row % 2000;
                    size_t c1 = OFF_HC + ((size_t)bb * 1000 + t / 2) * 300;
                    size_t c2 = OFF_HC + (16000 + (size_t)bb * 500 + t / 4) * 300;
                    size_t c3 = OFF_HC + (24000 + (size_t)bb * 200 + t / 10) * 300;
                    size_t c4 = OFF_HC + (27200 + (size_t)bb * 80 + t / 25) * 300;
                    float y0 = fmaxf(aA[ni][tile][q] + cebe, 0.f);
                    float y1 = ws[c1 + e] * 0.5f;
                    float y2 = ws[c2 + e] * 0.25f;
                    float y3 = ws[c3 + e] * 0.1f;
                    float y4 = ws[c4 + e] * 0.04f;
                    float gacc = b2;
                    #pragma unroll
                    for (int k = 0; k < 3; k++) {
                        float a = b1[k] + y0 * w1[k][0] + y1 * w1[k][1] + y2 * w1[k][2]
                                + y3 * w1[k][3] + y4 * w1[k][4];
                        gacc += fmaxf(a, 0.f) * w2[k];
                    }
                    ws[OFF_GATE + (size_t)row * 300 + e] = fmaxf(gacc, 0.f);
                    ws[OFF_R2 + (size_t)row * 300 + e] = tanhf(aZ[ni][tile][q] + bze);
                }
            }
        }
    }
}

// ---------------- MRU scan: 40 chunks x 50 steps ----------------
__global__ void k_scan1(float* ws){
    int tid = blockIdx.x * 256 + threadIdx.x;
    if (tid >= 192000) return;
    int c = tid / 4800, ch = tid % 4800;
    int b = ch / 300, d = ch % 300;
    size_t base = (size_t)b * 2000 * 300 + d;
    float A = 1.f, Bv = 0.f;
    int t0 = c * 50;
    for (int k = 0; k < 50; k++) {
        size_t ix = base + (size_t)(t0 + k) * 300;
        float g = ws[OFF_GATE + ix], zz = ws[OFF_R2 + ix];
        Bv = g * Bv + (1.f - g) * zz;
        A *= g;
    }
    ws[OFF_SCANA + tid] = A;
    ws[OFF_SCANB + tid] = Bv;
}

__global__ void k_scan2(float* ws){
    int ch = blockIdx.x * 256 + threadIdx.x;
    if (ch >= 4800) return;
    float c = 0.f;
    for (int j = 0; j < 40; j++) {
        ws[OFF_CST + (size_t)j * 4800 + ch] = c;
        c = ws[OFF_SCANA + (size_t)j * 4800 + ch] * c + ws[OFF_SCANB + (size_t)j * 4800 + ch];
    }
}

__global__ void k_scan3(float* ws){
    int tid = blockIdx.x * 256 + threadIdx.x;
    if (tid >= 192000) return;
    int c = tid / 4800, ch = tid % 4800;
    int b = ch / 300, d = ch % 300;
    size_t base = (size_t)b * 2000 * 300 + d;
    float cc = ws[OFF_CST + tid];
    int t0 = c * 50;
    for (int k = 0; k < 50; k++) {
        size_t ix = base + (size_t)(t0 + k) * 300;
        float g = ws[OFF_GATE + ix], zz = ws[OFF_R2 + ix];
        cc = g * cc + (1.f - g) * zz;
        ws[OFF_R2 + ix] = cc;   // cs in place of z
    }
}

// ---------------- Wo MFMA fused with enc = tanh(o)*cs (in place), M=32 ----------------
__global__ __launch_bounds__(256) void k_oenc(float* ws, const float* bo){
    int row0 = blockIdx.x * 32;
    __shared__ ushortT LA[20480];
    int tid = threadIdx.x;
    lds_zero_kt9(LA, tid);
    __syncthreads();
    for (int v = tid; v < 2400; v += 256) {
        int r = v / 75, dc4 = v % 75;
        float4 s = *(const float4*)&ws[OFF_ART + (size_t)(row0 + r) * 300 + dc4 * 4];
        lds_store_split(LA, r, dc4, s);
    }
    __syncthreads();

    int lane = tid & 63, wv = tid >> 6;
    int mrow = lane & 15, quad = lane >> 4;
    const ushortT* wb = (const ushortT*)(ws + OFF_WB);

    for (int p = 0; p < 3; p++) {
        int n0 = wv + p * 8; if (n0 >= 19) break;
        int n1 = n0 + 4; bool has1 = (n1 < 19);
        f32x4 acc[2][2] = {{{0.f,0.f,0.f,0.f},{0.f,0.f,0.f,0.f}},
                           {{0.f,0.f,0.f,0.f},{0.f,0.f,0.f,0.f}}};
        #pragma unroll
        for (int kt = 0; kt < 10; kt++) {
            bf8 Ah0 = lds_afrag(LA, 0, kt, 0, lane), Al0 = lds_afrag(LA, 0, kt, 1, lane);
            bf8 Ah1 = lds_afrag(LA, 1, kt, 0, lane), Al1 = lds_afrag(LA, 1, kt, 1, lane);
            bf8 Bh = load_bfrag(wb, 120, kt, n0, lane);
            bf8 Bl = load_bfrag(wb, 130, kt, n0, lane);
            acc[0][0] = __builtin_amdgcn_mfma_f32_16x16x32_bf16(Ah0, Bh, acc[0][0], 0, 0, 0);
            acc[0][0] = __builtin_amdgcn_mfma_f32_16x16x32_bf16(Ah0, Bl, acc[0][0], 0, 0, 0);
            acc[0][0] = __builtin_amdgcn_mfma_f32_16x16x32_bf16(Al0, Bh, acc[0][0], 0, 0, 0);
            acc[0][1] = __builtin_amdgcn_mfma_f32_16x16x32_bf16(Ah1, Bh, acc[0][1], 0, 0, 0);
            acc[0][1] = __builtin_amdgcn_mfma_f32_16x16x32_bf16(Ah1, Bl, acc[0][1], 0, 0, 0);
            acc[0][1] = __builtin_amdgcn_mfma_f32_16x16x32_bf16(Al1, Bh, acc[0][1], 0, 0, 0);
            if (has1) {
                bf8 Bh1 = load_bfrag(wb, 120, kt, n1, lane);
                bf8 Bl1 = load_bfrag(wb, 130, kt, n1, lane);
                acc[1][0] = __builtin_amdgcn_mfma_f32_16x16x32_bf16(Ah0, Bh1, acc[1][0], 0, 0, 0);
                acc[1][0] = __builtin_amdgcn_mfma_f32_16x16x32_bf16(Ah0, Bl1, acc[1][0], 0, 0, 0);
                acc[1][0] = __builtin_amdgcn_mfma_f32_16x16x32_bf16(Al0, Bh1, acc[1][0], 0, 0, 0);
                acc[1][1] = __builtin_amdgcn_mfma_f32_16x16x32_bf16(Ah1, Bh1, acc[1][1], 0, 0, 0);
                acc[1][1] = __builtin_amdgcn_mfma_f32_16x16x32_bf16(Ah1, Bl1, acc[1][1], 0, 0, 0);
                acc[1][1] = __builtin_amdgcn_mfma_f32_16x16x32_bf16(Al1, Bh1, acc[1][1], 0, 0, 0);
            }
        }
        #pragma unroll
        for (int ni = 0; ni < 2; ni++) {
            if (ni && !has1) break;
            int nt = ni ? n1 : n0;
            int e = nt * 16 + mrow;
            if (e >= 300) continue;
            float bv = bo[e];
            #pragma unroll
            for (int tile = 0; tile < 2; tile++)
                #pragma unroll
                for (int q = 0; q < 4; q++) {
                    size_t idx = OFF_R2 + (size_t)(row0 + tile * 16 + quad * 4 + q) * 300 + e;
                    ws[idx] = tanhf(acc[ni][tile][q] + bv) * ws[idx];
                }
        }
    }
}

// ---------------- key projections ----------------
__global__ __launch_bounds__(320) void k_keys(float* ws, const float* f1W, const float* f1b,
                                              const float* f2W, const float* f2b,
                                              const float* f3W, const float* f3b){
    int rid = blockIdx.x;
    const float* src; const float* W; const float* bias; float* out;
    if (rid < 480)       { src = ws + OFF_QEMB + (size_t)rid * 300;               W = f1W; bias = f1b; out = ws + OFF_KEYSQ + (size_t)rid * 300; }
    else if (rid < 1504) { int rr = rid - 480;  src = ws + OFF_OPTE + (size_t)rr * 300; W = f2W; bias = f2b; out = ws + OFF_KEYS2 + (size_t)rr * 300; }
    else                 { int rr = rid - 1504; src = ws + OFF_OPTE + (size_t)rr * 300; W = f3W; bias = f3b; out = ws + OFF_KEYS3 + (size_t)rr * 300; }
    __shared__ float X[300];
    int tid = threadIdx.x;
    for (int i = tid; i < 300; i += 320) X[i] = src[i];
    __syncthreads();
    if (tid < 300) {
        float acc = bias[tid];
        const float* wr = W + (size_t)tid * 300;
        for (int d = 0; d < 300; d++) acc += X[d] * wr[d];
        out[tid] = acc;
    }
}

// ---------------- M_all = Q · K_all^T per batch (30 x 128, K=300) ----------------
__global__ __launch_bounds__(256) void k_matt(float* ws){
    int b = blockIdx.x;
    __shared__ float Q[30 * 300];
    int tid = threadIdx.x;
    for (int v = tid; v < 2250; v += 256)
        *(float4*)&Q[v * 4] = *(const float4*)&ws[OFF_QEMB + (size_t)b * 9000 + (size_t)v * 4];
    __syncthreads();
    int cw = tid & 127, half = tid >> 7;
    int combo = cw >> 4, w = cw & 15;
    size_t kbase = (combo < 4)
        ? OFF_KEYS2 + ((size_t)combo * 256 + (size_t)b * 16 + w) * 300
        : OFF_KEYS3 + ((size_t)(combo - 4) * 256 + (size_t)b * 16 + w) * 300;
    const float4* kr = (const float4*)&ws[kbase];
    for (int wp = half * 15; wp < half * 15 + 15; wp++) {
        const float4* qr = (const float4*)&Q[wp * 300];
        float a = 0.f;
        #pragma unroll 5
        for (int j = 0; j < 75; j++) {
            float4 k = kr[j], q = qr[j];
            a += k.x * q.x + k.y * q.y + k.z * q.z + k.w * q.w;
        }
        ws[OFF_MALL + (size_t)b * 3840 + (size_t)wp * 128 + cw] = a;
    }
}

// ---------------- attention: S1+softmax, S_all = P1·M_all + softmax + colsums ----------------
__global__ __launch_bounds__(256) void k_attn(float* ws){
    int tile = blockIdx.x, b = blockIdx.y;
    int t0 = tile * 32;
    __shared__ __align__(16) float U[9728];
    __shared__ float S[32 * 30];
    int tid = threadIdx.x;

    for (int v = tid; v < 2432; v += 256) {
        int r = v / 76, c = v % 76;
        int t = t0 + r;
        float4 val = make_float4(0.f, 0.f, 0.f, 0.f);
        if (c < 75 && t < 2000)
            val = *(const float4*)&ws[OFF_R2 + ((size_t)b * 2000 + t) * 300 + (size_t)c * 4];
        *(float4*)&U[r * 304 + c * 4] = val;
    }
    __syncthreads();

    if (tid < 240) {
        int q = tid / 30, w = tid % 30;
        const float4* kr = (const float4*)&ws[OFF_KEYSQ + (size_t)b * 9000 + (size_t)w * 300];
        const float4* x0 = (const float4*)&U[(q * 4 + 0) * 304];
        const float4* x1 = (const float4*)&U[(q * 4 + 1) * 304];
        const float4* x2 = (const float4*)&U[(q * 4 + 2) * 304];
        const float4* x3 = (const float4*)&U[(q * 4 + 3) * 304];
        float a0 = 0.f, a1 = 0.f, a2 = 0.f, a3 = 0.f;
        #pragma unroll 5
        for (int j = 0; j < 75; j++) {
            float4 k = kr[j];
            float4 v0 = x0[j], v1 = x1[j], v2 = x2[j], v3 = x3[j];
            a0 += v0.x * k.x + v0.y * k.y + v0.z * k.z + v0.w * k.w;
            a1 += v1.x * k.x + v1.y * k.y + v1.z * k.z + v1.w * k.w;
            a2 += v2.x * k.x + v2.y * k.y + v2.z * k.z + v2.w * k.w;
            a3 += v3.x * k.x + v3.y * k.y + v3.z * k.z + v3.w * k.w;
        }
        S[(q * 4 + 0) * 30 + w] = a0;
        S[(q * 4 + 1) * 30 + w] = a1;
        S[(q * 4 + 2) * 30 + w] = a2;
        S[(q * 4 + 3) * 30 + w] = a3;
    }
    __syncthreads();

    for (int v = tid; v < 960; v += 256)
        *(float4*)&U[v * 4] = *(const float4*)&ws[OFF_MALL + (size_t)b * 3840 + (size_t)v * 4];
    if (tid < 32) {
        float m = -1e30f;
        for (int w = 0; w < 30; w++) m = fmaxf(m, S[tid * 30 + w]);
        float s = 0.f;
        for (int w = 0; w < 30; w++) { float e = expf(S[tid * 30 + w] - m); S[tid * 30 + w] = e; s += e; }
        float inv = 1.f / s;
        for (int w = 0; w < 30; w++) S[tid * 30 + w] *= inv;
    }
    __syncthreads();

    {
        int c = tid >> 5, tl = tid & 31;
        float v[16];
        #pragma unroll
        for (int w = 0; w < 16; w++) v[w] = 0.f;
        for (int wp = 0; wp < 30; wp++) {
            float p1 = S[tl * 30 + wp];
            const float* Mr = &U[wp * 128 + c * 16];
            #pragma unroll
            for (int w = 0; w < 16; w++) v[w] += p1 * Mr[w];
        }
        float mx = v[0];
        #pragma unroll
        for (int w = 1; w < 16; w++) mx = fmaxf(mx, v[w]);
        float sum = 0.f;
        #pragma unroll
        for (int w = 0; w < 16; w++) { v[w] = expf(v[w] - mx); sum += v[w]; }
        float inv = ((t0 + tl) < 2000) ? (1.f / sum) : 0.f;
        #pragma unroll
        for (int w = 0; w < 16; w += 4) {
            float4 o = make_float4(v[w] * inv, v[w+1] * inv, v[w+2] * inv, v[w+3] * inv);
            *(float4*)&U[4224 + tl * 132 + c * 16 + w] = o;
        }
    }
    __syncthreads();

    if (tid < 128) {
        int combo = tid >> 4, w = tid & 15;
        float s = 0.f;
        for (int r = 0; r < 32; r++) s += U[4224 + r * 132 + tid];
        ws[OFF_PART + (((size_t)combo * 16 + b) * 63 + tile) * 16 + w] = s;
    }
}

// ---------------- final: reduce PART, (2D)->75->1 ----------------
__global__ __launch_bounds__(256) void k_final(float* ws, const float* as1W, const float* as1b,
                                               const float* as2W, const float* as2b, float* out){
    int blk = blockIdx.x; int o = blk >> 4, b = blk & 15;
    __shared__ float vec[600]; __shared__ float cm[32]; __shared__ float hb[80];
    int tid = threadIdx.x;
    if (tid < 32) {
        int half = tid / 16, wk = tid % 16;
        int combo = half ? (4 + o) : o;
        float s = 0.f;
        size_t base = OFF_PART + (((size_t)combo * 16 + b) * 63) * 16 + wk;
        for (int t = 0; t < 63; t++) s += ws[base + (size_t)t * 16];
        cm[tid] = s * (1.f / 2000.f);
    }
    __syncthreads();
    const float* oe = ws + OFF_OPTE + ((size_t)o * 256 + (size_t)b * 16) * 300;
    for (int idx = tid; idx < 600; idx += 256) {
        int half = idx / 300, e = idx % 300;
        float acc = 0.f;
        for (int w = 0; w < 16; w++) acc += cm[half * 16 + w] * oe[(size_t)w * 300 + e];
        vec[idx] = acc;
    }
    __syncthreads();
    if (tid < 75) {
        float acc = as1b[tid];
        for (int m = 0; m < 600; m++) acc += vec[m] * as1W[(size_t)tid * 600 + m];
        hb[tid] = fmaxf(acc, 0.f);
    }
    __syncthreads();
    if (tid == 0) {
        float s = as2b[0];
        for (int j = 0; j < 75; j++) s += hb[j] * as2W[j];
        out[b * 4 + o] = s;
    }
}

extern "C" void kernel_launch(void* const* d_in, const int* in_sizes, int n_in,
                              void* d_out, int out_size, void* d_ws, size_t ws_size,
                              hipStream_t stream) {
    float* ws = (float*)d_ws;
    const int* o1 = (const int*)d_in[0];
    const int* o2 = (const int*)d_in[1];
    const int* o3 = (const int*)d_in[2];
    const int* o4 = (const int*)d_in[3];
    const int* qin = (const int*)d_in[4];
    const int* ain = (const int*)d_in[5];
    const float* emb  = (const float*)d_in[6];
    const float* ceW  = (const float*)d_in[7];
    const float* ceb  = (const float*)d_in[8];
    const float* m1W  = (const float*)d_in[9];
    const float* m1b  = (const float*)d_in[10];
    const float* m2W  = (const float*)d_in[11];
    const float* m2b  = (const float*)d_in[12];
    const float* Wz   = (const float*)d_in[13];
    const float* bz   = (const float*)d_in[14];
    const float* Wo   = (const float*)d_in[15];
    const float* bo   = (const float*)d_in[16];
    const float* f1W  = (const float*)d_in[17];
    const float* f1b  = (const float*)d_in[18];
    const float* f2W  = (const float*)d_in[19];
    const float* f2b  = (const float*)d_in[20];
    const float* f3W  = (const float*)d_in[21];
    const float* f3b  = (const float*)d_in[22];
    const float* as1W = (const float*)d_in[23];
    const float* as1b = (const float*)d_in[24];
    const float* as2W = (const float*)d_in[25];
    const float* as2b = (const float*)d_in[26];

    k_pack<<<(680960 + 255) / 256, 256, 0, stream>>>(ws, ceW, Wz, Wo);
    k_gather<<<(2512800 + 255) / 256, 256, 0, stream>>>(ws, emb, ain, qin, o1, o2, o3, o4);
    k_s2s5<<<(1680000 + 255) / 256, 256, 0, stream>>>(ws);
    k_ce_coarse<<<890, 256, 0, stream>>>(ws, ceb);
    k_fused<<<1000, 256, 0, stream>>>(ws, ceb, m1W, m1b, m2W, m2b, bz);
    k_scan1<<<750, 256, 0, stream>>>(ws);
    k_scan2<<<19, 256, 0, stream>>>(ws);
    k_scan3<<<750, 256, 0, stream>>>(ws);
    k_oenc<<<1000, 256, 0, stream>>>(ws, bo);
    k_keys<<<2528, 320, 0, stream>>>(ws, f1W, f1b, f2W, f2b, f3W, f3b);
    k_matt<<<16, 256, 0, stream>>>(ws);
    k_attn<<<dim3(63, 16), 256, 0, stream>>>(ws);
    k_final<<<64, 256, 0, stream>>>(ws, as1W, as1b, as2W, as2b, (float*)d_out);
}

// Round 8
// 539.124 us; speedup vs baseline: 2.3016x; 1.1970x over previous
//
#include <hip/hip_runtime.h>
#include <math.h>

typedef unsigned short ushortT;
typedef short bf8 __attribute__((ext_vector_type(8)));
typedef float f32x4 __attribute__((ext_vector_type(4)));
typedef unsigned short us4 __attribute__((ext_vector_type(4)));

__device__ __forceinline__ float bf2f(ushortT u){
    union { unsigned int i; float f; } v; v.i = ((unsigned int)u) << 16; return v.f;
}
__device__ __forceinline__ ushortT f2bf(float f){
    union { float f; unsigned int i; } v; v.f = f;
    unsigned int x = v.i;
    return (ushortT)((x + 0x7fffu + ((x >> 16) & 1u)) >> 16);
}
__device__ __forceinline__ float4 f4add(float4 a, float4 b){
    return make_float4(a.x + b.x, a.y + b.y, a.z + b.z, a.w + b.w);
}

// B=16, T=2000, D=300; fp32 I/O. All DIM x DIM matvecs on bf16-split MFMA
// (xh*wh + xh*wl + xl*wh), M=32 row tiles, A split into LDS fragments.

// ---------------- workspace layout (float indices), ~161.2 MB ----------------
constexpr size_t OFF_ART   = 0;           // 9,600,000  article emb -> o (in place)
constexpr size_t OFF_R2    = 9600000;     // 9,600,000  S5 -> z -> cs -> enc
constexpr size_t OFF_GATE  = 19200000;    // 9,600,000  S2 -> gate
constexpr size_t OFF_HC    = 28800000;    // 8,544,000  coarse CE outputs
constexpr size_t OFF_WB    = 37344000;    //   972,800 f32 = 10 matrices bf16 hi/lo frags
constexpr size_t OFF_QEMB  = 38316800;    //   144,000
constexpr size_t OFF_KEYSQ = 38460800;    //   144,000
constexpr size_t OFF_OPTE  = 38604800;    //   307,200
constexpr size_t OFF_KEYS2 = 38912000;    //   307,200
constexpr size_t OFF_KEYS3 = 39219200;    //   307,200
constexpr size_t OFF_SCANA = 39526400;    //   192,000
constexpr size_t OFF_SCANB = 39718400;    //   192,000
constexpr size_t OFF_CST   = 39910400;    //   192,000
constexpr size_t OFF_PART  = 40102400;    //   129,024
constexpr size_t OFF_MALL  = 40231424;    //    61,440  M_all = Q·K_all^T
// end = 40,292,864 floats = 161.2 MB

// HC rows: r2 [0,16000)=b*1000+g | r4 [16000,24000)=b*500+g
//          r10 [24000,27200)=b*200+g | r25 [27200,28480)=b*80+g
// S2 (at OFF_GATE): 16000 rows = b*1000+g | S5 (at OFF_R2): 6400 rows = b*400+g

// WB (ushort units): ((mp + kt)*19 + nt)*512 + lane*8 + j
//   mp = matrix*20 + part*10
//   matrix: 0..4 ce, 5 Wz, 6 Wo, 7 f1W, 8 f2W, 9 f3W; part: 0 hi, 1 lo

__global__ void k_pack(float* ws, const float* ceW, const float* Wz, const float* Wo,
                       const float* f1W, const float* f2W, const float* f3W){
    int id = blockIdx.x * 256 + threadIdx.x;
    if (id >= 972800) return;          // 10 * 97280
    int m = id / 97280; int rr = id % 97280;
    int kt = rr / 9728; rr %= 9728;
    int nt = rr / 512;  rr %= 512;
    int lane = rr / 8; int j = rr % 8;
    int d = kt * 32 + (lane >> 4) * 8 + j;
    int e = nt * 16 + (lane & 15);
    float w = 0.f;
    if (d < 300 && e < 300) {
        const float* src = (m < 5) ? (ceW + (size_t)m * 90000)
                         : (m == 5) ? Wz : (m == 6) ? Wo
                         : (m == 7) ? f1W : (m == 8) ? f2W : f3W;
        w = src[(size_t)e * 300 + d];
    }
    ushortT hi = f2bf(w);
    ushortT lo = f2bf(w - bf2f(hi));
    ushortT* wb = (ushortT*)(ws + OFF_WB);
    wb[((size_t)(m * 20 + kt) * 19 + nt) * 512 + lane * 8 + j] = hi;
    wb[((size_t)(m * 20 + 10 + kt) * 19 + nt) * 512 + lane * 8 + j] = lo;
}

__device__ __forceinline__ bf8 load_bfrag(const ushortT* wb, int mp, int kt, int nt, int lane){
    return *(const bf8*)(wb + (((size_t)(mp + kt) * 19 + nt) * 512 + lane * 8));
}
__device__ __forceinline__ bf8 lds_afrag(const ushortT* LA, int tile, int kt, int part, int lane){
    return *(const bf8*)(LA + ((tile * 10 + kt) * 2 + part) * 512 + lane * 8);
}
__device__ __forceinline__ void lds_store_split(ushortT* LA, int r, int dc4, float4 s){
    int kt = dc4 / 8;
    int kk = (dc4 % 8) * 4;
    int quad = kk / 8, j = kk % 8;
    int lane = quad * 16 + (r & 15), tile = r >> 4;
    us4 h, l;
    h.x = f2bf(s.x); l.x = f2bf(s.x - bf2f(h.x));
    h.y = f2bf(s.y); l.y = f2bf(s.y - bf2f(h.y));
    h.z = f2bf(s.z); l.z = f2bf(s.z - bf2f(h.z));
    h.w = f2bf(s.w); l.w = f2bf(s.w - bf2f(h.w));
    int base = ((tile * 10 + kt) * 2) * 512 + lane * 8 + j;
    *(us4*)&LA[base] = h;
    *(us4*)&LA[base + 512] = l;
}
__device__ __forceinline__ void lds_zero_kt9(ushortT* LA, int tid){
    for (int i = tid; i < 1024; i += 256) {
        int sl = i >> 8, u = i & 255;
        int slice = (sl < 2) ? (18 + sl) : (36 + sl); // 18,19,38,39
        *(unsigned int*)&LA[slice * 512 + u * 2] = 0u;
    }
}

// ---------------- gather + inline S2/S5 group sums ----------------
// blocks [0,160): article, gb = b*10+c covers t in [c*200, c*200+200)
// blocks [160,513): question + options (flat f4 ids)
__global__ __launch_bounds__(320) void k_gather2(float* ws, const float* emb,
                         const int* art_in, const int* q_in,
                         const int* o1, const int* o2, const int* o3, const int* o4){
    int gb = blockIdx.x, tid = threadIdx.x;
    const float4* embv = (const float4*)emb;
    if (gb < 160) {
        if (tid >= 300) return;
        int b = gb / 10, c = gb % 10;
        int rg = tid / 75, d4 = tid % 75;
        int tbase = c * 200 + rg * 50;
        float4 s2 = make_float4(0.f,0.f,0.f,0.f), s5 = s2;
        float4* artv  = (float4*)(ws + OFF_ART);
        float4* s2v   = (float4*)(ws + OFF_GATE);
        float4* s5v   = (float4*)(ws + OFF_R2);
        for (int i = 0; i < 50; i++) {
            int t = tbase + i;
            int tok = art_in[b * 2000 + t];
            float4 v = embv[(size_t)tok * 75 + d4];
            artv[((size_t)b * 2000 + t) * 75 + d4] = v;
            s2 = f4add(s2, v); s5 = f4add(s5, v);
            if ((i & 1) == 1) { s2v[((size_t)b * 1000 + (t >> 1)) * 75 + d4] = s2; s2 = make_float4(0.f,0.f,0.f,0.f); }
            if (i % 5 == 4)   { s5v[((size_t)b * 400 + t / 5) * 75 + d4] = s5;   s5 = make_float4(0.f,0.f,0.f,0.f); }
        }
    } else {
        int id = (gb - 160) * 320 + tid;
        if (id < 36000) {
            size_t row = id / 75; int wi = id % 75;
            ((float4*)(ws + OFF_QEMB))[id] = embv[(size_t)q_in[row] * 75 + wi];
        } else if (id < 112800) {
            int i3 = id - 36000; size_t row = i3 / 75; int wi = i3 % 75;
            int opt = (int)(row / 256); int rr = (int)(row % 256);
            const int* op = (opt == 0) ? o1 : (opt == 1) ? o2 : (opt == 2) ? o3 : o4;
            ((float4*)(ws + OFF_OPTE))[i3] = embv[(size_t)op[rr] * 75 + wi];
        }
    }
}

// ---------------- coarse CE (r=2,4,10,25): M=32, LDS-split A, MFMA ----------------
// blocks: [0,40) r25 | [40,140) r10 | [140,390) r4 | [390,890) r2
__global__ __launch_bounds__(256) void k_ce_coarse(float* ws, const float* ceb){
    int gb = blockIdx.x;
    int kind, rows0, wi, rowLocal0;
    if (gb < 40)       { kind = 3; rows0 = 27200; wi = 4; rowLocal0 = gb * 32; }
    else if (gb < 140) { kind = 2; rows0 = 24000; wi = 3; rowLocal0 = (gb - 40) * 32; }
    else if (gb < 390) { kind = 1; rows0 = 16000; wi = 2; rowLocal0 = (gb - 140) * 32; }
    else               { kind = 0; rows0 = 0;     wi = 1; rowLocal0 = (gb - 390) * 32; }

    __shared__ ushortT LA[20480];
    int tid = threadIdx.x;
    lds_zero_kt9(LA, tid);
    __syncthreads();
    const float4* S2v = (const float4*)(ws + OFF_GATE);
    const float4* S5v = (const float4*)(ws + OFF_R2);
    for (int v = tid; v < 2400; v += 256) {
        int r = v / 75, dc4 = v % 75;
        int R = rowLocal0 + r;
        float4 s;
        if (kind == 0) {
            s = S2v[(size_t)R * 75 + dc4];
        } else if (kind == 1) {
            int b = R / 500, g = R % 500;
            const float4* p = S2v + ((size_t)b * 1000 + 2 * g) * 75 + dc4;
            s = f4add(p[0], p[75]);
        } else if (kind == 2) {
            int b = R / 200, g = R % 200;
            const float4* p = S5v + ((size_t)b * 400 + 2 * g) * 75 + dc4;
            s = f4add(p[0], p[75]);
        } else {
            int b = R / 80, g = R % 80;
            const float4* p = S5v + ((size_t)b * 400 + 5 * g) * 75 + dc4;
            s = f4add(f4add(p[0], p[75]), f4add(p[150], p[225]));
            s = f4add(s, p[300]);
        }
        lds_store_split(LA, r, dc4, s);
    }
    __syncthreads();

    int lane = tid & 63, wv = tid >> 6;
    int mrow = lane & 15, quad = lane >> 4;
    const ushortT* wb = (const ushortT*)(ws + OFF_WB);
    int mpH = wi * 20, mpL = wi * 20 + 10;

    for (int p = 0; p < 5; p++) {
        int nt = wv + p * 4; if (nt >= 19) break;
        f32x4 a0 = {0.f,0.f,0.f,0.f}, a1 = {0.f,0.f,0.f,0.f};
        #pragma unroll
        for (int kt = 0; kt < 10; kt++) {
            bf8 Ah0 = lds_afrag(LA, 0, kt, 0, lane), Al0 = lds_afrag(LA, 0, kt, 1, lane);
            bf8 Ah1 = lds_afrag(LA, 1, kt, 0, lane), Al1 = lds_afrag(LA, 1, kt, 1, lane);
            bf8 Bh = load_bfrag(wb, mpH, kt, nt, lane);
            bf8 Bl = load_bfrag(wb, mpL, kt, nt, lane);
            a0 = __builtin_amdgcn_mfma_f32_16x16x32_bf16(Ah0, Bh, a0, 0, 0, 0);
            a1 = __builtin_amdgcn_mfma_f32_16x16x32_bf16(Ah1, Bh, a1, 0, 0, 0);
            a0 = __builtin_amdgcn_mfma_f32_16x16x32_bf16(Ah0, Bl, a0, 0, 0, 0);
            a1 = __builtin_amdgcn_mfma_f32_16x16x32_bf16(Ah1, Bl, a1, 0, 0, 0);
            a0 = __builtin_amdgcn_mfma_f32_16x16x32_bf16(Al0, Bh, a0, 0, 0, 0);
            a1 = __builtin_amdgcn_mfma_f32_16x16x32_bf16(Al1, Bh, a1, 0, 0, 0);
        }
        int e = nt * 16 + mrow;
        if (e < 300) {
            float bv = ceb[wi * 300 + e];
            #pragma unroll
            for (int q = 0; q < 4; q++) {
                int r0 = rows0 + rowLocal0 + quad * 4 + q;
                ws[OFF_HC + (size_t)r0 * 300 + e] = fmaxf(a0[q] + bv, 0.f);
                ws[OFF_HC + (size_t)(r0 + 16) * 300 + e] = fmaxf(a1[q] + bv, 0.f);
            }
        }
    }
}

// ---------------- fused: ce0 + Wz + Wo MFMA (shared A) + gate/z/o epilogue ----------------
// gate -> GATE, z -> R2, o -> ART (in place; ART dead afterwards)
__global__ __launch_bounds__(256) void k_fused(float* ws, const float* ceb,
                                               const float* m1W, const float* m1b,
                                               const float* m2W, const float* m2b,
                                               const float* bz, const float* bo){
    int row0 = blockIdx.x * 32;
    __shared__ ushortT LA[20480];
    int tid = threadIdx.x;
    lds_zero_kt9(LA, tid);
    __syncthreads();
    for (int v = tid; v < 2400; v += 256) {
        int r = v / 75, dc4 = v % 75;
        float4 s = *(const float4*)&ws[OFF_ART + (size_t)(row0 + r) * 300 + dc4 * 4];
        lds_store_split(LA, r, dc4, s);
    }
    __syncthreads();

    float w1[3][5], b1[3], w2[3], b2;
    #pragma unroll
    for (int k = 0; k < 3; k++) {
        #pragma unroll
        for (int i = 0; i < 5; i++) w1[k][i] = m1W[k * 5 + i];
        b1[k] = m1b[k]; w2[k] = m2W[k];
    }
    b2 = m2b[0];

    int lane = tid & 63, wv = tid >> 6;
    int mrow = lane & 15, quad = lane >> 4;
    const ushortT* wb = (const ushortT*)(ws + OFF_WB);

    for (int p = 0; p < 5; p++) {
        int nt = wv + p * 4; if (nt >= 19) break;
        f32x4 aA0 = {0.f,0.f,0.f,0.f}, aA1 = aA0;
        f32x4 aZ0 = aA0, aZ1 = aA0, aO0 = aA0, aO1 = aA0;
        #pragma unroll
        for (int kt = 0; kt < 10; kt++) {
            bf8 Ah0 = lds_afrag(LA, 0, kt, 0, lane), Al0 = lds_afrag(LA, 0, kt, 1, lane);
            bf8 Ah1 = lds_afrag(LA, 1, kt, 0, lane), Al1 = lds_afrag(LA, 1, kt, 1, lane);
            bf8 BAh = load_bfrag(wb, 0,   kt, nt, lane);
            bf8 BAl = load_bfrag(wb, 10,  kt, nt, lane);
            bf8 BZh = load_bfrag(wb, 100, kt, nt, lane);
            bf8 BZl = load_bfrag(wb, 110, kt, nt, lane);
            bf8 BOh = load_bfrag(wb, 120, kt, nt, lane);
            bf8 BOl = load_bfrag(wb, 130, kt, nt, lane);
            aA0 = __builtin_amdgcn_mfma_f32_16x16x32_bf16(Ah0, BAh, aA0, 0, 0, 0);
            aZ0 = __builtin_amdgcn_mfma_f32_16x16x32_bf16(Ah0, BZh, aZ0, 0, 0, 0);
            aO0 = __builtin_amdgcn_mfma_f32_16x16x32_bf16(Ah0, BOh, aO0, 0, 0, 0);
            aA1 = __builtin_amdgcn_mfma_f32_16x16x32_bf16(Ah1, BAh, aA1, 0, 0, 0);
            aZ1 = __builtin_amdgcn_mfma_f32_16x16x32_bf16(Ah1, BZh, aZ1, 0, 0, 0);
            aO1 = __builtin_amdgcn_mfma_f32_16x16x32_bf16(Ah1, BOh, aO1, 0, 0, 0);
            aA0 = __builtin_amdgcn_mfma_f32_16x16x32_bf16(Ah0, BAl, aA0, 0, 0, 0);
            aZ0 = __builtin_amdgcn_mfma_f32_16x16x32_bf16(Ah0, BZl, aZ0, 0, 0, 0);
            aO0 = __builtin_amdgcn_mfma_f32_16x16x32_bf16(Ah0, BOl, aO0, 0, 0, 0);
            aA1 = __builtin_amdgcn_mfma_f32_16x16x32_bf16(Ah1, BAl, aA1, 0, 0, 0);
            aZ1 = __builtin_amdgcn_mfma_f32_16x16x32_bf16(Ah1, BZl, aZ1, 0, 0, 0);
            aO1 = __builtin_amdgcn_mfma_f32_16x16x32_bf16(Ah1, BOl, aO1, 0, 0, 0);
            aA0 = __builtin_amdgcn_mfma_f32_16x16x32_bf16(Al0, BAh, aA0, 0, 0, 0);
            aZ0 = __builtin_amdgcn_mfma_f32_16x16x32_bf16(Al0, BZh, aZ0, 0, 0, 0);
            aO0 = __builtin_amdgcn_mfma_f32_16x16x32_bf16(Al0, BOh, aO0, 0, 0, 0);
            aA1 = __builtin_amdgcn_mfma_f32_16x16x32_bf16(Al1, BAh, aA1, 0, 0, 0);
            aZ1 = __builtin_amdgcn_mfma_f32_16x16x32_bf16(Al1, BZh, aZ1, 0, 0, 0);
            aO1 = __builtin_amdgcn_mfma_f32_16x16x32_bf16(Al1, BOh, aO1, 0, 0, 0);
        }
        int e = nt * 16 + mrow;
        if (e < 300) {
            float cebe = ceb[e], bze = bz[e], boe = bo[e];
            #pragma unroll
            for (int tile = 0; tile < 2; tile++) {
                #pragma unroll
                for (int q = 0; q < 4; q++) {
                    float vA = tile ? aA1[q] : aA0[q];
                    float vZ = tile ? aZ1[q] : aZ0[q];
                    float vO = tile ? aO1[q] : aO0[q];
                    int row = row0 + tile * 16 + quad * 4 + q;
                    int bb = row / 2000, t = row % 2000;
                    size_t c1 = OFF_HC + ((size_t)bb * 1000 + t / 2) * 300;
                    size_t c2 = OFF_HC + (16000 + (size_t)bb * 500 + t / 4) * 300;
                    size_t c3 = OFF_HC + (24000 + (size_t)bb * 200 + t / 10) * 300;
                    size_t c4 = OFF_HC + (27200 + (size_t)bb * 80 + t / 25) * 300;
                    float y0 = fmaxf(vA + cebe, 0.f);
                    float y1 = ws[c1 + e] * 0.5f;
                    float y2 = ws[c2 + e] * 0.25f;
                    float y3 = ws[c3 + e] * 0.1f;
                    float y4 = ws[c4 + e] * 0.04f;
                    float gacc = b2;
                    #pragma unroll
                    for (int k = 0; k < 3; k++) {
                        float a = b1[k] + y0 * w1[k][0] + y1 * w1[k][1] + y2 * w1[k][2]
                                + y3 * w1[k][3] + y4 * w1[k][4];
                        gacc += fmaxf(a, 0.f) * w2[k];
                    }
                    ws[OFF_GATE + (size_t)row * 300 + e] = fmaxf(gacc, 0.f);
                    ws[OFF_R2 + (size_t)row * 300 + e] = tanhf(vZ + bze);
                    ws[OFF_ART + (size_t)row * 300 + e] = tanhf(vO + boe);
                }
            }
        }
    }
}

// ---------------- MRU scan: 40 chunks x 50 steps ----------------
__global__ void k_scan1(float* ws){
    int tid = blockIdx.x * 256 + threadIdx.x;
    if (tid >= 192000) return;
    int c = tid / 4800, ch = tid % 4800;
    int b = ch / 300, d = ch % 300;
    size_t base = (size_t)b * 2000 * 300 + d;
    float A = 1.f, Bv = 0.f;
    int t0 = c * 50;
    for (int k = 0; k < 50; k++) {
        size_t ix = base + (size_t)(t0 + k) * 300;
        float g = ws[OFF_GATE + ix], zz = ws[OFF_R2 + ix];
        Bv = g * Bv + (1.f - g) * zz;
        A *= g;
    }
    ws[OFF_SCANA + tid] = A;
    ws[OFF_SCANB + tid] = Bv;
}

__global__ void k_scan2(float* ws){
    int ch = blockIdx.x * 256 + threadIdx.x;
    if (ch >= 4800) return;
    float c = 0.f;
    for (int j = 0; j < 40; j++) {
        ws[OFF_CST + (size_t)j * 4800 + ch] = c;
        c = ws[OFF_SCANA + (size_t)j * 4800 + ch] * c + ws[OFF_SCANB + (size_t)j * 4800 + ch];
    }
}

// scan3: recompute cs and write enc = o * cs  (o from ART region)
__global__ void k_scan3(float* ws){
    int tid = blockIdx.x * 256 + threadIdx.x;
    if (tid >= 192000) return;
    int c = tid / 4800, ch = tid % 4800;
    int b = ch / 300, d = ch % 300;
    size_t base = (size_t)b * 2000 * 300 + d;
    float cc = ws[OFF_CST + tid];
    int t0 = c * 50;
    for (int k = 0; k < 50; k++) {
        size_t ix = base + (size_t)(t0 + k) * 300;
        float g = ws[OFF_GATE + ix], zz = ws[OFF_R2 + ix];
        cc = g * cc + (1.f - g) * zz;
        ws[OFF_R2 + ix] = ws[OFF_ART + ix] * cc;
    }
}

// ---------------- key projections via MFMA: f1(q), f2(opt), f3(opt) ----------------
// blocks: [0,15) f1/QEMB->KEYSQ | [15,47) f2/OPTE->KEYS2 | [47,79) f3/OPTE->KEYS3
__global__ __launch_bounds__(256) void k_keysm(float* ws, const float* f1b,
                                               const float* f2b, const float* f3b){
    int gb = blockIdx.x;
    int wm, rowLocal0; size_t inoff, outoff; const float* bias;
    if (gb < 15)      { wm = 7; inoff = OFF_QEMB; outoff = OFF_KEYSQ; bias = f1b; rowLocal0 = gb * 32; }
    else if (gb < 47) { wm = 8; inoff = OFF_OPTE; outoff = OFF_KEYS2; bias = f2b; rowLocal0 = (gb - 15) * 32; }
    else              { wm = 9; inoff = OFF_OPTE; outoff = OFF_KEYS3; bias = f3b; rowLocal0 = (gb - 47) * 32; }

    __shared__ ushortT LA[20480];
    int tid = threadIdx.x;
    lds_zero_kt9(LA, tid);
    __syncthreads();
    for (int v = tid; v < 2400; v += 256) {
        int r = v / 75, dc4 = v % 75;
        float4 s = *(const float4*)&ws[inoff + (size_t)(rowLocal0 + r) * 300 + dc4 * 4];
        lds_store_split(LA, r, dc4, s);
    }
    __syncthreads();

    int lane = tid & 63, wv = tid >> 6;
    int mrow = lane & 15, quad = lane >> 4;
    const ushortT* wb = (const ushortT*)(ws + OFF_WB);
    int mpH = wm * 20, mpL = wm * 20 + 10;

    for (int p = 0; p < 5; p++) {
        int nt = wv + p * 4; if (nt >= 19) break;
        f32x4 a0 = {0.f,0.f,0.f,0.f}, a1 = {0.f,0.f,0.f,0.f};
        #pragma unroll
        for (int kt = 0; kt < 10; kt++) {
            bf8 Ah0 = lds_afrag(LA, 0, kt, 0, lane), Al0 = lds_afrag(LA, 0, kt, 1, lane);
            bf8 Ah1 = lds_afrag(LA, 1, kt, 0, lane), Al1 = lds_afrag(LA, 1, kt, 1, lane);
            bf8 Bh = load_bfrag(wb, mpH, kt, nt, lane);
            bf8 Bl = load_bfrag(wb, mpL, kt, nt, lane);
            a0 = __builtin_amdgcn_mfma_f32_16x16x32_bf16(Ah0, Bh, a0, 0, 0, 0);
            a1 = __builtin_amdgcn_mfma_f32_16x16x32_bf16(Ah1, Bh, a1, 0, 0, 0);
            a0 = __builtin_amdgcn_mfma_f32_16x16x32_bf16(Ah0, Bl, a0, 0, 0, 0);
            a1 = __builtin_amdgcn_mfma_f32_16x16x32_bf16(Ah1, Bl, a1, 0, 0, 0);
            a0 = __builtin_amdgcn_mfma_f32_16x16x32_bf16(Al0, Bh, a0, 0, 0, 0);
            a1 = __builtin_amdgcn_mfma_f32_16x16x32_bf16(Al1, Bh, a1, 0, 0, 0);
        }
        int e = nt * 16 + mrow;
        if (e < 300) {
            float bv = bias[e];
            #pragma unroll
            for (int q = 0; q < 4; q++) {
                int r0 = rowLocal0 + quad * 4 + q;
                ws[outoff + (size_t)r0 * 300 + e] = a0[q] + bv;
                ws[outoff + (size_t)(r0 + 16) * 300 + e] = a1[q] + bv;
            }
        }
    }
}

// ---------------- M_all = Q · K_all^T per batch (30 x 128, K=300) ----------------
__global__ __launch_bounds__(256) void k_matt(float* ws){
    int b = blockIdx.x;
    __shared__ float Q[30 * 300];
    int tid = threadIdx.x;
    for (int v = tid; v < 2250; v += 256)
        *(float4*)&Q[v * 4] = *(const float4*)&ws[OFF_QEMB + (size_t)b * 9000 + (size_t)v * 4];
    __syncthreads();
    int cw = tid & 127, half = tid >> 7;
    int combo = cw >> 4, w = cw & 15;
    size_t kbase = (combo < 4)
        ? OFF_KEYS2 + ((size_t)combo * 256 + (size_t)b * 16 + w) * 300
        : OFF_KEYS3 + ((size_t)(combo - 4) * 256 + (size_t)b * 16 + w) * 300;
    const float4* kr = (const float4*)&ws[kbase];
    for (int wp = half * 15; wp < half * 15 + 15; wp++) {
        const float4* qr = (const float4*)&Q[wp * 300];
        float a = 0.f;
        #pragma unroll 5
        for (int j = 0; j < 75; j++) {
            float4 k = kr[j], q = qr[j];
            a += k.x * q.x + k.y * q.y + k.z * q.z + k.w * q.w;
        }
        ws[OFF_MALL + (size_t)b * 3840 + (size_t)wp * 128 + cw] = a;
    }
}

// ---------------- attention: S1+softmax, S_all = P1·M_all + softmax + colsums ----------------
__global__ __launch_bounds__(256) void k_attn(float* ws){
    int tile = blockIdx.x, b = blockIdx.y;
    int t0 = tile * 32;
    __shared__ __align__(16) float U[9728];
    __shared__ float S[32 * 30];
    int tid = threadIdx.x;

    for (int v = tid; v < 2432; v += 256) {
        int r = v / 76, c = v % 76;
        int t = t0 + r;
        float4 val = make_float4(0.f, 0.f, 0.f, 0.f);
        if (c < 75 && t < 2000)
            val = *(const float4*)&ws[OFF_R2 + ((size_t)b * 2000 + t) * 300 + (size_t)c * 4];
        *(float4*)&U[r * 304 + c * 4] = val;
    }
    __syncthreads();

    if (tid < 240) {
        int q = tid / 30, w = tid % 30;
        const float4* kr = (const float4*)&ws[OFF_KEYSQ + (size_t)b * 9000 + (size_t)w * 300];
        const float4* x0 = (const float4*)&U[(q * 4 + 0) * 304];
        const float4* x1 = (const float4*)&U[(q * 4 + 1) * 304];
        const float4* x2 = (const float4*)&U[(q * 4 + 2) * 304];
        const float4* x3 = (const float4*)&U[(q * 4 + 3) * 304];
        float a0 = 0.f, a1 = 0.f, a2 = 0.f, a3 = 0.f;
        #pragma unroll 5
        for (int j = 0; j < 75; j++) {
            float4 k = kr[j];
            float4 v0 = x0[j], v1 = x1[j], v2 = x2[j], v3 = x3[j];
            a0 += v0.x * k.x + v0.y * k.y + v0.z * k.z + v0.w * k.w;
            a1 += v1.x * k.x + v1.y * k.y + v1.z * k.z + v1.w * k.w;
            a2 += v2.x * k.x + v2.y * k.y + v2.z * k.z + v2.w * k.w;
            a3 += v3.x * k.x + v3.y * k.y + v3.z * k.z + v3.w * k.w;
        }
        S[(q * 4 + 0) * 30 + w] = a0;
        S[(q * 4 + 1) * 30 + w] = a1;
        S[(q * 4 + 2) * 30 + w] = a2;
        S[(q * 4 + 3) * 30 + w] = a3;
    }
    __syncthreads();

    for (int v = tid; v < 960; v += 256)
        *(float4*)&U[v * 4] = *(const float4*)&ws[OFF_MALL + (size_t)b * 3840 + (size_t)v * 4];
    if (tid < 32) {
        float m = -1e30f;
        for (int w = 0; w < 30; w++) m = fmaxf(m, S[tid * 30 + w]);
        float s = 0.f;
        for (int w = 0; w < 30; w++) { float e = expf(S[tid * 30 + w] - m); S[tid * 30 + w] = e; s += e; }
        float inv = 1.f / s;
        for (int w = 0; w < 30; w++) S[tid * 30 + w] *= inv;
    }
    __syncthreads();

    {
        int c = tid >> 5, tl = tid & 31;
        float v[16];
        #pragma unroll
        for (int w = 0; w < 16; w++) v[w] = 0.f;
        for (int wp = 0; wp < 30; wp++) {
            float p1 = S[tl * 30 + wp];
            const float* Mr = &U[wp * 128 + c * 16];
            #pragma unroll
            for (int w = 0; w < 16; w++) v[w] += p1 * Mr[w];
        }
        float mx = v[0];
        #pragma unroll
        for (int w = 1; w < 16; w++) mx = fmaxf(mx, v[w]);
        float sum = 0.f;
        #pragma unroll
        for (int w = 0; w < 16; w++) { v[w] = expf(v[w] - mx); sum += v[w]; }
        float inv = ((t0 + tl) < 2000) ? (1.f / sum) : 0.f;
        #pragma unroll
        for (int w = 0; w < 16; w += 4) {
            float4 o = make_float4(v[w] * inv, v[w+1] * inv, v[w+2] * inv, v[w+3] * inv);
            *(float4*)&U[4224 + tl * 132 + c * 16 + w] = o;
        }
    }
    __syncthreads();

    if (tid < 128) {
        int combo = tid >> 4, w = tid & 15;
        float s = 0.f;
        for (int r = 0; r < 32; r++) s += U[4224 + r * 132 + tid];
        ws[OFF_PART + (((size_t)combo * 16 + b) * 63 + tile) * 16 + w] = s;
    }
}

// ---------------- final: reduce PART, (2D)->75->1 ----------------
__global__ __launch_bounds__(256) void k_final(float* ws, const float* as1W, const float* as1b,
                                               const float* as2W, const float* as2b, float* out){
    int blk = blockIdx.x; int o = blk >> 4, b = blk & 15;
    __shared__ float vec[600]; __shared__ float cm[32]; __shared__ float hb[80];
    int tid = threadIdx.x;
    if (tid < 32) {
        int half = tid / 16, wk = tid % 16;
        int combo = half ? (4 + o) : o;
        float s = 0.f;
        size_t base = OFF_PART + (((size_t)combo * 16 + b) * 63) * 16 + wk;
        for (int t = 0; t < 63; t++) s += ws[base + (size_t)t * 16];
        cm[tid] = s * (1.f / 2000.f);
    }
    __syncthreads();
    const float* oe = ws + OFF_OPTE + ((size_t)o * 256 + (size_t)b * 16) * 300;
    for (int idx = tid; idx < 600; idx += 256) {
        int half = idx / 300, e = idx % 300;
        float acc = 0.f;
        for (int w = 0; w < 16; w++) acc += cm[half * 16 + w] * oe[(size_t)w * 300 + e];
        vec[idx] = acc;
    }
    __syncthreads();
    if (tid < 75) {
        float acc = as1b[tid];
        for (int m = 0; m < 600; m++) acc += vec[m] * as1W[(size_t)tid * 600 + m];
        hb[tid] = fmaxf(acc, 0.f);
    }
    __syncthreads();
    if (tid == 0) {
        float s = as2b[0];
        for (int j = 0; j < 75; j++) s += hb[j] * as2W[j];
        out[b * 4 + o] = s;
    }
}

extern "C" void kernel_launch(void* const* d_in, const int* in_sizes, int n_in,
                              void* d_out, int out_size, void* d_ws, size_t ws_size,
                              hipStream_t stream) {
    float* ws = (float*)d_ws;
    const int* o1 = (const int*)d_in[0];
    const int* o2 = (const int*)d_in[1];
    const int* o3 = (const int*)d_in[2];
    const int* o4 = (const int*)d_in[3];
    const int* qin = (const int*)d_in[4];
    const int* ain = (const int*)d_in[5];
    const float* emb  = (const float*)d_in[6];
    const float* ceW  = (const float*)d_in[7];
    const float* ceb  = (const float*)d_in[8];
    const float* m1W  = (const float*)d_in[9];
    const float* m1b  = (const float*)d_in[10];
    const float* m2W  = (const float*)d_in[11];
    const float* m2b  = (const float*)d_in[12];
    const float* Wz   = (const float*)d_in[13];
    const float* bz   = (const float*)d_in[14];
    const float* Wo   = (const float*)d_in[15];
    const float* bo   = (const float*)d_in[16];
    const float* f1W  = (const float*)d_in[17];
    const float* f1b  = (const float*)d_in[18];
    const float* f2W  = (const float*)d_in[19];
    const float* f2b  = (const float*)d_in[20];
    const float* f3W  = (const float*)d_in[21];
    const float* f3b  = (const float*)d_in[22];
    const float* as1W = (const float*)d_in[23];
    const float* as1b = (const float*)d_in[24];
    const float* as2W = (const float*)d_in[25];
    const float* as2b = (const float*)d_in[26];

    k_pack<<<3800, 256, 0, stream>>>(ws, ceW, Wz, Wo, f1W, f2W, f3W);
    k_gather2<<<513, 320, 0, stream>>>(ws, emb, ain, qin, o1, o2, o3, o4);
    k_ce_coarse<<<890, 256, 0, stream>>>(ws, ceb);
    k_fused<<<1000, 256, 0, stream>>>(ws, ceb, m1W, m1b, m2W, m2b, bz, bo);
    k_scan1<<<750, 256, 0, stream>>>(ws);
    k_scan2<<<19, 256, 0, stream>>>(ws);
    k_scan3<<<750, 256, 0, stream>>>(ws);
    k_keysm<<<79, 256, 0, stream>>>(ws, f1b, f2b, f3b);
    k_matt<<<16, 256, 0, stream>>>(ws);
    k_attn<<<dim3(63, 16), 256, 0, stream>>>(ws);
    k_final<<<64, 256, 0, stream>>>(ws, as1W, as1b, as2W, as2b, (float*)d_out);
}